// Round 2
// baseline (929.277 us; speedup 1.0000x reference)
//
#include <hip/hip_runtime.h>
#include <hip/hip_bf16.h>

// ---------------------------------------------------------------------------
// GATEncoder: 2x (GAT(128->4x64, concat) -> PReLU -> GAT(256->32) -> PReLU)
// then MoCo q/k projections (l2-norm), entity-pair fusion MLP, adversarial sums.
// ALL float tensors are f32 (in_npz size proves inputs can't be bf16).
// Strategy: CSR-by-dst build once; gather-based edge softmax (no segment_max —
// shift-invariant, scores bounded ~11); intermediates f32 in d_ws.
// ---------------------------------------------------------------------------

// ------------------------------ CSR build ----------------------------------
__global__ void k_zero_i(int* __restrict__ p, int n) {
    int i = blockIdx.x * 256 + threadIdx.x;
    if (i < n) p[i] = 0;
}

__global__ void k_count(const int* __restrict__ dst, int E, int* __restrict__ cnt) {
    int e = blockIdx.x * 256 + threadIdx.x;
    if (e < E) atomicAdd(&cnt[dst[e]], 1);
}

__global__ __launch_bounds__(1024) void k_scan(const int* __restrict__ cnt,
                                               int* __restrict__ rowptr, int n, int E) {
    __shared__ int tile[1024];
    int tid = threadIdx.x;
    int carry = 0;
    for (int base = 0; base < n; base += 1024) {
        int i = base + tid;
        int v = (i < n) ? cnt[i] : 0;
        tile[tid] = v;
        __syncthreads();
        for (int off = 1; off < 1024; off <<= 1) {
            int t = (tid >= off) ? tile[tid - off] : 0;
            __syncthreads();
            tile[tid] += t;
            __syncthreads();
        }
        if (i < n) rowptr[i] = carry + tile[tid] - v;  // exclusive
        carry += tile[1023];
        __syncthreads();
    }
    if (tid == 0) rowptr[n] = E;
}

__global__ void k_copy_i(const int* __restrict__ a, int* __restrict__ b, int n) {
    int i = blockIdx.x * 256 + threadIdx.x;
    if (i < n) b[i] = a[i];
}

__global__ void k_fill(const int* __restrict__ src, const int* __restrict__ dst, int E,
                       int* __restrict__ cursor, int* __restrict__ csrc) {
    int e = blockIdx.x * 256 + threadIdx.x;
    if (e < E) {
        int d = dst[e];
        int pos = atomicAdd(&cursor[d], 1);
        csrc[pos] = src[e];
    }
}

// ------------------------------ GEMMs --------------------------------------
// h1[n, m] = sum_k x[n,k] * W1[k,m]    x: f32 [N,128], W1: f32 [128,256]
__global__ __launch_bounds__(256) void k_gemm1(const float* __restrict__ x,
                                               const float* __restrict__ W,
                                               float* __restrict__ h, int N) {
    __shared__ float xs[8][128];
    int tid = threadIdx.x;
    int n0 = blockIdx.x * 8;
    {   // 8 rows x 128 f32 = 1024 floats = 256 threads x float4
        int r = tid >> 5, c4 = tid & 31;  // c4: which float4 of the row
        int n = n0 + r;
        float4 v = make_float4(0.f, 0.f, 0.f, 0.f);
        if (n < N) v = reinterpret_cast<const float4*>(x + (size_t)n * 128)[c4];
        xs[r][c4 * 4 + 0] = v.x;
        xs[r][c4 * 4 + 1] = v.y;
        xs[r][c4 * 4 + 2] = v.z;
        xs[r][c4 * 4 + 3] = v.w;
    }
    __syncthreads();
    float acc[8] = {};
    for (int k = 0; k < 128; ++k) {
        float wk = W[k * 256 + tid];
#pragma unroll
        for (int r = 0; r < 8; ++r) acc[r] += xs[r][k] * wk;
    }
    for (int r = 0; r < 8; ++r) {
        int n = n0 + r;
        if (n < N) h[(size_t)n * 256 + tid] = acc[r];
    }
}

// h2[n, c] = sum_k x1[n,k] * W2[k,c]   x1: f32 [N,256], W2: f32 [256,32]
__global__ __launch_bounds__(256) void k_gemm2(const float* __restrict__ x1,
                                               const float* __restrict__ W2,
                                               float* __restrict__ h2, int N) {
    __shared__ float xs[8][256];
    int tid = threadIdx.x;
    int n0 = blockIdx.x * 8;
    {   // 8 rows x 256 f32 = 2048 floats = 256 threads x 2 float4
        int r = tid >> 5, c4 = tid & 31;
        int n = n0 + r;
        float4 a = make_float4(0.f, 0.f, 0.f, 0.f), b = a;
        if (n < N) {
            const float4* row = reinterpret_cast<const float4*>(x1 + (size_t)n * 256);
            a = row[c4];
            b = row[32 + c4];
        }
        xs[r][c4 * 4 + 0] = a.x; xs[r][c4 * 4 + 1] = a.y;
        xs[r][c4 * 4 + 2] = a.z; xs[r][c4 * 4 + 3] = a.w;
        xs[r][128 + c4 * 4 + 0] = b.x; xs[r][128 + c4 * 4 + 1] = b.y;
        xs[r][128 + c4 * 4 + 2] = b.z; xs[r][128 + c4 * 4 + 3] = b.w;
    }
    __syncthreads();
    int r = tid >> 5, c = tid & 31;
    int n = n0 + r;
    float acc = 0.f;
    for (int k = 0; k < 256; ++k) acc += xs[r][k] * W2[k * 32 + c];
    if (n < N) h2[(size_t)n * 32 + c] = acc;
}

// ------------------------- attention scores --------------------------------
// s[n,h] = sum_c h1[n, h*64+c] * a[h,c]   (one 64-lane wave per node)
__global__ __launch_bounds__(256) void k_scores1(const float* __restrict__ h,
                                                 const float* __restrict__ as,
                                                 const float* __restrict__ ad,
                                                 float* __restrict__ ssrc,
                                                 float* __restrict__ sdst, int N) {
    int n = (blockIdx.x * 256 + threadIdx.x) >> 6;
    int lane = threadIdx.x & 63;
    if (n >= N) return;
    for (int hh = 0; hh < 4; ++hh) {
        float v = h[(size_t)n * 256 + hh * 64 + lane];
        float ps = v * as[hh * 64 + lane];
        float pd = v * ad[hh * 64 + lane];
        for (int m = 32; m; m >>= 1) {
            ps += __shfl_xor(ps, m);
            pd += __shfl_xor(pd, m);
        }
        if (lane == 0) {
            ssrc[n * 4 + hh] = ps;
            sdst[n * 4 + hh] = pd;
        }
    }
}

// s2[n] = sum_c h2[n,c] * a2[c]  (32 lanes per node)
__global__ __launch_bounds__(256) void k_scores2(const float* __restrict__ h2,
                                                 const float* __restrict__ as,
                                                 const float* __restrict__ ad,
                                                 float* __restrict__ s2s,
                                                 float* __restrict__ s2d, int N) {
    int n = (blockIdx.x * 256 + threadIdx.x) >> 5;
    int l = threadIdx.x & 31;
    if (n >= N) return;
    float v = h2[(size_t)n * 32 + l];
    float ps = v * as[l];
    float pd = v * ad[l];
    for (int m = 16; m; m >>= 1) {
        ps += __shfl_xor(ps, m);
        pd += __shfl_xor(pd, m);
    }
    if (l == 0) {
        s2s[n] = ps;
        s2d[n] = pd;
    }
}

// ----------------------- edge-softmax aggregation --------------------------
// Layer 1: one wave per dst node, 4 heads x 64 ch. exp without max-shift
// (softmax shift-invariant; |e| <~ 11 so exp is f32-safe).
__global__ __launch_bounds__(256) void k_agg1(const int* __restrict__ rowptr,
                                              const int* __restrict__ csrc,
                                              const float* __restrict__ ssrc,
                                              const float* __restrict__ sdst,
                                              const float* __restrict__ h,
                                              const float* __restrict__ b1,
                                              const float* __restrict__ p1,
                                              float* __restrict__ x1, int N) {
    int n = (blockIdx.x * 256 + threadIdx.x) >> 6;
    int lane = threadIdx.x & 63;
    if (n >= N) return;
    float sd0 = sdst[n * 4 + 0], sd1 = sdst[n * 4 + 1];
    float sd2 = sdst[n * 4 + 2], sd3 = sdst[n * 4 + 3];
    int beg = rowptr[n], end = rowptr[n + 1];
    float a0 = 0, a1 = 0, a2 = 0, a3 = 0;
    float z0 = 0, z1 = 0, z2 = 0, z3 = 0;
    for (int j = beg; j < end; ++j) {
        int s = csrc[j];
        const float* sr = ssrc + (size_t)s * 4;
        float e0 = sr[0] + sd0, e1 = sr[1] + sd1, e2 = sr[2] + sd2, e3 = sr[3] + sd3;
        e0 = e0 > 0.f ? e0 : 0.2f * e0;
        e1 = e1 > 0.f ? e1 : 0.2f * e1;
        e2 = e2 > 0.f ? e2 : 0.2f * e2;
        e3 = e3 > 0.f ? e3 : 0.2f * e3;
        float q0 = __expf(e0), q1 = __expf(e1), q2 = __expf(e2), q3 = __expf(e3);
        z0 += q0; z1 += q1; z2 += q2; z3 += q3;
        const float* hr = h + (size_t)s * 256;
        a0 += q0 * hr[lane];
        a1 += q1 * hr[64 + lane];
        a2 += q2 * hr[128 + lane];
        a3 += q3 * hr[192 + lane];
    }
    float* xr = x1 + (size_t)n * 256;
    {
        int c = lane;
        float v = a0 / (z0 + 1e-16f) + b1[c];
        xr[c] = v > 0.f ? v : p1[c] * v;
        c = 64 + lane;
        v = a1 / (z1 + 1e-16f) + b1[c];
        xr[c] = v > 0.f ? v : p1[c] * v;
        c = 128 + lane;
        v = a2 / (z2 + 1e-16f) + b1[c];
        xr[c] = v > 0.f ? v : p1[c] * v;
        c = 192 + lane;
        v = a3 / (z3 + 1e-16f) + b1[c];
        xr[c] = v > 0.f ? v : p1[c] * v;
    }
}

// Layer 2: one wave per dst node, 1 head x 32 ch (upper 32 lanes duplicate).
__global__ __launch_bounds__(256) void k_agg2(const int* __restrict__ rowptr,
                                              const int* __restrict__ csrc,
                                              const float* __restrict__ s2s,
                                              const float* __restrict__ s2d,
                                              const float* __restrict__ h2,
                                              const float* __restrict__ b2,
                                              const float* __restrict__ p2,
                                              float* __restrict__ x2, int N) {
    int n = (blockIdx.x * 256 + threadIdx.x) >> 6;
    int lane = threadIdx.x & 63;
    if (n >= N) return;
    float sd = s2d[n];
    int beg = rowptr[n], end = rowptr[n + 1];
    float acc = 0.f, z = 0.f;
    int c = lane & 31;
    for (int j = beg; j < end; ++j) {
        int s = csrc[j];
        float e = s2s[s] + sd;
        e = e > 0.f ? e : 0.2f * e;
        float q = __expf(e);
        z += q;
        acc += q * h2[(size_t)s * 32 + c];
    }
    if (lane < 32) {
        float v = acc / (z + 1e-16f) + b2[c];
        x2[(size_t)n * 32 + c] = v > 0.f ? v : p2[c] * v;
    }
}

// ------------------------------- heads -------------------------------------
// q = l2norm(x2 @ Wp): 32 lanes per node
__global__ __launch_bounds__(256) void k_proj(const float* __restrict__ x2,
                                              const float* __restrict__ Wp,
                                              float* __restrict__ out, int N) {
    int n = (blockIdx.x * 256 + threadIdx.x) >> 5;
    int o = threadIdx.x & 31;
    if (n >= N) return;
    float acc = 0.f;
    for (int c = 0; c < 32; ++c) acc += x2[(size_t)n * 32 + c] * Wp[c * 32 + o];
    float s = acc * acc;
    for (int m = 16; m; m >>= 1) s += __shfl_xor(s, m);
    float q = acc / (sqrtf(s) + 1e-12f);
    out[(size_t)n * 32 + o] = q;
}

__global__ void k_wsum(const float* __restrict__ advw,
                       const float* __restrict__ advb,
                       float* __restrict__ wsum, float* __restrict__ bsum) {
    int c = threadIdx.x;  // 32 threads
    float s = 0.f;
    for (int j = 0; j < 32; ++j) s += advw[c * 32 + j];
    wsum[c] = s;
    float b = advb[c];
    for (int m = 16; m; m >>= 1) b += __shfl_xor(b, m);
    if (c == 0) bsum[0] = b;
}

// sc[n] = sum_c x2[n,c]*wsum[c] + bsum
__global__ __launch_bounds__(256) void k_adv(const float* __restrict__ x2,
                                             const float* __restrict__ wsum,
                                             const float* __restrict__ bsum,
                                             float* __restrict__ out, int N) {
    int n = (blockIdx.x * 256 + threadIdx.x) >> 5;
    int l = threadIdx.x & 31;
    if (n >= N) return;
    float v = x2[(size_t)n * 32 + l] * wsum[l];
    for (int m = 16; m; m >>= 1) v += __shfl_xor(v, m);
    if (l == 0) out[n] = v + bsum[0];
}

// Fusion decoder: one wave per pair (lanes 32-63 duplicate lanes 0-31)
__global__ __launch_bounds__(256) void k_fusion(const float* __restrict__ x2o,
                                                const int* __restrict__ idx,
                                                const float* __restrict__ Wf,
                                                const float* __restrict__ bfb,
                                                const float* __restrict__ Wlog,
                                                const float* __restrict__ blog,
                                                const float* __restrict__ Wlog1,
                                                const float* __restrict__ blog1,
                                                float* __restrict__ out_log,
                                                float* __restrict__ out_log1,
                                                int NB) {
    int i = (blockIdx.x * 256 + threadIdx.x) >> 6;
    int lane = threadIdx.x & 63;
    if (i >= NB) return;
    int o = lane & 31;
    int i1 = idx[i], i2 = idx[NB + i];
    float acc = bfb[o];
    for (int c = 0; c < 32; ++c) acc += x2o[(size_t)i1 * 32 + c] * Wf[c * 32 + o];
    for (int c = 0; c < 32; ++c) acc += x2o[(size_t)i2 * 32 + c] * Wf[(32 + c) * 32 + o];
    float h = acc > 0.f ? acc : 0.f;
    float v0 = h * Wlog[o];
    float v1 = h * Wlog1[o];
    for (int m = 16; m; m >>= 1) {
        v0 += __shfl_xor(v0, m);
        v1 += __shfl_xor(v1, m);
    }
    if (lane == 0) {
        out_log[i] = v0 + blog[0];
        out_log1[i] = v1 + blog1[0];
    }
}

__global__ void k_copy_f(const float* __restrict__ in, float* __restrict__ out, int n) {
    int i = blockIdx.x * 256 + threadIdx.x;
    if (i < n) out[i] = in[i];
}

// ---------------------------------------------------------------------------
extern "C" void kernel_launch(void* const* d_in, const int* in_sizes, int n_in,
                              void* d_out, int out_size, void* d_ws, size_t ws_size,
                              hipStream_t stream) {
    const float* x_o = (const float*)d_in[0];
    const float* x_a = (const float*)d_in[1];
    const float* W1 = (const float*)d_in[2];
    const float* a_src1 = (const float*)d_in[3];
    const float* a_dst1 = (const float*)d_in[4];
    const float* b1 = (const float*)d_in[5];
    const float* p1 = (const float*)d_in[6];
    const float* W2 = (const float*)d_in[7];
    const float* a_src2 = (const float*)d_in[8];
    const float* a_dst2 = (const float*)d_in[9];
    const float* b2 = (const float*)d_in[10];
    const float* p2 = (const float*)d_in[11];
    const float* adv_w = (const float*)d_in[12];
    const float* adv_b = (const float*)d_in[13];
    const float* Wq = (const float*)d_in[14];
    const float* Wk = (const float*)d_in[15];
    const float* Wf = (const float*)d_in[16];
    const float* bf_ = (const float*)d_in[17];
    const float* Wlog = (const float*)d_in[18];
    const float* blog = (const float*)d_in[19];
    const float* Wlog1 = (const float*)d_in[20];
    const float* blog1 = (const float*)d_in[21];
    const int* ei = (const int*)d_in[22];
    const int* idx = (const int*)d_in[23];

    const int N = in_sizes[0] / 128;
    const int E = in_sizes[22] / 2;
    const int NB = in_sizes[23] / 2;
    const int* esrc = ei;
    const int* edst = ei + E;

    char* ws = (char*)d_ws;
    size_t off = 0;
    auto alloc = [&](size_t bytes) -> void* {
        void* p = ws + off;
        off += (bytes + 255) & ~(size_t)255;
        return p;
    };
    float* h1 = (float*)alloc((size_t)N * 256 * 4);
    float* x1 = (float*)alloc((size_t)N * 256 * 4);
    float* h2 = (float*)alloc((size_t)N * 32 * 4);
    float* x2o = (float*)alloc((size_t)N * 32 * 4);
    float* x2a = (float*)alloc((size_t)N * 32 * 4);
    float* ssrc = (float*)alloc((size_t)N * 4 * 4);
    float* sdst = (float*)alloc((size_t)N * 4 * 4);
    float* s2s = (float*)alloc((size_t)N * 4);
    float* s2d = (float*)alloc((size_t)N * 4);
    int* rowptr = (int*)alloc((size_t)(N + 1) * 4);
    int* cursor = (int*)alloc((size_t)N * 4);
    int* csrc = (int*)alloc((size_t)E * 4);
    float* wsum = (float*)alloc(32 * 4);
    float* bsum = (float*)alloc(4);

    // --- CSR build (shared by both encodes / both layers) ---
    k_zero_i<<<(N + 255) / 256, 256, 0, stream>>>(cursor, N);
    k_count<<<(E + 255) / 256, 256, 0, stream>>>(edst, E, cursor);
    k_scan<<<1, 1024, 0, stream>>>(cursor, rowptr, N, E);
    k_copy_i<<<(N + 255) / 256, 256, 0, stream>>>(rowptr, cursor, N);
    k_fill<<<(E + 255) / 256, 256, 0, stream>>>(esrc, edst, E, cursor, csrc);

    // --- two encodes ---
    for (int pass = 0; pass < 2; ++pass) {
        const float* xin = (pass == 0) ? x_o : x_a;
        float* x2 = (pass == 0) ? x2o : x2a;
        k_gemm1<<<(N + 7) / 8, 256, 0, stream>>>(xin, W1, h1, N);
        k_scores1<<<(N + 3) / 4, 256, 0, stream>>>(h1, a_src1, a_dst1, ssrc, sdst, N);
        k_agg1<<<(N + 3) / 4, 256, 0, stream>>>(rowptr, csrc, ssrc, sdst, h1, b1, p1, x1, N);
        k_gemm2<<<(N + 7) / 8, 256, 0, stream>>>(x1, W2, h2, N);
        k_scores2<<<(N + 7) / 8, 256, 0, stream>>>(h2, a_src2, a_dst2, s2s, s2d, N);
        k_agg2<<<(N + 3) / 4, 256, 0, stream>>>(rowptr, csrc, s2s, s2d, h2, b2, p2, x2, N);
    }

    // --- output heads ---
    float* out = (float*)d_out;
    float* o_log = out;                        // [NB]
    float* o_q = o_log + NB;                   // [N*32]
    float* o_k = o_q + (size_t)N * 32;         // [N*32]
    float* o_x2 = o_k + (size_t)N * 32;        // [N*32]
    float* o_logits = o_x2 + (size_t)N * 32;   // [2N]
    float* o_log1 = o_logits + (size_t)2 * N;  // [NB]

    k_proj<<<(N + 7) / 8, 256, 0, stream>>>(x2o, Wq, o_q, N);
    k_proj<<<(N + 7) / 8, 256, 0, stream>>>(x2a, Wk, o_k, N);
    k_copy_f<<<(N * 32 + 255) / 256, 256, 0, stream>>>(x2o, o_x2, N * 32);
    k_wsum<<<1, 32, 0, stream>>>(adv_w, adv_b, wsum, bsum);
    k_adv<<<(N + 7) / 8, 256, 0, stream>>>(x2o, wsum, bsum, o_logits, N);
    k_adv<<<(N + 7) / 8, 256, 0, stream>>>(x2a, wsum, bsum, o_logits + N, N);
    k_fusion<<<(NB + 3) / 4, 256, 0, stream>>>(x2o, idx, Wf, bf_, Wlog, blog, Wlog1, blog1,
                                               o_log, o_log1, NB);
}

// Round 3
// 758.513 us; speedup vs baseline: 1.2251x; 1.2251x over previous
//
#include <hip/hip_runtime.h>
#include <hip/hip_bf16.h>
#include <hip/hip_fp16.h>

// ---------------------------------------------------------------------------
// GATEncoder on MI355X. Structure:
//   CSR-by-dst built once (hierarchical scan, no serial block);
//   gemm1 (16 rows/blk, f32) -> fp16 h1 payload + fused attention scores;
//   agg1: wave/node, 8B/lane fp16 gather (512B/row), shift-invariant softmax;
//   gemm2 (+fused scores2); agg2: 2 nodes/wave; fused heads kernel.
// Precision: payload fp16 (rel 2^-11) only on the gathered h1; all math f32.
// ---------------------------------------------------------------------------

// ------------------------------ CSR build ----------------------------------
__global__ void k_zero_i(int* __restrict__ p, int n) {
    int i = blockIdx.x * 256 + threadIdx.x;
    if (i < n) p[i] = 0;
}

__global__ void k_count(const int* __restrict__ dst, int E, int* __restrict__ cnt) {
    int e = blockIdx.x * 256 + threadIdx.x;
    if (e < E) atomicAdd(&cnt[dst[e]], 1);
}

// local exclusive scan of 256 counts per block; block totals to bsums
__global__ __launch_bounds__(256) void k_scan_local(const int* __restrict__ cnt,
                                                    int* __restrict__ rowptr,
                                                    int* __restrict__ bsums, int N) {
    __shared__ int t[256];
    int tid = threadIdx.x;
    int i = blockIdx.x * 256 + tid;
    int v = (i < N) ? cnt[i] : 0;
    t[tid] = v;
    __syncthreads();
    for (int off = 1; off < 256; off <<= 1) {
        int u = (tid >= off) ? t[tid - off] : 0;
        __syncthreads();
        t[tid] += u;
        __syncthreads();
    }
    if (i < N) rowptr[i] = t[tid] - v;  // exclusive within block
    if (tid == 255) bsums[blockIdx.x] = t[255];
}

// exclusive scan of up to 256 block sums (G<=256)
__global__ __launch_bounds__(256) void k_scan_bsums(int* __restrict__ bsums, int G) {
    __shared__ int t[256];
    int tid = threadIdx.x;
    int v = (tid < G) ? bsums[tid] : 0;
    t[tid] = v;
    __syncthreads();
    for (int off = 1; off < 256; off <<= 1) {
        int u = (tid >= off) ? t[tid - off] : 0;
        __syncthreads();
        t[tid] += u;
        __syncthreads();
    }
    if (tid < G) bsums[tid] = t[tid] - v;  // exclusive
}

// apply block offsets; also produce cursor copy and rowptr[N]=E
__global__ __launch_bounds__(256) void k_scan_apply(int* __restrict__ rowptr,
                                                    const int* __restrict__ bsums,
                                                    int* __restrict__ cursor, int N, int E) {
    int i = blockIdx.x * 256 + threadIdx.x;
    if (i < N) {
        int r = rowptr[i] + bsums[blockIdx.x];
        rowptr[i] = r;
        cursor[i] = r;
    }
    if (i == 0) rowptr[N] = E;
}

__global__ void k_fill(const int* __restrict__ src, const int* __restrict__ dst, int E,
                       int* __restrict__ cursor, int* __restrict__ csrc) {
    int e = blockIdx.x * 256 + threadIdx.x;
    if (e < E) {
        int d = dst[e];
        int pos = atomicAdd(&cursor[d], 1);
        csrc[pos] = src[e];
    }
}

// --------------------------- layer-1 GEMM + scores -------------------------
// h1h[n,m](fp16) = x[n,:] @ W1[:,m];  ssrc/sdst[n,h] = <h1[n,h,:], a_{s,d}[h,:]>
// 16 rows/block, 256 threads (thread = output column), wave w == head w.
__global__ __launch_bounds__(256) void k_gemm1(const float* __restrict__ x,
                                               const float* __restrict__ W,
                                               const float* __restrict__ as1,
                                               const float* __restrict__ ad1,
                                               __half* __restrict__ h1h,
                                               float* __restrict__ ssrc,
                                               float* __restrict__ sdst, int N) {
    __shared__ float xs[16][128];
    int tid = threadIdx.x;
    int n0 = blockIdx.x * 16;
    // stage 16 rows x 128 = 512 float4, 2 per thread
    for (int i = tid; i < 16 * 32; i += 256) {
        int r = i >> 5, c4 = i & 31;
        int n = n0 + r;
        float4 v = make_float4(0.f, 0.f, 0.f, 0.f);
        if (n < N) v = reinterpret_cast<const float4*>(x + (size_t)n * 128)[c4];
        *reinterpret_cast<float4*>(&xs[r][c4 * 4]) = v;
    }
    __syncthreads();
    float acc[16] = {};
    for (int k4 = 0; k4 < 32; ++k4) {
        float w0 = W[(k4 * 4 + 0) * 256 + tid];
        float w1 = W[(k4 * 4 + 1) * 256 + tid];
        float w2 = W[(k4 * 4 + 2) * 256 + tid];
        float w3 = W[(k4 * 4 + 3) * 256 + tid];
#pragma unroll
        for (int r = 0; r < 16; ++r) {
            float4 xv = *reinterpret_cast<const float4*>(&xs[r][k4 * 4]);
            acc[r] += xv.x * w0 + xv.y * w1 + xv.z * w2 + xv.w * w3;
        }
    }
    float a_s = as1[tid], a_d = ad1[tid];
    int w = tid >> 6, lane = tid & 63;
#pragma unroll
    for (int r = 0; r < 16; ++r) {
        int n = n0 + r;
        if (n < N) h1h[(size_t)n * 256 + tid] = __float2half(acc[r]);
        float ps = acc[r] * a_s, pd = acc[r] * a_d;
        for (int m = 32; m; m >>= 1) {
            ps += __shfl_xor(ps, m);
            pd += __shfl_xor(pd, m);
        }
        if (lane == 0 && n < N) {
            ssrc[n * 4 + w] = ps;
            sdst[n * 4 + w] = pd;
        }
    }
}

// ------------------------- layer-1 edge aggregation ------------------------
// One wave per dst node. Lane l owns channels 4l..4l+3 (head = l>>4).
// Per edge: 16B ssrc broadcast + 8B/lane fp16 row (512B/wave), 1 exp/lane.
__global__ __launch_bounds__(256) void k_agg1(const int* __restrict__ rowptr,
                                              const int* __restrict__ csrc,
                                              const float* __restrict__ ssrc,
                                              const float* __restrict__ sdst,
                                              const __half* __restrict__ h1h,
                                              const float* __restrict__ b1,
                                              const float* __restrict__ p1,
                                              float* __restrict__ x1, int N) {
    int n = (blockIdx.x * 256 + threadIdx.x) >> 6;
    int lane = threadIdx.x & 63;
    if (n >= N) return;
    int hs = lane >> 4;
    float4 sd4 = reinterpret_cast<const float4*>(sdst)[n];
    float sdh = hs == 0 ? sd4.x : hs == 1 ? sd4.y : hs == 2 ? sd4.z : sd4.w;
    int beg = rowptr[n], end = rowptr[n + 1];
    float ax = 0.f, ay = 0.f, az = 0.f, aw = 0.f, z = 0.f;
    for (int j = beg; j < end; ++j) {
        int s = csrc[j];
        float4 ss4 = reinterpret_cast<const float4*>(ssrc)[s];
        float ssh = hs == 0 ? ss4.x : hs == 1 ? ss4.y : hs == 2 ? ss4.z : ss4.w;
        float e = ssh + sdh;
        e = e > 0.f ? e : 0.2f * e;
        float q = __expf(e);
        z += q;
        uint2 u = reinterpret_cast<const uint2*>(h1h + (size_t)s * 256)[lane];
        __half2 p0 = *reinterpret_cast<__half2*>(&u.x);
        __half2 p1v = *reinterpret_cast<__half2*>(&u.y);
        float2 f0 = __half22float2(p0);
        float2 f1 = __half22float2(p1v);
        ax += q * f0.x;
        ay += q * f0.y;
        az += q * f1.x;
        aw += q * f1.y;
    }
    float rz = 1.f / (z + 1e-16f);
    float4 bb = reinterpret_cast<const float4*>(b1)[lane];
    float4 pp = reinterpret_cast<const float4*>(p1)[lane];
    float4 v;
    v.x = ax * rz + bb.x;
    v.y = ay * rz + bb.y;
    v.z = az * rz + bb.z;
    v.w = aw * rz + bb.w;
    v.x = v.x > 0.f ? v.x : pp.x * v.x;
    v.y = v.y > 0.f ? v.y : pp.y * v.y;
    v.z = v.z > 0.f ? v.z : pp.z * v.z;
    v.w = v.w > 0.f ? v.w : pp.w * v.w;
    reinterpret_cast<float4*>(x1 + (size_t)n * 256)[lane] = v;
}

// --------------------------- layer-2 GEMM + scores -------------------------
// h2[n,c] = x1[n,:] @ W2[:,c]; s2s/s2d fused (32-lane group reduce).
__global__ __launch_bounds__(256) void k_gemm2(const float* __restrict__ x1,
                                               const float* __restrict__ W2,
                                               const float* __restrict__ as2,
                                               const float* __restrict__ ad2,
                                               float* __restrict__ h2,
                                               float* __restrict__ s2s,
                                               float* __restrict__ s2d, int N) {
    __shared__ float xs[8][256];
    int tid = threadIdx.x;
    int n0 = blockIdx.x * 8;
    for (int i = tid; i < 8 * 64; i += 256) {
        int r = i >> 6, c4 = i & 63;
        int n = n0 + r;
        float4 v = make_float4(0.f, 0.f, 0.f, 0.f);
        if (n < N) v = reinterpret_cast<const float4*>(x1 + (size_t)n * 256)[c4];
        *reinterpret_cast<float4*>(&xs[r][c4 * 4]) = v;
    }
    __syncthreads();
    int r = tid >> 5, c = tid & 31;
    int n = n0 + r;
    float acc = 0.f;
    for (int k4 = 0; k4 < 64; ++k4) {
        float4 xv = *reinterpret_cast<const float4*>(&xs[r][k4 * 4]);
        acc += xv.x * W2[(k4 * 4 + 0) * 32 + c] + xv.y * W2[(k4 * 4 + 1) * 32 + c] +
               xv.z * W2[(k4 * 4 + 2) * 32 + c] + xv.w * W2[(k4 * 4 + 3) * 32 + c];
    }
    if (n < N) h2[(size_t)n * 32 + c] = acc;
    float ps = acc * as2[c], pd = acc * ad2[c];
    for (int m = 16; m; m >>= 1) {
        ps += __shfl_xor(ps, m);
        pd += __shfl_xor(pd, m);
    }
    if (c == 0 && n < N) {
        s2s[n] = ps;
        s2d[n] = pd;
    }
}

// ------------------------- layer-2 edge aggregation ------------------------
// 32-lane group per dst node (2 nodes per wave).
__global__ __launch_bounds__(256) void k_agg2(const int* __restrict__ rowptr,
                                              const int* __restrict__ csrc,
                                              const float* __restrict__ s2s,
                                              const float* __restrict__ s2d,
                                              const float* __restrict__ h2,
                                              const float* __restrict__ b2,
                                              const float* __restrict__ p2,
                                              float* __restrict__ x2, int N) {
    int n = (blockIdx.x * 256 + threadIdx.x) >> 5;
    int c = threadIdx.x & 31;
    if (n >= N) return;
    float sd = s2d[n];
    int beg = rowptr[n], end = rowptr[n + 1];
    float acc = 0.f, z = 0.f;
    for (int j = beg; j < end; ++j) {
        int s = csrc[j];
        float e = s2s[s] + sd;
        e = e > 0.f ? e : 0.2f * e;
        float q = __expf(e);
        z += q;
        acc += q * h2[(size_t)s * 32 + c];
    }
    float v = acc / (z + 1e-16f) + b2[c];
    x2[(size_t)n * 32 + c] = v > 0.f ? v : p2[c] * v;
}

// ------------------------------- heads -------------------------------------
__global__ void k_wsum(const float* __restrict__ advw, const float* __restrict__ advb,
                       float* __restrict__ wsum, float* __restrict__ bsum) {
    int c = threadIdx.x;  // 32 threads
    float s = 0.f;
    for (int j = 0; j < 32; ++j) s += advw[c * 32 + j];
    wsum[c] = s;
    float b = advb[c];
    for (int m = 16; m; m >>= 1) b += __shfl_xor(b, m);
    if (c == 0) bsum[0] = b;
}

// per node (32-lane group): q = l2n(x2o@Wq), k = l2n(x2a@Wk), x2 copy, adv sums
__global__ __launch_bounds__(256) void k_heads(const float* __restrict__ x2o,
                                               const float* __restrict__ x2a,
                                               const float* __restrict__ Wq,
                                               const float* __restrict__ Wk,
                                               const float* __restrict__ wsum,
                                               const float* __restrict__ bsum,
                                               float* __restrict__ o_q,
                                               float* __restrict__ o_k,
                                               float* __restrict__ o_x2,
                                               float* __restrict__ o_logits, int N) {
    int n = (blockIdx.x * 256 + threadIdx.x) >> 5;
    int o = threadIdx.x & 31;
    if (n >= N) return;
    float xo = x2o[(size_t)n * 32 + o];
    float xa = x2a[(size_t)n * 32 + o];
    float accq = 0.f, acck = 0.f;
    for (int c = 0; c < 32; ++c) {
        float xoc = __shfl(xo, c, 32);
        float xac = __shfl(xa, c, 32);
        accq += xoc * Wq[c * 32 + o];
        acck += xac * Wk[c * 32 + o];
    }
    float sq = accq * accq, sk = acck * acck;
    for (int m = 16; m; m >>= 1) {
        sq += __shfl_xor(sq, m);
        sk += __shfl_xor(sk, m);
    }
    o_q[(size_t)n * 32 + o] = accq / (sqrtf(sq) + 1e-12f);
    o_k[(size_t)n * 32 + o] = acck / (sqrtf(sk) + 1e-12f);
    o_x2[(size_t)n * 32 + o] = xo;
    float vo = xo * wsum[o], va = xa * wsum[o];
    for (int m = 16; m; m >>= 1) {
        vo += __shfl_xor(vo, m);
        va += __shfl_xor(va, m);
    }
    if (o == 0) {
        o_logits[n] = vo + bsum[0];
        o_logits[N + n] = va + bsum[0];
    }
}

// Fusion decoder: 32-lane group per pair
__global__ __launch_bounds__(256) void k_fusion(const float* __restrict__ x2o,
                                                const int* __restrict__ idx,
                                                const float* __restrict__ Wf,
                                                const float* __restrict__ bfb,
                                                const float* __restrict__ Wlog,
                                                const float* __restrict__ blog,
                                                const float* __restrict__ Wlog1,
                                                const float* __restrict__ blog1,
                                                float* __restrict__ out_log,
                                                float* __restrict__ out_log1, int NB) {
    int i = (blockIdx.x * 256 + threadIdx.x) >> 5;
    int o = threadIdx.x & 31;
    if (i >= NB) return;
    int i1 = idx[i], i2 = idx[NB + i];
    float e1 = x2o[(size_t)i1 * 32 + o];
    float e2 = x2o[(size_t)i2 * 32 + o];
    float acc = bfb[o];
    for (int c = 0; c < 32; ++c) {
        acc += __shfl(e1, c, 32) * Wf[c * 32 + o];
        acc += __shfl(e2, c, 32) * Wf[(32 + c) * 32 + o];
    }
    float h = acc > 0.f ? acc : 0.f;
    float v0 = h * Wlog[o];
    float v1 = h * Wlog1[o];
    for (int m = 16; m; m >>= 1) {
        v0 += __shfl_xor(v0, m);
        v1 += __shfl_xor(v1, m);
    }
    if (o == 0) {
        out_log[i] = v0 + blog[0];
        out_log1[i] = v1 + blog1[0];
    }
}

// ---------------------------------------------------------------------------
extern "C" void kernel_launch(void* const* d_in, const int* in_sizes, int n_in,
                              void* d_out, int out_size, void* d_ws, size_t ws_size,
                              hipStream_t stream) {
    const float* x_o = (const float*)d_in[0];
    const float* x_a = (const float*)d_in[1];
    const float* W1 = (const float*)d_in[2];
    const float* a_src1 = (const float*)d_in[3];
    const float* a_dst1 = (const float*)d_in[4];
    const float* b1 = (const float*)d_in[5];
    const float* p1 = (const float*)d_in[6];
    const float* W2 = (const float*)d_in[7];
    const float* a_src2 = (const float*)d_in[8];
    const float* a_dst2 = (const float*)d_in[9];
    const float* b2 = (const float*)d_in[10];
    const float* p2 = (const float*)d_in[11];
    const float* adv_w = (const float*)d_in[12];
    const float* adv_b = (const float*)d_in[13];
    const float* Wq = (const float*)d_in[14];
    const float* Wk = (const float*)d_in[15];
    const float* Wf = (const float*)d_in[16];
    const float* bf_ = (const float*)d_in[17];
    const float* Wlog = (const float*)d_in[18];
    const float* blog = (const float*)d_in[19];
    const float* Wlog1 = (const float*)d_in[20];
    const float* blog1 = (const float*)d_in[21];
    const int* ei = (const int*)d_in[22];
    const int* idx = (const int*)d_in[23];

    const int N = in_sizes[0] / 128;
    const int E = in_sizes[22] / 2;
    const int NB = in_sizes[23] / 2;
    const int* esrc = ei;
    const int* edst = ei + E;
    const int GS = (N + 255) / 256;  // scan blocks (196 <= 256)

    char* ws = (char*)d_ws;
    size_t off = 0;
    auto alloc = [&](size_t bytes) -> void* {
        void* p = ws + off;
        off += (bytes + 255) & ~(size_t)255;
        return p;
    };
    __half* h1h = (__half*)alloc((size_t)N * 256 * 2);
    float* x1 = (float*)alloc((size_t)N * 256 * 4);
    float* h2 = (float*)alloc((size_t)N * 32 * 4);
    float* x2o = (float*)alloc((size_t)N * 32 * 4);
    float* x2a = (float*)alloc((size_t)N * 32 * 4);
    float* ssrc = (float*)alloc((size_t)N * 4 * 4);
    float* sdst = (float*)alloc((size_t)N * 4 * 4);
    float* s2s = (float*)alloc((size_t)N * 4);
    float* s2d = (float*)alloc((size_t)N * 4);
    int* rowptr = (int*)alloc((size_t)(N + 1) * 4);
    int* cursor = (int*)alloc((size_t)N * 4);
    int* bsums = (int*)alloc(256 * 4);
    int* csrc = (int*)alloc((size_t)E * 4);
    float* wsum = (float*)alloc(32 * 4);
    float* bsum = (float*)alloc(4);

    // --- CSR build ---
    k_zero_i<<<GS, 256, 0, stream>>>(cursor, N);  // cursor used as counts first
    k_count<<<(E + 255) / 256, 256, 0, stream>>>(edst, E, cursor);
    k_scan_local<<<GS, 256, 0, stream>>>(cursor, rowptr, bsums, N);
    k_scan_bsums<<<1, 256, 0, stream>>>(bsums, GS);
    k_scan_apply<<<GS, 256, 0, stream>>>(rowptr, bsums, cursor, N, E);
    k_fill<<<(E + 255) / 256, 256, 0, stream>>>(esrc, edst, E, cursor, csrc);

    // --- two encodes ---
    for (int pass = 0; pass < 2; ++pass) {
        const float* xin = (pass == 0) ? x_o : x_a;
        float* x2 = (pass == 0) ? x2o : x2a;
        k_gemm1<<<(N + 15) / 16, 256, 0, stream>>>(xin, W1, a_src1, a_dst1, h1h, ssrc, sdst, N);
        k_agg1<<<(N + 3) / 4, 256, 0, stream>>>(rowptr, csrc, ssrc, sdst, h1h, b1, p1, x1, N);
        k_gemm2<<<(N + 7) / 8, 256, 0, stream>>>(x1, W2, a_src2, a_dst2, h2, s2s, s2d, N);
        k_agg2<<<(N + 7) / 8, 256, 0, stream>>>(rowptr, csrc, s2s, s2d, h2, b2, p2, x2, N);
    }

    // --- output heads ---
    float* out = (float*)d_out;
    float* o_log = out;                        // [NB]
    float* o_q = o_log + NB;                   // [N*32]
    float* o_k = o_q + (size_t)N * 32;         // [N*32]
    float* o_x2 = o_k + (size_t)N * 32;        // [N*32]
    float* o_logits = o_x2 + (size_t)N * 32;   // [2N]
    float* o_log1 = o_logits + (size_t)2 * N;  // [NB]

    k_wsum<<<1, 32, 0, stream>>>(adv_w, adv_b, wsum, bsum);
    k_heads<<<(N + 7) / 8, 256, 0, stream>>>(x2o, x2a, Wq, Wk, wsum, bsum,
                                             o_q, o_k, o_x2, o_logits, N);
    k_fusion<<<(NB + 7) / 8, 256, 0, stream>>>(x2o, idx, Wf, bf_, Wlog, blog, Wlog1, blog1,
                                               o_log, o_log1, NB);
}

// Round 4
// 614.867 us; speedup vs baseline: 1.5113x; 1.2336x over previous
//
#include <hip/hip_runtime.h>
#include <hip/hip_bf16.h>
#include <hip/hip_fp16.h>

// ---------------------------------------------------------------------------
// GATEncoder on MI355X.
//   CSR-by-dst built once (hierarchical scan);
//   gemm1 -> fp16 h1 payload + fused attention scores;
//   k_eq*: edge-parallel exp(leaky(score)) precompute (breaks the latency
//          chain that pinned agg kernels at ~2200 cyc/edge in R3);
//   agg1/agg2: 4x-unrolled independent gathers (ILP), shift-invariant softmax.
// ---------------------------------------------------------------------------

// ------------------------------ CSR build ----------------------------------
__global__ void k_zero_i(int* __restrict__ p, int n) {
    int i = blockIdx.x * 256 + threadIdx.x;
    if (i < n) p[i] = 0;
}

__global__ void k_count(const int* __restrict__ dst, int E, int* __restrict__ cnt) {
    int e = blockIdx.x * 256 + threadIdx.x;
    if (e < E) atomicAdd(&cnt[dst[e]], 1);
}

__global__ __launch_bounds__(256) void k_scan_local(const int* __restrict__ cnt,
                                                    int* __restrict__ rowptr,
                                                    int* __restrict__ bsums, int N) {
    __shared__ int t[256];
    int tid = threadIdx.x;
    int i = blockIdx.x * 256 + tid;
    int v = (i < N) ? cnt[i] : 0;
    t[tid] = v;
    __syncthreads();
    for (int off = 1; off < 256; off <<= 1) {
        int u = (tid >= off) ? t[tid - off] : 0;
        __syncthreads();
        t[tid] += u;
        __syncthreads();
    }
    if (i < N) rowptr[i] = t[tid] - v;  // exclusive within block
    if (tid == 255) bsums[blockIdx.x] = t[255];
}

__global__ __launch_bounds__(256) void k_scan_bsums(int* __restrict__ bsums, int G) {
    __shared__ int t[256];
    int tid = threadIdx.x;
    int v = (tid < G) ? bsums[tid] : 0;
    t[tid] = v;
    __syncthreads();
    for (int off = 1; off < 256; off <<= 1) {
        int u = (tid >= off) ? t[tid - off] : 0;
        __syncthreads();
        t[tid] += u;
        __syncthreads();
    }
    if (tid < G) bsums[tid] = t[tid] - v;  // exclusive
}

__global__ __launch_bounds__(256) void k_scan_apply(int* __restrict__ rowptr,
                                                    const int* __restrict__ bsums,
                                                    int* __restrict__ cursor, int N, int E) {
    int i = blockIdx.x * 256 + threadIdx.x;
    if (i < N) {
        int r = rowptr[i] + bsums[blockIdx.x];
        rowptr[i] = r;
        cursor[i] = r;
    }
    if (i == 0) rowptr[N] = E;
}

__global__ void k_fill(const int* __restrict__ src, const int* __restrict__ dst, int E,
                       int* __restrict__ cursor, int* __restrict__ csrc,
                       int* __restrict__ cdst) {
    int e = blockIdx.x * 256 + threadIdx.x;
    if (e < E) {
        int d = dst[e];
        int pos = atomicAdd(&cursor[d], 1);
        csrc[pos] = src[e];
        cdst[pos] = d;
    }
}

// --------------------------- layer-1 GEMM + scores -------------------------
__global__ __launch_bounds__(256) void k_gemm1(const float* __restrict__ x,
                                               const float* __restrict__ W,
                                               const float* __restrict__ as1,
                                               const float* __restrict__ ad1,
                                               __half* __restrict__ h1h,
                                               float* __restrict__ ssrc,
                                               float* __restrict__ sdst, int N) {
    __shared__ float xs[16][128];
    int tid = threadIdx.x;
    int n0 = blockIdx.x * 16;
    for (int i = tid; i < 16 * 32; i += 256) {
        int r = i >> 5, c4 = i & 31;
        int n = n0 + r;
        float4 v = make_float4(0.f, 0.f, 0.f, 0.f);
        if (n < N) v = reinterpret_cast<const float4*>(x + (size_t)n * 128)[c4];
        *reinterpret_cast<float4*>(&xs[r][c4 * 4]) = v;
    }
    __syncthreads();
    float acc[16] = {};
    for (int k4 = 0; k4 < 32; ++k4) {
        float w0 = W[(k4 * 4 + 0) * 256 + tid];
        float w1 = W[(k4 * 4 + 1) * 256 + tid];
        float w2 = W[(k4 * 4 + 2) * 256 + tid];
        float w3 = W[(k4 * 4 + 3) * 256 + tid];
#pragma unroll
        for (int r = 0; r < 16; ++r) {
            float4 xv = *reinterpret_cast<const float4*>(&xs[r][k4 * 4]);
            acc[r] += xv.x * w0 + xv.y * w1 + xv.z * w2 + xv.w * w3;
        }
    }
    float a_s = as1[tid], a_d = ad1[tid];
    int w = tid >> 6, lane = tid & 63;
#pragma unroll
    for (int r = 0; r < 16; ++r) {
        int n = n0 + r;
        if (n < N) h1h[(size_t)n * 256 + tid] = __float2half(acc[r]);
        float ps = acc[r] * a_s, pd = acc[r] * a_d;
        for (int m = 32; m; m >>= 1) {
            ps += __shfl_xor(ps, m);
            pd += __shfl_xor(pd, m);
        }
        if (lane == 0 && n < N) {
            ssrc[n * 4 + w] = ps;
            sdst[n * 4 + w] = pd;
        }
    }
}

// --------------------- edge-parallel score precompute ----------------------
// q4[j] = exp(leaky(ssrc4[csrc[j]] + sdst4[cdst[j]])): coalesced in j,
// random 16B gathers hit the 800KB score arrays in L2; TLP hides latency.
__global__ __launch_bounds__(256) void k_eq1(const int* __restrict__ csrc,
                                             const int* __restrict__ cdst,
                                             const float* __restrict__ ssrc,
                                             const float* __restrict__ sdst,
                                             float4* __restrict__ q4, int E) {
    int j = blockIdx.x * 256 + threadIdx.x;
    if (j >= E) return;
    int s = csrc[j], d = cdst[j];
    float4 a = reinterpret_cast<const float4*>(ssrc)[s];
    float4 b = reinterpret_cast<const float4*>(sdst)[d];
    float4 e;
    e.x = a.x + b.x; e.y = a.y + b.y; e.z = a.z + b.z; e.w = a.w + b.w;
    e.x = e.x > 0.f ? e.x : 0.2f * e.x;
    e.y = e.y > 0.f ? e.y : 0.2f * e.y;
    e.z = e.z > 0.f ? e.z : 0.2f * e.z;
    e.w = e.w > 0.f ? e.w : 0.2f * e.w;
    e.x = __expf(e.x); e.y = __expf(e.y); e.z = __expf(e.z); e.w = __expf(e.w);
    q4[j] = e;
}

__global__ __launch_bounds__(256) void k_eq2(const int* __restrict__ csrc,
                                             const int* __restrict__ cdst,
                                             const float* __restrict__ s2s,
                                             const float* __restrict__ s2d,
                                             float* __restrict__ q2, int E) {
    int j = blockIdx.x * 256 + threadIdx.x;
    if (j >= E) return;
    float e = s2s[csrc[j]] + s2d[cdst[j]];
    e = e > 0.f ? e : 0.2f * e;
    q2[j] = __expf(e);
}

// ------------------------- layer-1 edge aggregation ------------------------
// Wave per dst node; lane owns ch 4l..4l+3 (head = l>>4). 4x unroll: 4
// independent h1h row gathers in flight per chunk. Branches are wave-uniform.
__global__ __launch_bounds__(256) void k_agg1(const int* __restrict__ rowptr,
                                              const int* __restrict__ csrc,
                                              const float4* __restrict__ q4,
                                              const __half* __restrict__ h1h,
                                              const float* __restrict__ b1,
                                              const float* __restrict__ p1,
                                              float* __restrict__ x1, int N) {
    int n = (blockIdx.x * 256 + threadIdx.x) >> 6;
    int lane = threadIdx.x & 63;
    if (n >= N) return;
    int hs = lane >> 4;
    int beg = rowptr[n], end = rowptr[n + 1];
    float ax = 0.f, ay = 0.f, az = 0.f, aw = 0.f, z = 0.f;
    int j = beg;
    for (; j + 4 <= end; j += 4) {
        int s0 = csrc[j], s1 = csrc[j + 1], s2 = csrc[j + 2], s3 = csrc[j + 3];
        float4 qa = q4[j], qb = q4[j + 1], qc = q4[j + 2], qd = q4[j + 3];
        float q0 = hs == 0 ? qa.x : hs == 1 ? qa.y : hs == 2 ? qa.z : qa.w;
        float q1 = hs == 0 ? qb.x : hs == 1 ? qb.y : hs == 2 ? qb.z : qb.w;
        float q2 = hs == 0 ? qc.x : hs == 1 ? qc.y : hs == 2 ? qc.z : qc.w;
        float q3 = hs == 0 ? qd.x : hs == 1 ? qd.y : hs == 2 ? qd.z : qd.w;
        uint2 u0 = reinterpret_cast<const uint2*>(h1h + (size_t)s0 * 256)[lane];
        uint2 u1 = reinterpret_cast<const uint2*>(h1h + (size_t)s1 * 256)[lane];
        uint2 u2 = reinterpret_cast<const uint2*>(h1h + (size_t)s2 * 256)[lane];
        uint2 u3 = reinterpret_cast<const uint2*>(h1h + (size_t)s3 * 256)[lane];
        z += q0 + q1 + q2 + q3;
        float2 f0a = __half22float2(*reinterpret_cast<__half2*>(&u0.x));
        float2 f0b = __half22float2(*reinterpret_cast<__half2*>(&u0.y));
        float2 f1a = __half22float2(*reinterpret_cast<__half2*>(&u1.x));
        float2 f1b = __half22float2(*reinterpret_cast<__half2*>(&u1.y));
        float2 f2a = __half22float2(*reinterpret_cast<__half2*>(&u2.x));
        float2 f2b = __half22float2(*reinterpret_cast<__half2*>(&u2.y));
        float2 f3a = __half22float2(*reinterpret_cast<__half2*>(&u3.x));
        float2 f3b = __half22float2(*reinterpret_cast<__half2*>(&u3.y));
        ax += q0 * f0a.x + q1 * f1a.x + q2 * f2a.x + q3 * f3a.x;
        ay += q0 * f0a.y + q1 * f1a.y + q2 * f2a.y + q3 * f3a.y;
        az += q0 * f0b.x + q1 * f1b.x + q2 * f2b.x + q3 * f3b.x;
        aw += q0 * f0b.y + q1 * f1b.y + q2 * f2b.y + q3 * f3b.y;
    }
    for (; j < end; ++j) {
        int s = csrc[j];
        float4 qa = q4[j];
        float q = hs == 0 ? qa.x : hs == 1 ? qa.y : hs == 2 ? qa.z : qa.w;
        uint2 u = reinterpret_cast<const uint2*>(h1h + (size_t)s * 256)[lane];
        float2 fa = __half22float2(*reinterpret_cast<__half2*>(&u.x));
        float2 fb = __half22float2(*reinterpret_cast<__half2*>(&u.y));
        z += q;
        ax += q * fa.x;
        ay += q * fa.y;
        az += q * fb.x;
        aw += q * fb.y;
    }
    float rz = 1.f / (z + 1e-16f);
    float4 bb = reinterpret_cast<const float4*>(b1)[lane];
    float4 pp = reinterpret_cast<const float4*>(p1)[lane];
    float4 v;
    v.x = ax * rz + bb.x;
    v.y = ay * rz + bb.y;
    v.z = az * rz + bb.z;
    v.w = aw * rz + bb.w;
    v.x = v.x > 0.f ? v.x : pp.x * v.x;
    v.y = v.y > 0.f ? v.y : pp.y * v.y;
    v.z = v.z > 0.f ? v.z : pp.z * v.z;
    v.w = v.w > 0.f ? v.w : pp.w * v.w;
    reinterpret_cast<float4*>(x1 + (size_t)n * 256)[lane] = v;
}

// --------------------------- layer-2 GEMM + scores -------------------------
__global__ __launch_bounds__(256) void k_gemm2(const float* __restrict__ x1,
                                               const float* __restrict__ W2,
                                               const float* __restrict__ as2,
                                               const float* __restrict__ ad2,
                                               float* __restrict__ h2,
                                               float* __restrict__ s2s,
                                               float* __restrict__ s2d, int N) {
    __shared__ float xs[8][256];
    int tid = threadIdx.x;
    int n0 = blockIdx.x * 8;
    for (int i = tid; i < 8 * 64; i += 256) {
        int r = i >> 6, c4 = i & 63;
        int n = n0 + r;
        float4 v = make_float4(0.f, 0.f, 0.f, 0.f);
        if (n < N) v = reinterpret_cast<const float4*>(x1 + (size_t)n * 256)[c4];
        *reinterpret_cast<float4*>(&xs[r][c4 * 4]) = v;
    }
    __syncthreads();
    int r = tid >> 5, c = tid & 31;
    int n = n0 + r;
    float acc = 0.f;
    for (int k4 = 0; k4 < 64; ++k4) {
        float4 xv = *reinterpret_cast<const float4*>(&xs[r][k4 * 4]);
        acc += xv.x * W2[(k4 * 4 + 0) * 32 + c] + xv.y * W2[(k4 * 4 + 1) * 32 + c] +
               xv.z * W2[(k4 * 4 + 2) * 32 + c] + xv.w * W2[(k4 * 4 + 3) * 32 + c];
    }
    if (n < N) h2[(size_t)n * 32 + c] = acc;
    float ps = acc * as2[c], pd = acc * ad2[c];
    for (int m = 16; m; m >>= 1) {
        ps += __shfl_xor(ps, m);
        pd += __shfl_xor(pd, m);
    }
    if (c == 0 && n < N) {
        s2s[n] = ps;
        s2d[n] = pd;
    }
}

// ------------------------- layer-2 edge aggregation ------------------------
// 32-lane group per dst node, 4x unroll (4 independent 128B row gathers).
__global__ __launch_bounds__(256) void k_agg2(const int* __restrict__ rowptr,
                                              const int* __restrict__ csrc,
                                              const float* __restrict__ q2,
                                              const float* __restrict__ h2,
                                              const float* __restrict__ b2,
                                              const float* __restrict__ p2,
                                              float* __restrict__ x2, int N) {
    int n = (blockIdx.x * 256 + threadIdx.x) >> 5;
    int c = threadIdx.x & 31;
    if (n >= N) return;
    int beg = rowptr[n], end = rowptr[n + 1];
    float acc = 0.f, z = 0.f;
    int j = beg;
    for (; j + 4 <= end; j += 4) {
        int s0 = csrc[j], s1 = csrc[j + 1], s2 = csrc[j + 2], s3 = csrc[j + 3];
        float q0 = q2[j], q1 = q2[j + 1], qq2 = q2[j + 2], q3 = q2[j + 3];
        float h0 = h2[(size_t)s0 * 32 + c];
        float h1 = h2[(size_t)s1 * 32 + c];
        float hh2 = h2[(size_t)s2 * 32 + c];
        float h3 = h2[(size_t)s3 * 32 + c];
        z += q0 + q1 + qq2 + q3;
        acc += q0 * h0 + q1 * h1 + qq2 * hh2 + q3 * h3;
    }
    for (; j < end; ++j) {
        int s = csrc[j];
        float q = q2[j];
        z += q;
        acc += q * h2[(size_t)s * 32 + c];
    }
    float v = acc / (z + 1e-16f) + b2[c];
    x2[(size_t)n * 32 + c] = v > 0.f ? v : p2[c] * v;
}

// ------------------------------- heads -------------------------------------
__global__ void k_wsum(const float* __restrict__ advw, const float* __restrict__ advb,
                       float* __restrict__ wsum, float* __restrict__ bsum) {
    int c = threadIdx.x;  // 32 threads
    float s = 0.f;
    for (int j = 0; j < 32; ++j) s += advw[c * 32 + j];
    wsum[c] = s;
    float b = advb[c];
    for (int m = 16; m; m >>= 1) b += __shfl_xor(b, m);
    if (c == 0) bsum[0] = b;
}

__global__ __launch_bounds__(256) void k_heads(const float* __restrict__ x2o,
                                               const float* __restrict__ x2a,
                                               const float* __restrict__ Wq,
                                               const float* __restrict__ Wk,
                                               const float* __restrict__ wsum,
                                               const float* __restrict__ bsum,
                                               float* __restrict__ o_q,
                                               float* __restrict__ o_k,
                                               float* __restrict__ o_x2,
                                               float* __restrict__ o_logits, int N) {
    int n = (blockIdx.x * 256 + threadIdx.x) >> 5;
    int o = threadIdx.x & 31;
    if (n >= N) return;
    float xo = x2o[(size_t)n * 32 + o];
    float xa = x2a[(size_t)n * 32 + o];
    float accq = 0.f, acck = 0.f;
    for (int c = 0; c < 32; ++c) {
        float xoc = __shfl(xo, c, 32);
        float xac = __shfl(xa, c, 32);
        accq += xoc * Wq[c * 32 + o];
        acck += xac * Wk[c * 32 + o];
    }
    float sq = accq * accq, sk = acck * acck;
    for (int m = 16; m; m >>= 1) {
        sq += __shfl_xor(sq, m);
        sk += __shfl_xor(sk, m);
    }
    o_q[(size_t)n * 32 + o] = accq / (sqrtf(sq) + 1e-12f);
    o_k[(size_t)n * 32 + o] = acck / (sqrtf(sk) + 1e-12f);
    o_x2[(size_t)n * 32 + o] = xo;
    float vo = xo * wsum[o], va = xa * wsum[o];
    for (int m = 16; m; m >>= 1) {
        vo += __shfl_xor(vo, m);
        va += __shfl_xor(va, m);
    }
    if (o == 0) {
        o_logits[n] = vo + bsum[0];
        o_logits[N + n] = va + bsum[0];
    }
}

__global__ __launch_bounds__(256) void k_fusion(const float* __restrict__ x2o,
                                                const int* __restrict__ idx,
                                                const float* __restrict__ Wf,
                                                const float* __restrict__ bfb,
                                                const float* __restrict__ Wlog,
                                                const float* __restrict__ blog,
                                                const float* __restrict__ Wlog1,
                                                const float* __restrict__ blog1,
                                                float* __restrict__ out_log,
                                                float* __restrict__ out_log1, int NB) {
    int i = (blockIdx.x * 256 + threadIdx.x) >> 5;
    int o = threadIdx.x & 31;
    if (i >= NB) return;
    int i1 = idx[i], i2 = idx[NB + i];
    float e1 = x2o[(size_t)i1 * 32 + o];
    float e2 = x2o[(size_t)i2 * 32 + o];
    float acc = bfb[o];
    for (int c = 0; c < 32; ++c) {
        acc += __shfl(e1, c, 32) * Wf[c * 32 + o];
        acc += __shfl(e2, c, 32) * Wf[(32 + c) * 32 + o];
    }
    float h = acc > 0.f ? acc : 0.f;
    float v0 = h * Wlog[o];
    float v1 = h * Wlog1[o];
    for (int m = 16; m; m >>= 1) {
        v0 += __shfl_xor(v0, m);
        v1 += __shfl_xor(v1, m);
    }
    if (o == 0) {
        out_log[i] = v0 + blog[0];
        out_log1[i] = v1 + blog1[0];
    }
}

// ---------------------------------------------------------------------------
extern "C" void kernel_launch(void* const* d_in, const int* in_sizes, int n_in,
                              void* d_out, int out_size, void* d_ws, size_t ws_size,
                              hipStream_t stream) {
    const float* x_o = (const float*)d_in[0];
    const float* x_a = (const float*)d_in[1];
    const float* W1 = (const float*)d_in[2];
    const float* a_src1 = (const float*)d_in[3];
    const float* a_dst1 = (const float*)d_in[4];
    const float* b1 = (const float*)d_in[5];
    const float* p1 = (const float*)d_in[6];
    const float* W2 = (const float*)d_in[7];
    const float* a_src2 = (const float*)d_in[8];
    const float* a_dst2 = (const float*)d_in[9];
    const float* b2 = (const float*)d_in[10];
    const float* p2 = (const float*)d_in[11];
    const float* adv_w = (const float*)d_in[12];
    const float* adv_b = (const float*)d_in[13];
    const float* Wq = (const float*)d_in[14];
    const float* Wk = (const float*)d_in[15];
    const float* Wf = (const float*)d_in[16];
    const float* bf_ = (const float*)d_in[17];
    const float* Wlog = (const float*)d_in[18];
    const float* blog = (const float*)d_in[19];
    const float* Wlog1 = (const float*)d_in[20];
    const float* blog1 = (const float*)d_in[21];
    const int* ei = (const int*)d_in[22];
    const int* idx = (const int*)d_in[23];

    const int N = in_sizes[0] / 128;
    const int E = in_sizes[22] / 2;
    const int NB = in_sizes[23] / 2;
    const int* esrc = ei;
    const int* edst = ei + E;
    const int GS = (N + 255) / 256;
    const int GE = (E + 255) / 256;

    char* ws = (char*)d_ws;
    size_t off = 0;
    auto alloc = [&](size_t bytes) -> void* {
        void* p = ws + off;
        off += (bytes + 255) & ~(size_t)255;
        return p;
    };
    __half* h1h = (__half*)alloc((size_t)N * 256 * 2);
    float* x1 = (float*)alloc((size_t)N * 256 * 4);
    float* h2 = (float*)alloc((size_t)N * 32 * 4);
    float* x2o = (float*)alloc((size_t)N * 32 * 4);
    float* x2a = (float*)alloc((size_t)N * 32 * 4);
    float* ssrc = (float*)alloc((size_t)N * 4 * 4);
    float* sdst = (float*)alloc((size_t)N * 4 * 4);
    float* s2s = (float*)alloc((size_t)N * 4);
    float* s2d = (float*)alloc((size_t)N * 4);
    int* rowptr = (int*)alloc((size_t)(N + 1) * 4);
    int* cursor = (int*)alloc((size_t)N * 4);
    int* bsums = (int*)alloc(256 * 4);
    int* csrc = (int*)alloc((size_t)E * 4);
    int* cdst = (int*)alloc((size_t)E * 4);
    float4* q4 = (float4*)alloc((size_t)E * 16);
    float* q2 = (float*)alloc((size_t)E * 4);
    float* wsum = (float*)alloc(32 * 4);
    float* bsum = (float*)alloc(4);

    // --- CSR build ---
    k_zero_i<<<GS, 256, 0, stream>>>(cursor, N);
    k_count<<<GE, 256, 0, stream>>>(edst, E, cursor);
    k_scan_local<<<GS, 256, 0, stream>>>(cursor, rowptr, bsums, N);
    k_scan_bsums<<<1, 256, 0, stream>>>(bsums, GS);
    k_scan_apply<<<GS, 256, 0, stream>>>(rowptr, bsums, cursor, N, E);
    k_fill<<<GE, 256, 0, stream>>>(esrc, edst, E, cursor, csrc, cdst);

    // --- two encodes ---
    for (int pass = 0; pass < 2; ++pass) {
        const float* xin = (pass == 0) ? x_o : x_a;
        float* x2 = (pass == 0) ? x2o : x2a;
        k_gemm1<<<(N + 15) / 16, 256, 0, stream>>>(xin, W1, a_src1, a_dst1, h1h, ssrc, sdst, N);
        k_eq1<<<GE, 256, 0, stream>>>(csrc, cdst, ssrc, sdst, q4, E);
        k_agg1<<<(N + 3) / 4, 256, 0, stream>>>(rowptr, csrc, q4, h1h, b1, p1, x1, N);
        k_gemm2<<<(N + 7) / 8, 256, 0, stream>>>(x1, W2, a_src2, a_dst2, h2, s2s, s2d, N);
        k_eq2<<<GE, 256, 0, stream>>>(csrc, cdst, s2s, s2d, q2, E);
        k_agg2<<<(N + 7) / 8, 256, 0, stream>>>(rowptr, csrc, q2, h2, b2, p2, x2, N);
    }

    // --- output heads ---
    float* out = (float*)d_out;
    float* o_log = out;                        // [NB]
    float* o_q = o_log + NB;                   // [N*32]
    float* o_k = o_q + (size_t)N * 32;         // [N*32]
    float* o_x2 = o_k + (size_t)N * 32;        // [N*32]
    float* o_logits = o_x2 + (size_t)N * 32;   // [2N]
    float* o_log1 = o_logits + (size_t)2 * N;  // [NB]

    k_wsum<<<1, 32, 0, stream>>>(adv_w, adv_b, wsum, bsum);
    k_heads<<<(N + 7) / 8, 256, 0, stream>>>(x2o, x2a, Wq, Wk, wsum, bsum,
                                             o_q, o_k, o_x2, o_logits, N);
    k_fusion<<<(NB + 7) / 8, 256, 0, stream>>>(x2o, idx, Wf, bf_, Wlog, blog, Wlog1, blog1,
                                               o_log, o_log1, NB);
}

// Round 5
// 424.444 us; speedup vs baseline: 2.1894x; 1.4486x over previous
//
#include <hip/hip_runtime.h>
#include <hip/hip_bf16.h>
#include <hip/hip_fp16.h>

// ---------------------------------------------------------------------------
// GATEncoder on MI355X.
//   CSR-by-dst built once (hierarchical scan);
//   fp16 MFMA GEMMs (16x16x32_f16): x pre-converted to fp16 (padded rows),
//     W pre-packed into B-fragment order; fused attention scores;
//   k_eq*: edge-parallel exp(leaky(score)) precompute;
//   agg1/agg2: 4x-unrolled independent gathers (ILP), shift-invariant softmax.
// Precision: fp16 payloads (rel 2^-11) on h1/x1 and GEMM inputs; f32 accum.
// ---------------------------------------------------------------------------

typedef _Float16 f16;
typedef f16 f16x4 __attribute__((ext_vector_type(4)));
typedef f16 f16x8 __attribute__((ext_vector_type(8)));
typedef float f32x4 __attribute__((ext_vector_type(4)));

// ------------------------------ CSR build ----------------------------------
__global__ void k_zero_i(int* __restrict__ p, int n) {
    int i = blockIdx.x * 256 + threadIdx.x;
    if (i < n) p[i] = 0;
}

__global__ void k_count(const int* __restrict__ dst, int E, int* __restrict__ cnt) {
    int e = blockIdx.x * 256 + threadIdx.x;
    if (e < E) atomicAdd(&cnt[dst[e]], 1);
}

__global__ __launch_bounds__(256) void k_scan_local(const int* __restrict__ cnt,
                                                    int* __restrict__ rowptr,
                                                    int* __restrict__ bsums, int N) {
    __shared__ int t[256];
    int tid = threadIdx.x;
    int i = blockIdx.x * 256 + tid;
    int v = (i < N) ? cnt[i] : 0;
    t[tid] = v;
    __syncthreads();
    for (int off = 1; off < 256; off <<= 1) {
        int u = (tid >= off) ? t[tid - off] : 0;
        __syncthreads();
        t[tid] += u;
        __syncthreads();
    }
    if (i < N) rowptr[i] = t[tid] - v;  // exclusive within block
    if (tid == 255) bsums[blockIdx.x] = t[255];
}

__global__ __launch_bounds__(256) void k_scan_bsums(int* __restrict__ bsums, int G) {
    __shared__ int t[256];
    int tid = threadIdx.x;
    int v = (tid < G) ? bsums[tid] : 0;
    t[tid] = v;
    __syncthreads();
    for (int off = 1; off < 256; off <<= 1) {
        int u = (tid >= off) ? t[tid - off] : 0;
        __syncthreads();
        t[tid] += u;
        __syncthreads();
    }
    if (tid < G) bsums[tid] = t[tid] - v;  // exclusive
}

__global__ __launch_bounds__(256) void k_scan_apply(int* __restrict__ rowptr,
                                                    const int* __restrict__ bsums,
                                                    int* __restrict__ cursor, int N, int E) {
    int i = blockIdx.x * 256 + threadIdx.x;
    if (i < N) {
        int r = rowptr[i] + bsums[blockIdx.x];
        rowptr[i] = r;
        cursor[i] = r;
    }
    if (i == 0) rowptr[N] = E;
}

__global__ void k_fill(const int* __restrict__ src, const int* __restrict__ dst, int E,
                       int* __restrict__ cursor, int* __restrict__ csrc,
                       int* __restrict__ cdst) {
    int e = blockIdx.x * 256 + threadIdx.x;
    if (e < E) {
        int d = dst[e];
        int pos = atomicAdd(&cursor[d], 1);
        csrc[pos] = src[e];
        cdst[pos] = d;
    }
}

// --------------------------- fp16 pre-conversion ---------------------------
// x f32 [N][128] -> xh fp16 [rows_pad][128], zero-filled pad rows.
__global__ __launch_bounds__(256) void k_xcvt(const float* __restrict__ x,
                                              f16* __restrict__ xh, int N, int rows_pad) {
    int i = blockIdx.x * 256 + threadIdx.x;  // one float4 each
    if (i >= rows_pad * 32) return;
    int row = i >> 5, c4 = i & 31;
    f16x4 h = {0, 0, 0, 0};
    if (row < N) {
        float4 v = reinterpret_cast<const float4*>(x + (size_t)row * 128)[c4];
        h[0] = (f16)v.x; h[1] = (f16)v.y; h[2] = (f16)v.z; h[3] = (f16)v.w;
    }
    *reinterpret_cast<f16x4*>(xh + (size_t)row * 128 + c4 * 4) = h;
}

// W f32 [K][Ncols] -> blob-packed fp16 B-fragments.
// blob b = (t*F + f)*64 + l, F = K/32; halves j: W[(32f+(l>>4)*8+j)*Ncols + 16t+(l&15)]
__global__ __launch_bounds__(256) void k_wpack(const float* __restrict__ W,
                                               f16* __restrict__ wpk, int K, int Ncols) {
    int b = blockIdx.x * 256 + threadIdx.x;
    int F = K >> 5;
    int total = (Ncols >> 4) * F * 64;
    if (b >= total) return;
    int l = b & 63, tf = b >> 6;
    int t = tf / F, f = tf % F;
    int col = t * 16 + (l & 15);
    int k0 = f * 32 + (l >> 4) * 8;
    f16x8 h;
#pragma unroll
    for (int j = 0; j < 8; ++j) h[j] = (f16)W[(size_t)(k0 + j) * Ncols + col];
    *reinterpret_cast<f16x8*>(wpk + (size_t)b * 8) = h;
}

// --------------------------- layer-1 MFMA GEMM + scores --------------------
// Wave computes 16 rows x 256 cols. A: row=l&15, k=(l>>4)*8+j. B: packed.
// C/D: col=l&15, row=(l>>4)*4+i  (m89-verified layout).
__global__ __launch_bounds__(256) void k_gemm1m(const f16* __restrict__ xh,
                                                const f16* __restrict__ wpk,
                                                const float* __restrict__ as1,
                                                const float* __restrict__ ad1,
                                                f16* __restrict__ h1h,
                                                float* __restrict__ ssrc,
                                                float* __restrict__ sdst, int N) {
    int tid = threadIdx.x;
    int w = tid >> 6, l = tid & 63;
    int c16 = l & 15, kg = l >> 4;
    int n0 = blockIdx.x * 64 + w * 16;
    const f16* xrow = xh + (size_t)(n0 + c16) * 128 + kg * 8;
    f16x8 af0 = *reinterpret_cast<const f16x8*>(xrow);
    f16x8 af1 = *reinterpret_cast<const f16x8*>(xrow + 32);
    f16x8 af2 = *reinterpret_cast<const f16x8*>(xrow + 64);
    f16x8 af3 = *reinterpret_cast<const f16x8*>(xrow + 96);
    float asv[16], adv[16];
#pragma unroll
    for (int t = 0; t < 16; ++t) {
        asv[t] = as1[t * 16 + c16];
        adv[t] = ad1[t * 16 + c16];
    }
    const f16x8* wp = reinterpret_cast<const f16x8*>(wpk);
    f32x4 acc[16];
#pragma unroll
    for (int t = 0; t < 16; ++t) {
        f32x4 a = {0.f, 0.f, 0.f, 0.f};
        a = __builtin_amdgcn_mfma_f32_16x16x32_f16(af0, wp[(t * 4 + 0) * 64 + l], a, 0, 0, 0);
        a = __builtin_amdgcn_mfma_f32_16x16x32_f16(af1, wp[(t * 4 + 1) * 64 + l], a, 0, 0, 0);
        a = __builtin_amdgcn_mfma_f32_16x16x32_f16(af2, wp[(t * 4 + 2) * 64 + l], a, 0, 0, 0);
        a = __builtin_amdgcn_mfma_f32_16x16x32_f16(af3, wp[(t * 4 + 3) * 64 + l], a, 0, 0, 0);
        acc[t] = a;
    }
    int rbase = n0 + kg * 4;
#pragma unroll
    for (int i = 0; i < 4; ++i) {
        int row = rbase + i;
        if (row < N) {
            f16* hr = h1h + (size_t)row * 256 + c16;
#pragma unroll
            for (int t = 0; t < 16; ++t) hr[t * 16] = (f16)acc[t][i];
        }
    }
#pragma unroll
    for (int i = 0; i < 4; ++i) {
        int row = rbase + i;
#pragma unroll
        for (int hh = 0; hh < 4; ++hh) {
            float ps = 0.f, pd = 0.f;
#pragma unroll
            for (int tt = 0; tt < 4; ++tt) {
                int t = hh * 4 + tt;
                ps += acc[t][i] * asv[t];
                pd += acc[t][i] * adv[t];
            }
#pragma unroll
            for (int m = 1; m < 16; m <<= 1) {
                ps += __shfl_xor(ps, m);
                pd += __shfl_xor(pd, m);
            }
            if (c16 == 0 && row < N) {
                ssrc[row * 4 + hh] = ps;
                sdst[row * 4 + hh] = pd;
            }
        }
    }
}

// --------------------------- layer-2 MFMA GEMM + scores --------------------
__global__ __launch_bounds__(256) void k_gemm2m(const f16* __restrict__ x1h,
                                                const f16* __restrict__ wpk2,
                                                const float* __restrict__ as2,
                                                const float* __restrict__ ad2,
                                                float* __restrict__ h2,
                                                float* __restrict__ s2s,
                                                float* __restrict__ s2d, int N) {
    int tid = threadIdx.x;
    int w = tid >> 6, l = tid & 63;
    int c16 = l & 15, kg = l >> 4;
    int n0 = blockIdx.x * 64 + w * 16;
    const f16* xrow = x1h + (size_t)(n0 + c16) * 256 + kg * 8;
    f16x8 af[8];
#pragma unroll
    for (int f = 0; f < 8; ++f) af[f] = *reinterpret_cast<const f16x8*>(xrow + f * 32);
    const f16x8* wp = reinterpret_cast<const f16x8*>(wpk2);
    f32x4 acc[2];
#pragma unroll
    for (int t = 0; t < 2; ++t) {
        f32x4 a = {0.f, 0.f, 0.f, 0.f};
#pragma unroll
        for (int f = 0; f < 8; ++f)
            a = __builtin_amdgcn_mfma_f32_16x16x32_f16(af[f], wp[(t * 8 + f) * 64 + l], a, 0, 0, 0);
        acc[t] = a;
    }
    float asv[2], adv[2];
#pragma unroll
    for (int t = 0; t < 2; ++t) {
        asv[t] = as2[t * 16 + c16];
        adv[t] = ad2[t * 16 + c16];
    }
    int rbase = n0 + kg * 4;
#pragma unroll
    for (int i = 0; i < 4; ++i) {
        int row = rbase + i;
        if (row < N) {
            float* hr = h2 + (size_t)row * 32 + c16;
#pragma unroll
            for (int t = 0; t < 2; ++t) hr[t * 16] = acc[t][i];
        }
        float ps = acc[0][i] * asv[0] + acc[1][i] * asv[1];
        float pd = acc[0][i] * adv[0] + acc[1][i] * adv[1];
#pragma unroll
        for (int m = 1; m < 16; m <<= 1) {
            ps += __shfl_xor(ps, m);
            pd += __shfl_xor(pd, m);
        }
        if (c16 == 0 && row < N) {
            s2s[row] = ps;
            s2d[row] = pd;
        }
    }
}

// --------------------- edge-parallel score precompute ----------------------
__global__ __launch_bounds__(256) void k_eq1(const int* __restrict__ csrc,
                                             const int* __restrict__ cdst,
                                             const float* __restrict__ ssrc,
                                             const float* __restrict__ sdst,
                                             float4* __restrict__ q4, int E) {
    int j = blockIdx.x * 256 + threadIdx.x;
    if (j >= E) return;
    int s = csrc[j], d = cdst[j];
    float4 a = reinterpret_cast<const float4*>(ssrc)[s];
    float4 b = reinterpret_cast<const float4*>(sdst)[d];
    float4 e;
    e.x = a.x + b.x; e.y = a.y + b.y; e.z = a.z + b.z; e.w = a.w + b.w;
    e.x = e.x > 0.f ? e.x : 0.2f * e.x;
    e.y = e.y > 0.f ? e.y : 0.2f * e.y;
    e.z = e.z > 0.f ? e.z : 0.2f * e.z;
    e.w = e.w > 0.f ? e.w : 0.2f * e.w;
    e.x = __expf(e.x); e.y = __expf(e.y); e.z = __expf(e.z); e.w = __expf(e.w);
    q4[j] = e;
}

__global__ __launch_bounds__(256) void k_eq2(const int* __restrict__ csrc,
                                             const int* __restrict__ cdst,
                                             const float* __restrict__ s2s,
                                             const float* __restrict__ s2d,
                                             float* __restrict__ q2, int E) {
    int j = blockIdx.x * 256 + threadIdx.x;
    if (j >= E) return;
    float e = s2s[csrc[j]] + s2d[cdst[j]];
    e = e > 0.f ? e : 0.2f * e;
    q2[j] = __expf(e);
}

// ------------------------- layer-1 edge aggregation ------------------------
__global__ __launch_bounds__(256) void k_agg1(const int* __restrict__ rowptr,
                                              const int* __restrict__ csrc,
                                              const float4* __restrict__ q4,
                                              const f16* __restrict__ h1h,
                                              const float* __restrict__ b1,
                                              const float* __restrict__ p1,
                                              f16* __restrict__ x1h, int N) {
    int n = (blockIdx.x * 256 + threadIdx.x) >> 6;
    int lane = threadIdx.x & 63;
    if (n >= N) return;
    int hs = lane >> 4;
    int beg = rowptr[n], end = rowptr[n + 1];
    float ax = 0.f, ay = 0.f, az = 0.f, aw = 0.f, z = 0.f;
    int j = beg;
    for (; j + 4 <= end; j += 4) {
        int s0 = csrc[j], s1 = csrc[j + 1], s2 = csrc[j + 2], s3 = csrc[j + 3];
        float4 qa = q4[j], qb = q4[j + 1], qc = q4[j + 2], qd = q4[j + 3];
        float q0 = hs == 0 ? qa.x : hs == 1 ? qa.y : hs == 2 ? qa.z : qa.w;
        float q1 = hs == 0 ? qb.x : hs == 1 ? qb.y : hs == 2 ? qb.z : qb.w;
        float q2 = hs == 0 ? qc.x : hs == 1 ? qc.y : hs == 2 ? qc.z : qc.w;
        float q3 = hs == 0 ? qd.x : hs == 1 ? qd.y : hs == 2 ? qd.z : qd.w;
        uint2 u0 = reinterpret_cast<const uint2*>(h1h + (size_t)s0 * 256)[lane];
        uint2 u1 = reinterpret_cast<const uint2*>(h1h + (size_t)s1 * 256)[lane];
        uint2 u2 = reinterpret_cast<const uint2*>(h1h + (size_t)s2 * 256)[lane];
        uint2 u3 = reinterpret_cast<const uint2*>(h1h + (size_t)s3 * 256)[lane];
        z += q0 + q1 + q2 + q3;
        float2 f0a = __half22float2(*reinterpret_cast<__half2*>(&u0.x));
        float2 f0b = __half22float2(*reinterpret_cast<__half2*>(&u0.y));
        float2 f1a = __half22float2(*reinterpret_cast<__half2*>(&u1.x));
        float2 f1b = __half22float2(*reinterpret_cast<__half2*>(&u1.y));
        float2 f2a = __half22float2(*reinterpret_cast<__half2*>(&u2.x));
        float2 f2b = __half22float2(*reinterpret_cast<__half2*>(&u2.y));
        float2 f3a = __half22float2(*reinterpret_cast<__half2*>(&u3.x));
        float2 f3b = __half22float2(*reinterpret_cast<__half2*>(&u3.y));
        ax += q0 * f0a.x + q1 * f1a.x + q2 * f2a.x + q3 * f3a.x;
        ay += q0 * f0a.y + q1 * f1a.y + q2 * f2a.y + q3 * f3a.y;
        az += q0 * f0b.x + q1 * f1b.x + q2 * f2b.x + q3 * f3b.x;
        aw += q0 * f0b.y + q1 * f1b.y + q2 * f2b.y + q3 * f3b.y;
    }
    for (; j < end; ++j) {
        int s = csrc[j];
        float4 qa = q4[j];
        float q = hs == 0 ? qa.x : hs == 1 ? qa.y : hs == 2 ? qa.z : qa.w;
        uint2 u = reinterpret_cast<const uint2*>(h1h + (size_t)s * 256)[lane];
        float2 fa = __half22float2(*reinterpret_cast<__half2*>(&u.x));
        float2 fb = __half22float2(*reinterpret_cast<__half2*>(&u.y));
        z += q;
        ax += q * fa.x;
        ay += q * fa.y;
        az += q * fb.x;
        aw += q * fb.y;
    }
    float rz = 1.f / (z + 1e-16f);
    float4 bb = reinterpret_cast<const float4*>(b1)[lane];
    float4 pp = reinterpret_cast<const float4*>(p1)[lane];
    float4 v;
    v.x = ax * rz + bb.x;
    v.y = ay * rz + bb.y;
    v.z = az * rz + bb.z;
    v.w = aw * rz + bb.w;
    v.x = v.x > 0.f ? v.x : pp.x * v.x;
    v.y = v.y > 0.f ? v.y : pp.y * v.y;
    v.z = v.z > 0.f ? v.z : pp.z * v.z;
    v.w = v.w > 0.f ? v.w : pp.w * v.w;
    f16x4 hv;
    hv[0] = (f16)v.x; hv[1] = (f16)v.y; hv[2] = (f16)v.z; hv[3] = (f16)v.w;
    *reinterpret_cast<f16x4*>(x1h + (size_t)n * 256 + lane * 4) = hv;
}

// ------------------------- layer-2 edge aggregation ------------------------
__global__ __launch_bounds__(256) void k_agg2(const int* __restrict__ rowptr,
                                              const int* __restrict__ csrc,
                                              const float* __restrict__ q2,
                                              const float* __restrict__ h2,
                                              const float* __restrict__ b2,
                                              const float* __restrict__ p2,
                                              float* __restrict__ x2, int N) {
    int n = (blockIdx.x * 256 + threadIdx.x) >> 5;
    int c = threadIdx.x & 31;
    if (n >= N) return;
    int beg = rowptr[n], end = rowptr[n + 1];
    float acc = 0.f, z = 0.f;
    int j = beg;
    for (; j + 4 <= end; j += 4) {
        int s0 = csrc[j], s1 = csrc[j + 1], s2 = csrc[j + 2], s3 = csrc[j + 3];
        float q0 = q2[j], q1 = q2[j + 1], qq2 = q2[j + 2], q3 = q2[j + 3];
        float h0 = h2[(size_t)s0 * 32 + c];
        float h1 = h2[(size_t)s1 * 32 + c];
        float hh2 = h2[(size_t)s2 * 32 + c];
        float h3 = h2[(size_t)s3 * 32 + c];
        z += q0 + q1 + qq2 + q3;
        acc += q0 * h0 + q1 * h1 + qq2 * hh2 + q3 * h3;
    }
    for (; j < end; ++j) {
        int s = csrc[j];
        float q = q2[j];
        z += q;
        acc += q * h2[(size_t)s * 32 + c];
    }
    float v = acc / (z + 1e-16f) + b2[c];
    x2[(size_t)n * 32 + c] = v > 0.f ? v : p2[c] * v;
}

// ------------------------------- heads -------------------------------------
__global__ void k_wsum(const float* __restrict__ advw, const float* __restrict__ advb,
                       float* __restrict__ wsum, float* __restrict__ bsum) {
    int c = threadIdx.x;  // 32 threads
    float s = 0.f;
    for (int j = 0; j < 32; ++j) s += advw[c * 32 + j];
    wsum[c] = s;
    float b = advb[c];
    for (int m = 16; m; m >>= 1) b += __shfl_xor(b, m);
    if (c == 0) bsum[0] = b;
}

__global__ __launch_bounds__(256) void k_heads(const float* __restrict__ x2o,
                                               const float* __restrict__ x2a,
                                               const float* __restrict__ Wq,
                                               const float* __restrict__ Wk,
                                               const float* __restrict__ wsum,
                                               const float* __restrict__ bsum,
                                               float* __restrict__ o_q,
                                               float* __restrict__ o_k,
                                               float* __restrict__ o_x2,
                                               float* __restrict__ o_logits, int N) {
    int n = (blockIdx.x * 256 + threadIdx.x) >> 5;
    int o = threadIdx.x & 31;
    if (n >= N) return;
    float xo = x2o[(size_t)n * 32 + o];
    float xa = x2a[(size_t)n * 32 + o];
    float accq = 0.f, acck = 0.f;
    for (int c = 0; c < 32; ++c) {
        float xoc = __shfl(xo, c, 32);
        float xac = __shfl(xa, c, 32);
        accq += xoc * Wq[c * 32 + o];
        acck += xac * Wk[c * 32 + o];
    }
    float sq = accq * accq, sk = acck * acck;
    for (int m = 16; m; m >>= 1) {
        sq += __shfl_xor(sq, m);
        sk += __shfl_xor(sk, m);
    }
    o_q[(size_t)n * 32 + o] = accq / (sqrtf(sq) + 1e-12f);
    o_k[(size_t)n * 32 + o] = acck / (sqrtf(sk) + 1e-12f);
    o_x2[(size_t)n * 32 + o] = xo;
    float vo = xo * wsum[o], va = xa * wsum[o];
    for (int m = 16; m; m >>= 1) {
        vo += __shfl_xor(vo, m);
        va += __shfl_xor(va, m);
    }
    if (o == 0) {
        o_logits[n] = vo + bsum[0];
        o_logits[N + n] = va + bsum[0];
    }
}

__global__ __launch_bounds__(256) void k_fusion(const float* __restrict__ x2o,
                                                const int* __restrict__ idx,
                                                const float* __restrict__ Wf,
                                                const float* __restrict__ bfb,
                                                const float* __restrict__ Wlog,
                                                const float* __restrict__ blog,
                                                const float* __restrict__ Wlog1,
                                                const float* __restrict__ blog1,
                                                float* __restrict__ out_log,
                                                float* __restrict__ out_log1, int NB) {
    int i = (blockIdx.x * 256 + threadIdx.x) >> 5;
    int o = threadIdx.x & 31;
    if (i >= NB) return;
    int i1 = idx[i], i2 = idx[NB + i];
    float e1 = x2o[(size_t)i1 * 32 + o];
    float e2 = x2o[(size_t)i2 * 32 + o];
    float acc = bfb[o];
    for (int c = 0; c < 32; ++c) {
        acc += __shfl(e1, c, 32) * Wf[c * 32 + o];
        acc += __shfl(e2, c, 32) * Wf[(32 + c) * 32 + o];
    }
    float h = acc > 0.f ? acc : 0.f;
    float v0 = h * Wlog[o];
    float v1 = h * Wlog1[o];
    for (int m = 16; m; m >>= 1) {
        v0 += __shfl_xor(v0, m);
        v1 += __shfl_xor(v1, m);
    }
    if (o == 0) {
        out_log[i] = v0 + blog[0];
        out_log1[i] = v1 + blog1[0];
    }
}

// ---------------------------------------------------------------------------
extern "C" void kernel_launch(void* const* d_in, const int* in_sizes, int n_in,
                              void* d_out, int out_size, void* d_ws, size_t ws_size,
                              hipStream_t stream) {
    const float* x_o = (const float*)d_in[0];
    const float* x_a = (const float*)d_in[1];
    const float* W1 = (const float*)d_in[2];
    const float* a_src1 = (const float*)d_in[3];
    const float* a_dst1 = (const float*)d_in[4];
    const float* b1 = (const float*)d_in[5];
    const float* p1 = (const float*)d_in[6];
    const float* W2 = (const float*)d_in[7];
    const float* a_src2 = (const float*)d_in[8];
    const float* a_dst2 = (const float*)d_in[9];
    const float* b2 = (const float*)d_in[10];
    const float* p2 = (const float*)d_in[11];
    const float* adv_w = (const float*)d_in[12];
    const float* adv_b = (const float*)d_in[13];
    const float* Wq = (const float*)d_in[14];
    const float* Wk = (const float*)d_in[15];
    const float* Wf = (const float*)d_in[16];
    const float* bf_ = (const float*)d_in[17];
    const float* Wlog = (const float*)d_in[18];
    const float* blog = (const float*)d_in[19];
    const float* Wlog1 = (const float*)d_in[20];
    const float* blog1 = (const float*)d_in[21];
    const int* ei = (const int*)d_in[22];
    const int* idx = (const int*)d_in[23];

    const int N = in_sizes[0] / 128;
    const int E = in_sizes[22] / 2;
    const int NB = in_sizes[23] / 2;
    const int* esrc = ei;
    const int* edst = ei + E;
    const int GS = (N + 255) / 256;
    const int GE = (E + 255) / 256;
    const int rows_pad = (N + 63) & ~63;

    char* ws = (char*)d_ws;
    size_t off = 0;
    auto alloc = [&](size_t bytes) -> void* {
        void* p = ws + off;
        off += (bytes + 255) & ~(size_t)255;
        return p;
    };
    f16* xh = (f16*)alloc((size_t)rows_pad * 128 * 2);
    f16* h1h = (f16*)alloc((size_t)N * 256 * 2);
    f16* x1h = (f16*)alloc((size_t)rows_pad * 256 * 2);
    f16* wpk1 = (f16*)alloc((size_t)16 * 4 * 64 * 8 * 2);
    f16* wpk2 = (f16*)alloc((size_t)2 * 8 * 64 * 8 * 2);
    float* h2 = (float*)alloc((size_t)N * 32 * 4);
    float* x2o = (float*)alloc((size_t)N * 32 * 4);
    float* x2a = (float*)alloc((size_t)N * 32 * 4);
    float* ssrc = (float*)alloc((size_t)N * 4 * 4);
    float* sdst = (float*)alloc((size_t)N * 4 * 4);
    float* s2s = (float*)alloc((size_t)N * 4);
    float* s2d = (float*)alloc((size_t)N * 4);
    int* rowptr = (int*)alloc((size_t)(N + 1) * 4);
    int* cursor = (int*)alloc((size_t)N * 4);
    int* bsums = (int*)alloc(256 * 4);
    int* csrc = (int*)alloc((size_t)E * 4);
    int* cdst = (int*)alloc((size_t)E * 4);
    float4* q4 = (float4*)alloc((size_t)E * 16);
    float* q2 = (float*)alloc((size_t)E * 4);
    float* wsum = (float*)alloc(32 * 4);
    float* bsum = (float*)alloc(4);

    // --- CSR build ---
    k_zero_i<<<GS, 256, 0, stream>>>(cursor, N);
    k_count<<<GE, 256, 0, stream>>>(edst, E, cursor);
    k_scan_local<<<GS, 256, 0, stream>>>(cursor, rowptr, bsums, N);
    k_scan_bsums<<<1, 256, 0, stream>>>(bsums, GS);
    k_scan_apply<<<GS, 256, 0, stream>>>(rowptr, bsums, cursor, N, E);
    k_fill<<<GE, 256, 0, stream>>>(esrc, edst, E, cursor, csrc, cdst);

    // --- weight packing (once) ---
    k_wpack<<<16, 256, 0, stream>>>(W1, wpk1, 128, 256);
    k_wpack<<<4, 256, 0, stream>>>(W2, wpk2, 256, 32);

    // --- two encodes ---
    for (int pass = 0; pass < 2; ++pass) {
        const float* xin = (pass == 0) ? x_o : x_a;
        float* x2 = (pass == 0) ? x2o : x2a;
        k_xcvt<<<(rows_pad * 32 + 255) / 256, 256, 0, stream>>>(xin, xh, N, rows_pad);
        k_gemm1m<<<rows_pad / 64, 256, 0, stream>>>(xh, wpk1, a_src1, a_dst1, h1h, ssrc, sdst, N);
        k_eq1<<<GE, 256, 0, stream>>>(csrc, cdst, ssrc, sdst, q4, E);
        k_agg1<<<(N + 3) / 4, 256, 0, stream>>>(rowptr, csrc, q4, h1h, b1, p1, x1h, N);
        k_gemm2m<<<rows_pad / 64, 256, 0, stream>>>(x1h, wpk2, a_src2, a_dst2, h2, s2s, s2d, N);
        k_eq2<<<GE, 256, 0, stream>>>(csrc, cdst, s2s, s2d, q2, E);
        k_agg2<<<(N + 7) / 8, 256, 0, stream>>>(rowptr, csrc, q2, h2, b2, p2, x2, N);
    }

    // --- output heads ---
    float* out = (float*)d_out;
    float* o_log = out;                        // [NB]
    float* o_q = o_log + NB;                   // [N*32]
    float* o_k = o_q + (size_t)N * 32;         // [N*32]
    float* o_x2 = o_k + (size_t)N * 32;        // [N*32]
    float* o_logits = o_x2 + (size_t)N * 32;   // [2N]
    float* o_log1 = o_logits + (size_t)2 * N;  // [NB]

    k_wsum<<<1, 32, 0, stream>>>(adv_w, adv_b, wsum, bsum);
    k_heads<<<(N + 7) / 8, 256, 0, stream>>>(x2o, x2a, Wq, Wk, wsum, bsum,
                                             o_q, o_k, o_x2, o_logits, N);
    k_fusion<<<(NB + 7) / 8, 256, 0, stream>>>(x2o, idx, Wf, bf_, Wlog, blog, Wlog1, blog1,
                                               o_log, o_log1, NB);
}

// Round 6
// 391.698 us; speedup vs baseline: 2.3724x; 1.0836x over previous
//
#include <hip/hip_runtime.h>
#include <hip/hip_bf16.h>
#include <hip/hip_fp16.h>

// ---------------------------------------------------------------------------
// GATEncoder on MI355X.
//   CSR-by-dst built once (hierarchical scan);
//   fp16 MFMA GEMMs (16x16x32_f16), W pre-packed to B-fragment order;
//   k_eq*: edge-parallel exp(leaky(score)) precompute;
//   agg1/agg2: 8-deep unrolled independent gathers (ILP);
//   BOTH encodes merged into single launches via pass-strided buffers when
//   ws_size permits (~196 MB); sequential fallback otherwise.
// Precision: fp16 payloads (rel 2^-11) on h1/x1 and GEMM inputs; f32 math.
// ---------------------------------------------------------------------------

typedef _Float16 f16;
typedef f16 f16x4 __attribute__((ext_vector_type(4)));
typedef f16 f16x8 __attribute__((ext_vector_type(8)));
typedef float f32x4 __attribute__((ext_vector_type(4)));

// ------------------------------ CSR build ----------------------------------
__global__ void k_zero_i(int* __restrict__ p, int n) {
    int i = blockIdx.x * 256 + threadIdx.x;
    if (i < n) p[i] = 0;
}

__global__ void k_count(const int* __restrict__ dst, int E, int* __restrict__ cnt) {
    int e = blockIdx.x * 256 + threadIdx.x;
    if (e < E) atomicAdd(&cnt[dst[e]], 1);
}

__global__ __launch_bounds__(256) void k_scan_local(const int* __restrict__ cnt,
                                                    int* __restrict__ rowptr,
                                                    int* __restrict__ bsums, int N) {
    __shared__ int t[256];
    int tid = threadIdx.x;
    int i = blockIdx.x * 256 + tid;
    int v = (i < N) ? cnt[i] : 0;
    t[tid] = v;
    __syncthreads();
    for (int off = 1; off < 256; off <<= 1) {
        int u = (tid >= off) ? t[tid - off] : 0;
        __syncthreads();
        t[tid] += u;
        __syncthreads();
    }
    if (i < N) rowptr[i] = t[tid] - v;  // exclusive within block
    if (tid == 255) bsums[blockIdx.x] = t[255];
}

__global__ __launch_bounds__(256) void k_scan_bsums(int* __restrict__ bsums, int G) {
    __shared__ int t[256];
    int tid = threadIdx.x;
    int v = (tid < G) ? bsums[tid] : 0;
    t[tid] = v;
    __syncthreads();
    for (int off = 1; off < 256; off <<= 1) {
        int u = (tid >= off) ? t[tid - off] : 0;
        __syncthreads();
        t[tid] += u;
        __syncthreads();
    }
    if (tid < G) bsums[tid] = t[tid] - v;  // exclusive
}

__global__ __launch_bounds__(256) void k_scan_apply(int* __restrict__ rowptr,
                                                    const int* __restrict__ bsums,
                                                    int* __restrict__ cursor, int N, int E) {
    int i = blockIdx.x * 256 + threadIdx.x;
    if (i < N) {
        int r = rowptr[i] + bsums[blockIdx.x];
        rowptr[i] = r;
        cursor[i] = r;
    }
    if (i == 0) rowptr[N] = E;
}

__global__ void k_fill(const int* __restrict__ src, const int* __restrict__ dst, int E,
                       int* __restrict__ cursor, int* __restrict__ csrc,
                       int* __restrict__ cdst) {
    int e = blockIdx.x * 256 + threadIdx.x;
    if (e < E) {
        int d = dst[e];
        int pos = atomicAdd(&cursor[d], 1);
        csrc[pos] = src[e];
        cdst[pos] = d;
    }
}

// --------------------------- fp16 pre-conversion ---------------------------
__global__ __launch_bounds__(256) void k_xcvt(const float* __restrict__ xa,
                                              const float* __restrict__ xb,
                                              f16* __restrict__ xh, int N, int rows_pad,
                                              int Bper, size_t xh_str) {
    int blk = blockIdx.x, pass = 0;
    if (blk >= Bper) { pass = 1; blk -= Bper; }
    const float* x = pass ? xb : xa;
    xh += (size_t)pass * xh_str;
    int i = blk * 256 + threadIdx.x;  // one float4 each
    if (i >= rows_pad * 32) return;
    int row = i >> 5, c4 = i & 31;
    f16x4 h = {0, 0, 0, 0};
    if (row < N) {
        float4 v = reinterpret_cast<const float4*>(x + (size_t)row * 128)[c4];
        h[0] = (f16)v.x; h[1] = (f16)v.y; h[2] = (f16)v.z; h[3] = (f16)v.w;
    }
    *reinterpret_cast<f16x4*>(xh + (size_t)row * 128 + c4 * 4) = h;
}

// W f32 [K][Ncols] -> blob-packed fp16 B-fragments.
__global__ __launch_bounds__(256) void k_wpack(const float* __restrict__ W,
                                               f16* __restrict__ wpk, int K, int Ncols) {
    int b = blockIdx.x * 256 + threadIdx.x;
    int F = K >> 5;
    int total = (Ncols >> 4) * F * 64;
    if (b >= total) return;
    int l = b & 63, tf = b >> 6;
    int t = tf / F, f = tf % F;
    int col = t * 16 + (l & 15);
    int k0 = f * 32 + (l >> 4) * 8;
    f16x8 h;
#pragma unroll
    for (int j = 0; j < 8; ++j) h[j] = (f16)W[(size_t)(k0 + j) * Ncols + col];
    *reinterpret_cast<f16x8*>(wpk + (size_t)b * 8) = h;
}

// --------------------------- layer-1 MFMA GEMM + scores --------------------
__global__ __launch_bounds__(256) void k_gemm1m(const f16* __restrict__ xh,
                                                const f16* __restrict__ wpk,
                                                const float* __restrict__ as1,
                                                const float* __restrict__ ad1,
                                                f16* __restrict__ h1h,
                                                float* __restrict__ ssrc,
                                                float* __restrict__ sdst, int N,
                                                int Bper, size_t xh_str, size_t h1_str,
                                                size_t s4_str) {
    int blk = blockIdx.x, pass = 0;
    if (blk >= Bper) { pass = 1; blk -= Bper; }
    xh += (size_t)pass * xh_str;
    h1h += (size_t)pass * h1_str;
    ssrc += (size_t)pass * s4_str;
    sdst += (size_t)pass * s4_str;
    int tid = threadIdx.x;
    int w = tid >> 6, l = tid & 63;
    int c16 = l & 15, kg = l >> 4;
    int n0 = blk * 64 + w * 16;
    const f16* xrow = xh + (size_t)(n0 + c16) * 128 + kg * 8;
    f16x8 af0 = *reinterpret_cast<const f16x8*>(xrow);
    f16x8 af1 = *reinterpret_cast<const f16x8*>(xrow + 32);
    f16x8 af2 = *reinterpret_cast<const f16x8*>(xrow + 64);
    f16x8 af3 = *reinterpret_cast<const f16x8*>(xrow + 96);
    float asv[16], adv[16];
#pragma unroll
    for (int t = 0; t < 16; ++t) {
        asv[t] = as1[t * 16 + c16];
        adv[t] = ad1[t * 16 + c16];
    }
    const f16x8* wp = reinterpret_cast<const f16x8*>(wpk);
    f32x4 acc[16];
#pragma unroll
    for (int t = 0; t < 16; ++t) {
        f32x4 a = {0.f, 0.f, 0.f, 0.f};
        a = __builtin_amdgcn_mfma_f32_16x16x32_f16(af0, wp[(t * 4 + 0) * 64 + l], a, 0, 0, 0);
        a = __builtin_amdgcn_mfma_f32_16x16x32_f16(af1, wp[(t * 4 + 1) * 64 + l], a, 0, 0, 0);
        a = __builtin_amdgcn_mfma_f32_16x16x32_f16(af2, wp[(t * 4 + 2) * 64 + l], a, 0, 0, 0);
        a = __builtin_amdgcn_mfma_f32_16x16x32_f16(af3, wp[(t * 4 + 3) * 64 + l], a, 0, 0, 0);
        acc[t] = a;
    }
    int rbase = n0 + kg * 4;
#pragma unroll
    for (int i = 0; i < 4; ++i) {
        int row = rbase + i;
        if (row < N) {
            f16* hr = h1h + (size_t)row * 256 + c16;
#pragma unroll
            for (int t = 0; t < 16; ++t) hr[t * 16] = (f16)acc[t][i];
        }
    }
#pragma unroll
    for (int i = 0; i < 4; ++i) {
        int row = rbase + i;
#pragma unroll
        for (int hh = 0; hh < 4; ++hh) {
            float ps = 0.f, pd = 0.f;
#pragma unroll
            for (int tt = 0; tt < 4; ++tt) {
                int t = hh * 4 + tt;
                ps += acc[t][i] * asv[t];
                pd += acc[t][i] * adv[t];
            }
#pragma unroll
            for (int m = 1; m < 16; m <<= 1) {
                ps += __shfl_xor(ps, m);
                pd += __shfl_xor(pd, m);
            }
            if (c16 == 0 && row < N) {
                ssrc[row * 4 + hh] = ps;
                sdst[row * 4 + hh] = pd;
            }
        }
    }
}

// --------------------------- layer-2 MFMA GEMM + scores --------------------
__global__ __launch_bounds__(256) void k_gemm2m(const f16* __restrict__ x1h,
                                                const f16* __restrict__ wpk2,
                                                const float* __restrict__ as2,
                                                const float* __restrict__ ad2,
                                                float* __restrict__ h2,
                                                float* __restrict__ s2s,
                                                float* __restrict__ s2d, int N,
                                                int Bper, size_t x1_str, size_t h2_str,
                                                size_t s1_str) {
    int blk = blockIdx.x, pass = 0;
    if (blk >= Bper) { pass = 1; blk -= Bper; }
    x1h += (size_t)pass * x1_str;
    h2 += (size_t)pass * h2_str;
    s2s += (size_t)pass * s1_str;
    s2d += (size_t)pass * s1_str;
    int tid = threadIdx.x;
    int w = tid >> 6, l = tid & 63;
    int c16 = l & 15, kg = l >> 4;
    int n0 = blk * 64 + w * 16;
    const f16* xrow = x1h + (size_t)(n0 + c16) * 256 + kg * 8;
    f16x8 af[8];
#pragma unroll
    for (int f = 0; f < 8; ++f) af[f] = *reinterpret_cast<const f16x8*>(xrow + f * 32);
    const f16x8* wp = reinterpret_cast<const f16x8*>(wpk2);
    f32x4 acc[2];
#pragma unroll
    for (int t = 0; t < 2; ++t) {
        f32x4 a = {0.f, 0.f, 0.f, 0.f};
#pragma unroll
        for (int f = 0; f < 8; ++f)
            a = __builtin_amdgcn_mfma_f32_16x16x32_f16(af[f], wp[(t * 8 + f) * 64 + l], a, 0, 0, 0);
        acc[t] = a;
    }
    float asv[2], adv[2];
#pragma unroll
    for (int t = 0; t < 2; ++t) {
        asv[t] = as2[t * 16 + c16];
        adv[t] = ad2[t * 16 + c16];
    }
    int rbase = n0 + kg * 4;
#pragma unroll
    for (int i = 0; i < 4; ++i) {
        int row = rbase + i;
        if (row < N) {
            float* hr = h2 + (size_t)row * 32 + c16;
#pragma unroll
            for (int t = 0; t < 2; ++t) hr[t * 16] = acc[t][i];
        }
        float ps = acc[0][i] * asv[0] + acc[1][i] * asv[1];
        float pd = acc[0][i] * adv[0] + acc[1][i] * adv[1];
#pragma unroll
        for (int m = 1; m < 16; m <<= 1) {
            ps += __shfl_xor(ps, m);
            pd += __shfl_xor(pd, m);
        }
        if (c16 == 0 && row < N) {
            s2s[row] = ps;
            s2d[row] = pd;
        }
    }
}

// --------------------- edge-parallel score precompute ----------------------
__global__ __launch_bounds__(256) void k_eq1(const int* __restrict__ csrc,
                                             const int* __restrict__ cdst,
                                             const float* __restrict__ ssrc,
                                             const float* __restrict__ sdst,
                                             float4* __restrict__ q4, int E,
                                             int Bper, size_t s4_str, size_t q4_str) {
    int blk = blockIdx.x, pass = 0;
    if (blk >= Bper) { pass = 1; blk -= Bper; }
    ssrc += (size_t)pass * s4_str;
    sdst += (size_t)pass * s4_str;
    q4 += (size_t)pass * q4_str;
    int j = blk * 256 + threadIdx.x;
    if (j >= E) return;
    int s = csrc[j], d = cdst[j];
    float4 a = reinterpret_cast<const float4*>(ssrc)[s];
    float4 b = reinterpret_cast<const float4*>(sdst)[d];
    float4 e;
    e.x = a.x + b.x; e.y = a.y + b.y; e.z = a.z + b.z; e.w = a.w + b.w;
    e.x = e.x > 0.f ? e.x : 0.2f * e.x;
    e.y = e.y > 0.f ? e.y : 0.2f * e.y;
    e.z = e.z > 0.f ? e.z : 0.2f * e.z;
    e.w = e.w > 0.f ? e.w : 0.2f * e.w;
    e.x = __expf(e.x); e.y = __expf(e.y); e.z = __expf(e.z); e.w = __expf(e.w);
    q4[j] = e;
}

__global__ __launch_bounds__(256) void k_eq2(const int* __restrict__ csrc,
                                             const int* __restrict__ cdst,
                                             const float* __restrict__ s2s,
                                             const float* __restrict__ s2d,
                                             float* __restrict__ q2, int E,
                                             int Bper, size_t s1_str, size_t q2_str) {
    int blk = blockIdx.x, pass = 0;
    if (blk >= Bper) { pass = 1; blk -= Bper; }
    s2s += (size_t)pass * s1_str;
    s2d += (size_t)pass * s1_str;
    q2 += (size_t)pass * q2_str;
    int j = blk * 256 + threadIdx.x;
    if (j >= E) return;
    float e = s2s[csrc[j]] + s2d[cdst[j]];
    e = e > 0.f ? e : 0.2f * e;
    q2[j] = __expf(e);
}

// ------------------------- layer-1 edge aggregation ------------------------
// Wave per dst node; lane owns ch 4l..4l+3 (head = l>>4). 8-deep unrolled
// independent gathers; q loaded as the lane's head scalar (qp[4j+hs]).
__global__ __launch_bounds__(256) void k_agg1(const int* __restrict__ rowptr,
                                              const int* __restrict__ csrc,
                                              const float* __restrict__ q4f,
                                              const f16* __restrict__ h1h,
                                              const float* __restrict__ b1,
                                              const float* __restrict__ p1,
                                              f16* __restrict__ x1h, int N,
                                              int Bper, size_t q4f_str, size_t h1_str,
                                              size_t x1_str) {
    int blk = blockIdx.x, pass = 0;
    if (blk >= Bper) { pass = 1; blk -= Bper; }
    q4f += (size_t)pass * q4f_str;
    h1h += (size_t)pass * h1_str;
    x1h += (size_t)pass * x1_str;
    int n = (blk * 256 + threadIdx.x) >> 6;
    int lane = threadIdx.x & 63;
    if (n >= N) return;
    int hs = lane >> 4;
    const float* qp = q4f + hs;
    int beg = rowptr[n], end = rowptr[n + 1];
    float ax = 0.f, ay = 0.f, az = 0.f, aw = 0.f, z = 0.f;
    int j = beg;
    for (; j + 8 <= end; j += 8) {
        int s[8]; float q[8]; uint2 u[8];
#pragma unroll
        for (int k = 0; k < 8; ++k) s[k] = csrc[j + k];
#pragma unroll
        for (int k = 0; k < 8; ++k) q[k] = qp[4 * (j + k)];
#pragma unroll
        for (int k = 0; k < 8; ++k)
            u[k] = reinterpret_cast<const uint2*>(h1h + (size_t)s[k] * 256)[lane];
#pragma unroll
        for (int k = 0; k < 8; ++k) {
            float2 fa = __half22float2(*reinterpret_cast<__half2*>(&u[k].x));
            float2 fb = __half22float2(*reinterpret_cast<__half2*>(&u[k].y));
            z += q[k];
            ax += q[k] * fa.x;
            ay += q[k] * fa.y;
            az += q[k] * fb.x;
            aw += q[k] * fb.y;
        }
    }
    for (; j < end; ++j) {
        int s = csrc[j];
        float q = qp[4 * j];
        uint2 u = reinterpret_cast<const uint2*>(h1h + (size_t)s * 256)[lane];
        float2 fa = __half22float2(*reinterpret_cast<__half2*>(&u.x));
        float2 fb = __half22float2(*reinterpret_cast<__half2*>(&u.y));
        z += q;
        ax += q * fa.x;
        ay += q * fa.y;
        az += q * fb.x;
        aw += q * fb.y;
    }
    float rz = 1.f / (z + 1e-16f);
    float4 bb = reinterpret_cast<const float4*>(b1)[lane];
    float4 pp = reinterpret_cast<const float4*>(p1)[lane];
    float4 v;
    v.x = ax * rz + bb.x;
    v.y = ay * rz + bb.y;
    v.z = az * rz + bb.z;
    v.w = aw * rz + bb.w;
    v.x = v.x > 0.f ? v.x : pp.x * v.x;
    v.y = v.y > 0.f ? v.y : pp.y * v.y;
    v.z = v.z > 0.f ? v.z : pp.z * v.z;
    v.w = v.w > 0.f ? v.w : pp.w * v.w;
    f16x4 hv;
    hv[0] = (f16)v.x; hv[1] = (f16)v.y; hv[2] = (f16)v.z; hv[3] = (f16)v.w;
    *reinterpret_cast<f16x4*>(x1h + (size_t)n * 256 + lane * 4) = hv;
}

// ------------------------- layer-2 edge aggregation ------------------------
__global__ __launch_bounds__(256) void k_agg2(const int* __restrict__ rowptr,
                                              const int* __restrict__ csrc,
                                              const float* __restrict__ q2,
                                              const float* __restrict__ h2,
                                              const float* __restrict__ b2,
                                              const float* __restrict__ p2,
                                              float* __restrict__ x2a_out,
                                              float* __restrict__ x2b_out, int N,
                                              int Bper, size_t q2_str, size_t h2_str) {
    int blk = blockIdx.x, pass = 0;
    if (blk >= Bper) { pass = 1; blk -= Bper; }
    q2 += (size_t)pass * q2_str;
    h2 += (size_t)pass * h2_str;
    float* x2 = pass ? x2b_out : x2a_out;
    int n = (blk * 256 + threadIdx.x) >> 5;
    int c = threadIdx.x & 31;
    if (n >= N) return;
    int beg = rowptr[n], end = rowptr[n + 1];
    float acc = 0.f, z = 0.f;
    int j = beg;
    for (; j + 8 <= end; j += 8) {
        int s[8]; float q[8]; float h[8];
#pragma unroll
        for (int k = 0; k < 8; ++k) s[k] = csrc[j + k];
#pragma unroll
        for (int k = 0; k < 8; ++k) q[k] = q2[j + k];
#pragma unroll
        for (int k = 0; k < 8; ++k) h[k] = h2[(size_t)s[k] * 32 + c];
#pragma unroll
        for (int k = 0; k < 8; ++k) {
            z += q[k];
            acc += q[k] * h[k];
        }
    }
    for (; j < end; ++j) {
        int s = csrc[j];
        float q = q2[j];
        z += q;
        acc += q * h2[(size_t)s * 32 + c];
    }
    float v = acc / (z + 1e-16f) + b2[c];
    x2[(size_t)n * 32 + c] = v > 0.f ? v : p2[c] * v;
}

// ------------------------------- heads -------------------------------------
__global__ void k_wsum(const float* __restrict__ advw, const float* __restrict__ advb,
                       float* __restrict__ wsum, float* __restrict__ bsum) {
    int c = threadIdx.x;  // 32 threads
    float s = 0.f;
    for (int j = 0; j < 32; ++j) s += advw[c * 32 + j];
    wsum[c] = s;
    float b = advb[c];
    for (int m = 16; m; m >>= 1) b += __shfl_xor(b, m);
    if (c == 0) bsum[0] = b;
}

__global__ __launch_bounds__(256) void k_heads(const float* __restrict__ x2o,
                                               const float* __restrict__ x2a,
                                               const float* __restrict__ Wq,
                                               const float* __restrict__ Wk,
                                               const float* __restrict__ wsum,
                                               const float* __restrict__ bsum,
                                               float* __restrict__ o_q,
                                               float* __restrict__ o_k,
                                               float* __restrict__ o_x2,
                                               float* __restrict__ o_logits, int N) {
    int n = (blockIdx.x * 256 + threadIdx.x) >> 5;
    int o = threadIdx.x & 31;
    if (n >= N) return;
    float xo = x2o[(size_t)n * 32 + o];
    float xa = x2a[(size_t)n * 32 + o];
    float accq = 0.f, acck = 0.f;
    for (int c = 0; c < 32; ++c) {
        float xoc = __shfl(xo, c, 32);
        float xac = __shfl(xa, c, 32);
        accq += xoc * Wq[c * 32 + o];
        acck += xac * Wk[c * 32 + o];
    }
    float sq = accq * accq, sk = acck * acck;
    for (int m = 16; m; m >>= 1) {
        sq += __shfl_xor(sq, m);
        sk += __shfl_xor(sk, m);
    }
    o_q[(size_t)n * 32 + o] = accq / (sqrtf(sq) + 1e-12f);
    o_k[(size_t)n * 32 + o] = acck / (sqrtf(sk) + 1e-12f);
    o_x2[(size_t)n * 32 + o] = xo;
    float vo = xo * wsum[o], va = xa * wsum[o];
    for (int m = 16; m; m >>= 1) {
        vo += __shfl_xor(vo, m);
        va += __shfl_xor(va, m);
    }
    if (o == 0) {
        o_logits[n] = vo + bsum[0];
        o_logits[N + n] = va + bsum[0];
    }
}

__global__ __launch_bounds__(256) void k_fusion(const float* __restrict__ x2o,
                                                const int* __restrict__ idx,
                                                const float* __restrict__ Wf,
                                                const float* __restrict__ bfb,
                                                const float* __restrict__ Wlog,
                                                const float* __restrict__ blog,
                                                const float* __restrict__ Wlog1,
                                                const float* __restrict__ blog1,
                                                float* __restrict__ out_log,
                                                float* __restrict__ out_log1, int NB) {
    int i = (blockIdx.x * 256 + threadIdx.x) >> 5;
    int o = threadIdx.x & 31;
    if (i >= NB) return;
    int i1 = idx[i], i2 = idx[NB + i];
    float e1 = x2o[(size_t)i1 * 32 + o];
    float e2 = x2o[(size_t)i2 * 32 + o];
    float acc = bfb[o];
    for (int c = 0; c < 32; ++c) {
        acc += __shfl(e1, c, 32) * Wf[c * 32 + o];
        acc += __shfl(e2, c, 32) * Wf[(32 + c) * 32 + o];
    }
    float h = acc > 0.f ? acc : 0.f;
    float v0 = h * Wlog[o];
    float v1 = h * Wlog1[o];
    for (int m = 16; m; m >>= 1) {
        v0 += __shfl_xor(v0, m);
        v1 += __shfl_xor(v1, m);
    }
    if (o == 0) {
        out_log[i] = v0 + blog[0];
        out_log1[i] = v1 + blog1[0];
    }
}

// ---------------------------------------------------------------------------
extern "C" void kernel_launch(void* const* d_in, const int* in_sizes, int n_in,
                              void* d_out, int out_size, void* d_ws, size_t ws_size,
                              hipStream_t stream) {
    const float* x_o = (const float*)d_in[0];
    const float* x_a = (const float*)d_in[1];
    const float* W1 = (const float*)d_in[2];
    const float* a_src1 = (const float*)d_in[3];
    const float* a_dst1 = (const float*)d_in[4];
    const float* b1 = (const float*)d_in[5];
    const float* p1 = (const float*)d_in[6];
    const float* W2 = (const float*)d_in[7];
    const float* a_src2 = (const float*)d_in[8];
    const float* a_dst2 = (const float*)d_in[9];
    const float* b2 = (const float*)d_in[10];
    const float* p2 = (const float*)d_in[11];
    const float* adv_w = (const float*)d_in[12];
    const float* adv_b = (const float*)d_in[13];
    const float* Wq = (const float*)d_in[14];
    const float* Wk = (const float*)d_in[15];
    const float* Wf = (const float*)d_in[16];
    const float* bf_ = (const float*)d_in[17];
    const float* Wlog = (const float*)d_in[18];
    const float* blog = (const float*)d_in[19];
    const float* Wlog1 = (const float*)d_in[20];
    const float* blog1 = (const float*)d_in[21];
    const int* ei = (const int*)d_in[22];
    const int* idx = (const int*)d_in[23];

    const int N = in_sizes[0] / 128;
    const int E = in_sizes[22] / 2;
    const int NB = in_sizes[23] / 2;
    const int* esrc = ei;
    const int* edst = ei + E;
    const int GS = (N + 255) / 256;
    const int GE = (E + 255) / 256;
    const int rows_pad = (N + 63) & ~63;

    // --- workspace layout: try merged (both passes resident), else per-pass.
    auto total_for = [&](int P) -> size_t {
        auto rup = [](size_t b) { return (b + 255) & ~(size_t)255; };
        size_t t = 0;
        t += rup((size_t)P * rows_pad * 128 * 2);   // xh
        t += rup((size_t)P * N * 256 * 2);          // h1h
        t += rup((size_t)P * rows_pad * 256 * 2);   // x1h
        t += rup((size_t)16 * 4 * 64 * 8 * 2);      // wpk1
        t += rup((size_t)2 * 8 * 64 * 8 * 2);       // wpk2
        t += rup((size_t)P * N * 32 * 4);           // h2
        t += rup((size_t)N * 32 * 4) * 2;           // x2o, x2a
        t += rup((size_t)P * N * 4 * 4) * 2;        // ssrc, sdst
        t += rup((size_t)P * N * 4) * 2;            // s2s, s2d
        t += rup((size_t)(N + 1) * 4);              // rowptr
        t += rup((size_t)N * 4);                    // cursor
        t += rup(256 * 4);                          // bsums
        t += rup((size_t)E * 4) * 2;                // csrc, cdst
        t += rup((size_t)P * E * 16);               // q4
        t += rup((size_t)P * E * 4);                // q2
        t += rup(32 * 4) + rup(4);                  // wsum, bsum
        return t;
    };
    const int P = (total_for(2) <= ws_size) ? 2 : 1;

    char* ws = (char*)d_ws;
    size_t off = 0;
    auto alloc = [&](size_t bytes) -> void* {
        void* p = ws + off;
        off += (bytes + 255) & ~(size_t)255;
        return p;
    };
    f16* xh = (f16*)alloc((size_t)P * rows_pad * 128 * 2);
    f16* h1h = (f16*)alloc((size_t)P * N * 256 * 2);
    f16* x1h = (f16*)alloc((size_t)P * rows_pad * 256 * 2);
    f16* wpk1 = (f16*)alloc((size_t)16 * 4 * 64 * 8 * 2);
    f16* wpk2 = (f16*)alloc((size_t)2 * 8 * 64 * 8 * 2);
    float* h2 = (float*)alloc((size_t)P * N * 32 * 4);
    float* x2o = (float*)alloc((size_t)N * 32 * 4);
    float* x2a = (float*)alloc((size_t)N * 32 * 4);
    float* ssrc = (float*)alloc((size_t)P * N * 4 * 4);
    float* sdst = (float*)alloc((size_t)P * N * 4 * 4);
    float* s2s = (float*)alloc((size_t)P * N * 4);
    float* s2d = (float*)alloc((size_t)P * N * 4);
    int* rowptr = (int*)alloc((size_t)(N + 1) * 4);
    int* cursor = (int*)alloc((size_t)N * 4);
    int* bsums = (int*)alloc(256 * 4);
    int* csrc = (int*)alloc((size_t)E * 4);
    int* cdst = (int*)alloc((size_t)E * 4);
    float4* q4 = (float4*)alloc((size_t)P * E * 16);
    float* q2 = (float*)alloc((size_t)P * E * 4);
    float* wsum = (float*)alloc(32 * 4);
    float* bsum = (float*)alloc(4);

    // --- CSR build ---
    k_zero_i<<<GS, 256, 0, stream>>>(cursor, N);
    k_count<<<GE, 256, 0, stream>>>(edst, E, cursor);
    k_scan_local<<<GS, 256, 0, stream>>>(cursor, rowptr, bsums, N);
    k_scan_bsums<<<1, 256, 0, stream>>>(bsums, GS);
    k_scan_apply<<<GS, 256, 0, stream>>>(rowptr, bsums, cursor, N, E);
    k_fill<<<GE, 256, 0, stream>>>(esrc, edst, E, cursor, csrc, cdst);

    // --- weight packing (once) ---
    k_wpack<<<16, 256, 0, stream>>>(W1, wpk1, 128, 256);
    k_wpack<<<4, 256, 0, stream>>>(W2, wpk2, 256, 32);

    // strides (elements) between pass-0 and pass-1 halves
    const size_t xh_str = (size_t)rows_pad * 128;
    const size_t h1_str = (size_t)N * 256;
    const size_t x1_str = (size_t)rows_pad * 256;
    const size_t h2_str = (size_t)N * 32;
    const size_t s4_str = (size_t)N * 4;
    const size_t s1_str = (size_t)N;
    const size_t q4f_str = (size_t)E * 4;  // float units
    const size_t q2_str = (size_t)E;

    const int Bx = (rows_pad * 32 + 255) / 256;
    const int Bg = rows_pad / 64;
    const int Ba1 = (N + 3) / 4;
    const int Ba2 = (N + 7) / 8;

    if (P == 2) {
        k_xcvt<<<2 * Bx, 256, 0, stream>>>(x_o, x_a, xh, N, rows_pad, Bx, xh_str);
        k_gemm1m<<<2 * Bg, 256, 0, stream>>>(xh, wpk1, a_src1, a_dst1, h1h, ssrc, sdst, N,
                                             Bg, xh_str, h1_str, s4_str);
        k_eq1<<<2 * GE, 256, 0, stream>>>(csrc, cdst, ssrc, sdst, q4, E, GE, s4_str, (size_t)E);
        k_agg1<<<2 * Ba1, 256, 0, stream>>>(rowptr, csrc, (const float*)q4, h1h, b1, p1, x1h,
                                            N, Ba1, q4f_str, h1_str, x1_str);
        k_gemm2m<<<2 * Bg, 256, 0, stream>>>(x1h, wpk2, a_src2, a_dst2, h2, s2s, s2d, N,
                                             Bg, x1_str, h2_str, s1_str);
        k_eq2<<<2 * GE, 256, 0, stream>>>(csrc, cdst, s2s, s2d, q2, E, GE, s1_str, q2_str);
        k_agg2<<<2 * Ba2, 256, 0, stream>>>(rowptr, csrc, q2, h2, b2, p2, x2o, x2a, N,
                                            Ba2, q2_str, h2_str);
    } else {
        for (int pass = 0; pass < 2; ++pass) {
            const float* xin = (pass == 0) ? x_o : x_a;
            float* x2 = (pass == 0) ? x2o : x2a;
            k_xcvt<<<Bx, 256, 0, stream>>>(xin, xin, xh, N, rows_pad, Bx, 0);
            k_gemm1m<<<Bg, 256, 0, stream>>>(xh, wpk1, a_src1, a_dst1, h1h, ssrc, sdst, N,
                                             Bg, 0, 0, 0);
            k_eq1<<<GE, 256, 0, stream>>>(csrc, cdst, ssrc, sdst, q4, E, GE, 0, 0);
            k_agg1<<<Ba1, 256, 0, stream>>>(rowptr, csrc, (const float*)q4, h1h, b1, p1, x1h,
                                            N, Ba1, 0, 0, 0);
            k_gemm2m<<<Bg, 256, 0, stream>>>(x1h, wpk2, a_src2, a_dst2, h2, s2s, s2d, N,
                                             Bg, 0, 0, 0);
            k_eq2<<<GE, 256, 0, stream>>>(csrc, cdst, s2s, s2d, q2, E, GE, 0, 0);
            k_agg2<<<Ba2, 256, 0, stream>>>(rowptr, csrc, q2, h2, b2, p2, x2, x2, N,
                                            Ba2, 0, 0);
        }
    }

    // --- output heads ---
    float* out = (float*)d_out;
    float* o_log = out;                        // [NB]
    float* o_q = o_log + NB;                   // [N*32]
    float* o_k = o_q + (size_t)N * 32;         // [N*32]
    float* o_x2 = o_k + (size_t)N * 32;        // [N*32]
    float* o_logits = o_x2 + (size_t)N * 32;   // [2N]
    float* o_log1 = o_logits + (size_t)2 * N;  // [NB]

    k_wsum<<<1, 32, 0, stream>>>(adv_w, adv_b, wsum, bsum);
    k_heads<<<(N + 7) / 8, 256, 0, stream>>>(x2o, x2a, Wq, Wk, wsum, bsum,
                                             o_q, o_k, o_x2, o_logits, N);
    k_fusion<<<(NB + 7) / 8, 256, 0, stream>>>(x2o, idx, Wf, bf_, Wlog, blog, Wlog1, blog1,
                                               o_log, o_log1, NB);
}

// Round 7
// 375.528 us; speedup vs baseline: 2.4746x; 1.0431x over previous
//
#include <hip/hip_runtime.h>
#include <hip/hip_bf16.h>
#include <hip/hip_fp16.h>

// ---------------------------------------------------------------------------
// GATEncoder on MI355X.
//   CSR-by-dst built once (hierarchical scan);
//   fp16 MFMA GEMMs (16x16x32_f16), W pre-packed to B-fragment order,
//     gemm1 converts f32 x -> fp16 in-register (no xcvt pass);
//   k_eq*: edge-parallel exp(leaky(score)) precompute, both passes per thread;
//   agg1/agg2: DUAL-PASS loops — 16 independent gathers in flight per wave
//     (8 per pass), shared index stream, shift-invariant softmax.
// Precision: fp16 payloads (rel 2^-11) on h1/x1 and GEMM inputs; f32 math.
// ---------------------------------------------------------------------------

typedef _Float16 f16;
typedef f16 f16x4 __attribute__((ext_vector_type(4)));
typedef f16 f16x8 __attribute__((ext_vector_type(8)));
typedef float f32x4 __attribute__((ext_vector_type(4)));

// ------------------------------ CSR build ----------------------------------
__global__ void k_zero_i(int* __restrict__ p, int n) {
    int i = blockIdx.x * 256 + threadIdx.x;
    if (i < n) p[i] = 0;
}

__global__ void k_count(const int* __restrict__ dst, int E, int* __restrict__ cnt) {
    int e = blockIdx.x * 256 + threadIdx.x;
    if (e < E) atomicAdd(&cnt[dst[e]], 1);
}

__global__ __launch_bounds__(256) void k_scan_local(const int* __restrict__ cnt,
                                                    int* __restrict__ rowptr,
                                                    int* __restrict__ bsums, int N) {
    __shared__ int t[256];
    int tid = threadIdx.x;
    int i = blockIdx.x * 256 + tid;
    int v = (i < N) ? cnt[i] : 0;
    t[tid] = v;
    __syncthreads();
    for (int off = 1; off < 256; off <<= 1) {
        int u = (tid >= off) ? t[tid - off] : 0;
        __syncthreads();
        t[tid] += u;
        __syncthreads();
    }
    if (i < N) rowptr[i] = t[tid] - v;  // exclusive within block
    if (tid == 255) bsums[blockIdx.x] = t[255];
}

__global__ __launch_bounds__(256) void k_scan_bsums(int* __restrict__ bsums, int G) {
    __shared__ int t[256];
    int tid = threadIdx.x;
    int v = (tid < G) ? bsums[tid] : 0;
    t[tid] = v;
    __syncthreads();
    for (int off = 1; off < 256; off <<= 1) {
        int u = (tid >= off) ? t[tid - off] : 0;
        __syncthreads();
        t[tid] += u;
        __syncthreads();
    }
    if (tid < G) bsums[tid] = t[tid] - v;  // exclusive
}

__global__ __launch_bounds__(256) void k_scan_apply(int* __restrict__ rowptr,
                                                    const int* __restrict__ bsums,
                                                    int* __restrict__ cursor, int N, int E) {
    int i = blockIdx.x * 256 + threadIdx.x;
    if (i < N) {
        int r = rowptr[i] + bsums[blockIdx.x];
        rowptr[i] = r;
        cursor[i] = r;
    }
    if (i == 0) rowptr[N] = E;
}

__global__ void k_fill(const int* __restrict__ src, const int* __restrict__ dst, int E,
                       int* __restrict__ cursor, int* __restrict__ csrc,
                       int* __restrict__ cdst) {
    int e = blockIdx.x * 256 + threadIdx.x;
    if (e < E) {
        int d = dst[e];
        int pos = atomicAdd(&cursor[d], 1);
        csrc[pos] = src[e];
        cdst[pos] = d;
    }
}

// --------------------------- weight packing --------------------------------
// W f32 [K][Ncols] -> blob-packed fp16 B-fragments. One launch packs both.
__device__ __forceinline__ void wpack_one(const float* __restrict__ W,
                                          f16* __restrict__ wpk, int K, int Ncols, int b) {
    int F = K >> 5;
    int total = (Ncols >> 4) * F * 64;
    if (b >= total) return;
    int l = b & 63, tf = b >> 6;
    int t = tf / F, f = tf % F;
    int col = t * 16 + (l & 15);
    int k0 = f * 32 + (l >> 4) * 8;
    f16x8 h;
#pragma unroll
    for (int j = 0; j < 8; ++j) h[j] = (f16)W[(size_t)(k0 + j) * Ncols + col];
    *reinterpret_cast<f16x8*>(wpk + (size_t)b * 8) = h;
}

__global__ __launch_bounds__(256) void k_wpack_all(const float* __restrict__ W1,
                                                   f16* __restrict__ wpk1,
                                                   const float* __restrict__ W2,
                                                   f16* __restrict__ wpk2) {
    int blk = blockIdx.x;
    if (blk < 16) wpack_one(W1, wpk1, 128, 256, blk * 256 + threadIdx.x);
    else wpack_one(W2, wpk2, 256, 32, (blk - 16) * 256 + threadIdx.x);
}

// --------------------------- layer-1 MFMA GEMM + scores --------------------
// Reads f32 x directly; converts to fp16 A-frags in-register.
__global__ __launch_bounds__(256) void k_gemm1m(const float* __restrict__ xa,
                                                const float* __restrict__ xb,
                                                const f16* __restrict__ wpk,
                                                const float* __restrict__ as1,
                                                const float* __restrict__ ad1,
                                                f16* __restrict__ h1h,
                                                float* __restrict__ ssrc,
                                                float* __restrict__ sdst, int N,
                                                int Bper, size_t h1_str, size_t s4_str) {
    int blk = blockIdx.x, pass = 0;
    if (blk >= Bper) { pass = 1; blk -= Bper; }
    const float* x = pass ? xb : xa;
    h1h += (size_t)pass * h1_str;
    ssrc += (size_t)pass * s4_str;
    sdst += (size_t)pass * s4_str;
    int tid = threadIdx.x;
    int w = tid >> 6, l = tid & 63;
    int c16 = l & 15, kg = l >> 4;
    int n0 = blk * 64 + w * 16;
    int arow = n0 + c16;
    f16x8 af[4];
    if (arow < N) {
        const float4* xr4 = reinterpret_cast<const float4*>(x + (size_t)arow * 128 + kg * 8);
#pragma unroll
        for (int f = 0; f < 4; ++f) {
            float4 v0 = xr4[f * 8];
            float4 v1 = xr4[f * 8 + 1];
            af[f][0] = (f16)v0.x; af[f][1] = (f16)v0.y;
            af[f][2] = (f16)v0.z; af[f][3] = (f16)v0.w;
            af[f][4] = (f16)v1.x; af[f][5] = (f16)v1.y;
            af[f][6] = (f16)v1.z; af[f][7] = (f16)v1.w;
        }
    } else {
#pragma unroll
        for (int f = 0; f < 4; ++f)
#pragma unroll
            for (int j = 0; j < 8; ++j) af[f][j] = (f16)0.f;
    }
    float asv[16], adv[16];
#pragma unroll
    for (int t = 0; t < 16; ++t) {
        asv[t] = as1[t * 16 + c16];
        adv[t] = ad1[t * 16 + c16];
    }
    const f16x8* wp = reinterpret_cast<const f16x8*>(wpk);
    f32x4 acc[16];
#pragma unroll
    for (int t = 0; t < 16; ++t) {
        f32x4 a = {0.f, 0.f, 0.f, 0.f};
        a = __builtin_amdgcn_mfma_f32_16x16x32_f16(af[0], wp[(t * 4 + 0) * 64 + l], a, 0, 0, 0);
        a = __builtin_amdgcn_mfma_f32_16x16x32_f16(af[1], wp[(t * 4 + 1) * 64 + l], a, 0, 0, 0);
        a = __builtin_amdgcn_mfma_f32_16x16x32_f16(af[2], wp[(t * 4 + 2) * 64 + l], a, 0, 0, 0);
        a = __builtin_amdgcn_mfma_f32_16x16x32_f16(af[3], wp[(t * 4 + 3) * 64 + l], a, 0, 0, 0);
        acc[t] = a;
    }
    int rbase = n0 + kg * 4;
#pragma unroll
    for (int i = 0; i < 4; ++i) {
        int row = rbase + i;
        if (row < N) {
            f16* hr = h1h + (size_t)row * 256 + c16;
#pragma unroll
            for (int t = 0; t < 16; ++t) hr[t * 16] = (f16)acc[t][i];
        }
    }
#pragma unroll
    for (int i = 0; i < 4; ++i) {
        int row = rbase + i;
#pragma unroll
        for (int hh = 0; hh < 4; ++hh) {
            float ps = 0.f, pd = 0.f;
#pragma unroll
            for (int tt = 0; tt < 4; ++tt) {
                int t = hh * 4 + tt;
                ps += acc[t][i] * asv[t];
                pd += acc[t][i] * adv[t];
            }
#pragma unroll
            for (int m = 1; m < 16; m <<= 1) {
                ps += __shfl_xor(ps, m);
                pd += __shfl_xor(pd, m);
            }
            if (c16 == 0 && row < N) {
                ssrc[row * 4 + hh] = ps;
                sdst[row * 4 + hh] = pd;
            }
        }
    }
}

// --------------------------- layer-2 MFMA GEMM + scores --------------------
__global__ __launch_bounds__(256) void k_gemm2m(const f16* __restrict__ x1h,
                                                const f16* __restrict__ wpk2,
                                                const float* __restrict__ as2,
                                                const float* __restrict__ ad2,
                                                float* __restrict__ h2,
                                                float* __restrict__ s2s,
                                                float* __restrict__ s2d, int N,
                                                int Bper, size_t x1_str, size_t h2_str,
                                                size_t s1_str) {
    int blk = blockIdx.x, pass = 0;
    if (blk >= Bper) { pass = 1; blk -= Bper; }
    x1h += (size_t)pass * x1_str;
    h2 += (size_t)pass * h2_str;
    s2s += (size_t)pass * s1_str;
    s2d += (size_t)pass * s1_str;
    int tid = threadIdx.x;
    int w = tid >> 6, l = tid & 63;
    int c16 = l & 15, kg = l >> 4;
    int n0 = blk * 64 + w * 16;
    const f16* xrow = x1h + (size_t)(n0 + c16) * 256 + kg * 8;
    f16x8 af[8];
#pragma unroll
    for (int f = 0; f < 8; ++f) af[f] = *reinterpret_cast<const f16x8*>(xrow + f * 32);
    const f16x8* wp = reinterpret_cast<const f16x8*>(wpk2);
    f32x4 acc[2];
#pragma unroll
    for (int t = 0; t < 2; ++t) {
        f32x4 a = {0.f, 0.f, 0.f, 0.f};
#pragma unroll
        for (int f = 0; f < 8; ++f)
            a = __builtin_amdgcn_mfma_f32_16x16x32_f16(af[f], wp[(t * 8 + f) * 64 + l], a, 0, 0, 0);
        acc[t] = a;
    }
    float asv[2], adv[2];
#pragma unroll
    for (int t = 0; t < 2; ++t) {
        asv[t] = as2[t * 16 + c16];
        adv[t] = ad2[t * 16 + c16];
    }
    int rbase = n0 + kg * 4;
#pragma unroll
    for (int i = 0; i < 4; ++i) {
        int row = rbase + i;
        if (row < N) {
            float* hr = h2 + (size_t)row * 32 + c16;
#pragma unroll
            for (int t = 0; t < 2; ++t) hr[t * 16] = acc[t][i];
        }
        float ps = acc[0][i] * asv[0] + acc[1][i] * asv[1];
        float pd = acc[0][i] * adv[0] + acc[1][i] * adv[1];
#pragma unroll
        for (int m = 1; m < 16; m <<= 1) {
            ps += __shfl_xor(ps, m);
            pd += __shfl_xor(pd, m);
        }
        if (c16 == 0 && row < N) {
            s2s[row] = ps;
            s2d[row] = pd;
        }
    }
}

// --------------- edge-parallel score precompute (both passes) --------------
__global__ __launch_bounds__(256) void k_eq1(const int* __restrict__ csrc,
                                             const int* __restrict__ cdst,
                                             const float* __restrict__ ssrc,
                                             const float* __restrict__ sdst,
                                             float4* __restrict__ q4, int E,
                                             size_t s4_str, size_t q4_str) {
    int j = blockIdx.x * 256 + threadIdx.x;
    if (j >= E) return;
    int s = csrc[j], d = cdst[j];
#pragma unroll
    for (int pass = 0; pass < 2; ++pass) {
        const float* sp = ssrc + pass * s4_str;
        const float* dp = sdst + pass * s4_str;
        float4 a = reinterpret_cast<const float4*>(sp)[s];
        float4 b = reinterpret_cast<const float4*>(dp)[d];
        float4 e;
        e.x = a.x + b.x; e.y = a.y + b.y; e.z = a.z + b.z; e.w = a.w + b.w;
        e.x = e.x > 0.f ? e.x : 0.2f * e.x;
        e.y = e.y > 0.f ? e.y : 0.2f * e.y;
        e.z = e.z > 0.f ? e.z : 0.2f * e.z;
        e.w = e.w > 0.f ? e.w : 0.2f * e.w;
        e.x = __expf(e.x); e.y = __expf(e.y); e.z = __expf(e.z); e.w = __expf(e.w);
        (q4 + pass * q4_str)[j] = e;
    }
}

__global__ __launch_bounds__(256) void k_eq2(const int* __restrict__ csrc,
                                             const int* __restrict__ cdst,
                                             const float* __restrict__ s2s,
                                             const float* __restrict__ s2d,
                                             float* __restrict__ q2, int E,
                                             size_t s1_str, size_t q2_str) {
    int j = blockIdx.x * 256 + threadIdx.x;
    if (j >= E) return;
    int s = csrc[j], d = cdst[j];
#pragma unroll
    for (int pass = 0; pass < 2; ++pass) {
        float e = (s2s + pass * s1_str)[s] + (s2d + pass * s1_str)[d];
        e = e > 0.f ? e : 0.2f * e;
        (q2 + pass * q2_str)[j] = __expf(e);
    }
}

// ------------------------- layer-1 edge aggregation ------------------------
// Wave per dst node, BOTH passes in one loop: 16 independent 8B/lane row
// gathers in flight per 8-chunk. n is wave-uniform (readfirstlane) so
// rowptr/csrc become scalar loads.
__global__ __launch_bounds__(256) void k_agg1(const int* __restrict__ rowptr,
                                              const int* __restrict__ csrc,
                                              const float* __restrict__ q4f,
                                              const f16* __restrict__ h1h,
                                              const float* __restrict__ b1,
                                              const float* __restrict__ p1,
                                              f16* __restrict__ x1h, int N,
                                              size_t q4f_str, size_t h1_str,
                                              size_t x1_str) {
    int n = __builtin_amdgcn_readfirstlane((blockIdx.x * 256 + threadIdx.x) >> 6);
    int lane = threadIdx.x & 63;
    if (n >= N) return;
    int hs = lane >> 4;
    const float* qp0 = q4f + hs;
    const float* qp1 = q4f + q4f_str + hs;
    const f16* hp1 = h1h + h1_str;
    int beg = rowptr[n], end = rowptr[n + 1];
    float a0x = 0, a0y = 0, a0z = 0, a0w = 0, z0 = 0;
    float a1x = 0, a1y = 0, a1z = 0, a1w = 0, z1 = 0;
    int j = beg;
    for (; j + 8 <= end; j += 8) {
        int s[8]; float q0[8], q1[8]; uint2 u0[8], u1[8];
#pragma unroll
        for (int k = 0; k < 8; ++k) s[k] = csrc[j + k];
#pragma unroll
        for (int k = 0; k < 8; ++k) q0[k] = qp0[4 * (j + k)];
#pragma unroll
        for (int k = 0; k < 8; ++k) q1[k] = qp1[4 * (j + k)];
#pragma unroll
        for (int k = 0; k < 8; ++k)
            u0[k] = reinterpret_cast<const uint2*>(h1h + (size_t)s[k] * 256)[lane];
#pragma unroll
        for (int k = 0; k < 8; ++k)
            u1[k] = reinterpret_cast<const uint2*>(hp1 + (size_t)s[k] * 256)[lane];
#pragma unroll
        for (int k = 0; k < 8; ++k) {
            float2 fa = __half22float2(*reinterpret_cast<__half2*>(&u0[k].x));
            float2 fb = __half22float2(*reinterpret_cast<__half2*>(&u0[k].y));
            z0 += q0[k];
            a0x += q0[k] * fa.x; a0y += q0[k] * fa.y;
            a0z += q0[k] * fb.x; a0w += q0[k] * fb.y;
            float2 ga = __half22float2(*reinterpret_cast<__half2*>(&u1[k].x));
            float2 gb = __half22float2(*reinterpret_cast<__half2*>(&u1[k].y));
            z1 += q1[k];
            a1x += q1[k] * ga.x; a1y += q1[k] * ga.y;
            a1z += q1[k] * gb.x; a1w += q1[k] * gb.y;
        }
    }
    for (; j < end; ++j) {
        int s = csrc[j];
        float q0 = qp0[4 * j], q1 = qp1[4 * j];
        uint2 u0 = reinterpret_cast<const uint2*>(h1h + (size_t)s * 256)[lane];
        uint2 u1 = reinterpret_cast<const uint2*>(hp1 + (size_t)s * 256)[lane];
        float2 fa = __half22float2(*reinterpret_cast<__half2*>(&u0.x));
        float2 fb = __half22float2(*reinterpret_cast<__half2*>(&u0.y));
        z0 += q0;
        a0x += q0 * fa.x; a0y += q0 * fa.y; a0z += q0 * fb.x; a0w += q0 * fb.y;
        float2 ga = __half22float2(*reinterpret_cast<__half2*>(&u1.x));
        float2 gb = __half22float2(*reinterpret_cast<__half2*>(&u1.y));
        z1 += q1;
        a1x += q1 * ga.x; a1y += q1 * ga.y; a1z += q1 * gb.x; a1w += q1 * gb.y;
    }
    float4 bb = reinterpret_cast<const float4*>(b1)[lane];
    float4 pp = reinterpret_cast<const float4*>(p1)[lane];
    {
        float rz = 1.f / (z0 + 1e-16f);
        float4 v;
        v.x = a0x * rz + bb.x; v.y = a0y * rz + bb.y;
        v.z = a0z * rz + bb.z; v.w = a0w * rz + bb.w;
        v.x = v.x > 0.f ? v.x : pp.x * v.x;
        v.y = v.y > 0.f ? v.y : pp.y * v.y;
        v.z = v.z > 0.f ? v.z : pp.z * v.z;
        v.w = v.w > 0.f ? v.w : pp.w * v.w;
        f16x4 hv;
        hv[0] = (f16)v.x; hv[1] = (f16)v.y; hv[2] = (f16)v.z; hv[3] = (f16)v.w;
        *reinterpret_cast<f16x4*>(x1h + (size_t)n * 256 + lane * 4) = hv;
    }
    {
        float rz = 1.f / (z1 + 1e-16f);
        float4 v;
        v.x = a1x * rz + bb.x; v.y = a1y * rz + bb.y;
        v.z = a1z * rz + bb.z; v.w = a1w * rz + bb.w;
        v.x = v.x > 0.f ? v.x : pp.x * v.x;
        v.y = v.y > 0.f ? v.y : pp.y * v.y;
        v.z = v.z > 0.f ? v.z : pp.z * v.z;
        v.w = v.w > 0.f ? v.w : pp.w * v.w;
        f16x4 hv;
        hv[0] = (f16)v.x; hv[1] = (f16)v.y; hv[2] = (f16)v.z; hv[3] = (f16)v.w;
        *reinterpret_cast<f16x4*>(x1h + x1_str + (size_t)n * 256 + lane * 4) = hv;
    }
}

// ------------------------- layer-2 edge aggregation ------------------------
// 32-lane group per dst node, BOTH passes per loop (16 gathers in flight).
__global__ __launch_bounds__(256) void k_agg2(const int* __restrict__ rowptr,
                                              const int* __restrict__ csrc,
                                              const float* __restrict__ q2,
                                              const float* __restrict__ h2,
                                              const float* __restrict__ b2,
                                              const float* __restrict__ p2,
                                              float* __restrict__ x2a_out,
                                              float* __restrict__ x2b_out, int N,
                                              size_t q2_str, size_t h2_str) {
    int n = (blockIdx.x * 256 + threadIdx.x) >> 5;
    int c = threadIdx.x & 31;
    if (n >= N) return;
    const float* qb = q2 + q2_str;
    const float* hb = h2 + h2_str;
    int beg = rowptr[n], end = rowptr[n + 1];
    float acc0 = 0.f, zz0 = 0.f, acc1 = 0.f, zz1 = 0.f;
    int j = beg;
    for (; j + 8 <= end; j += 8) {
        int s[8]; float qa[8], qc[8], ha[8], hc[8];
#pragma unroll
        for (int k = 0; k < 8; ++k) s[k] = csrc[j + k];
#pragma unroll
        for (int k = 0; k < 8; ++k) qa[k] = q2[j + k];
#pragma unroll
        for (int k = 0; k < 8; ++k) qc[k] = qb[j + k];
#pragma unroll
        for (int k = 0; k < 8; ++k) ha[k] = h2[(size_t)s[k] * 32 + c];
#pragma unroll
        for (int k = 0; k < 8; ++k) hc[k] = hb[(size_t)s[k] * 32 + c];
#pragma unroll
        for (int k = 0; k < 8; ++k) {
            zz0 += qa[k]; acc0 += qa[k] * ha[k];
            zz1 += qc[k]; acc1 += qc[k] * hc[k];
        }
    }
    for (; j < end; ++j) {
        int s = csrc[j];
        float q0 = q2[j], q1 = qb[j];
        zz0 += q0; acc0 += q0 * h2[(size_t)s * 32 + c];
        zz1 += q1; acc1 += q1 * hb[(size_t)s * 32 + c];
    }
    float bbv = b2[c], ppv = p2[c];
    float v0 = acc0 / (zz0 + 1e-16f) + bbv;
    x2a_out[(size_t)n * 32 + c] = v0 > 0.f ? v0 : ppv * v0;
    float v1 = acc1 / (zz1 + 1e-16f) + bbv;
    x2b_out[(size_t)n * 32 + c] = v1 > 0.f ? v1 : ppv * v1;
}

// ------------------------------- heads -------------------------------------
// per node (32-lane group): q/k projections (l2-norm), x2 copy, adv sums.
// wsum/bsum computed in-register per thread (adv_w row sums).
__global__ __launch_bounds__(256) void k_heads(const float* __restrict__ x2o,
                                               const float* __restrict__ x2a,
                                               const float* __restrict__ Wq,
                                               const float* __restrict__ Wk,
                                               const float* __restrict__ advw,
                                               const float* __restrict__ advb,
                                               float* __restrict__ o_q,
                                               float* __restrict__ o_k,
                                               float* __restrict__ o_x2,
                                               float* __restrict__ o_logits, int N) {
    int n = (blockIdx.x * 256 + threadIdx.x) >> 5;
    int o = threadIdx.x & 31;
    if (n >= N) return;
    float ws = 0.f;
    {
        const float4* aw4 = reinterpret_cast<const float4*>(advw + o * 32);
#pragma unroll
        for (int t = 0; t < 8; ++t) {
            float4 v = aw4[t];
            ws += v.x + v.y + v.z + v.w;
        }
    }
    float bs = advb[o];
    for (int m = 16; m; m >>= 1) bs += __shfl_xor(bs, m);
    float xo = x2o[(size_t)n * 32 + o];
    float xa = x2a[(size_t)n * 32 + o];
    float accq = 0.f, acck = 0.f;
    for (int c = 0; c < 32; ++c) {
        float xoc = __shfl(xo, c, 32);
        float xac = __shfl(xa, c, 32);
        accq += xoc * Wq[c * 32 + o];
        acck += xac * Wk[c * 32 + o];
    }
    float sq = accq * accq, sk = acck * acck;
    for (int m = 16; m; m >>= 1) {
        sq += __shfl_xor(sq, m);
        sk += __shfl_xor(sk, m);
    }
    o_q[(size_t)n * 32 + o] = accq / (sqrtf(sq) + 1e-12f);
    o_k[(size_t)n * 32 + o] = acck / (sqrtf(sk) + 1e-12f);
    o_x2[(size_t)n * 32 + o] = xo;
    float vo = xo * ws, va = xa * ws;
    for (int m = 16; m; m >>= 1) {
        vo += __shfl_xor(vo, m);
        va += __shfl_xor(va, m);
    }
    if (o == 0) {
        o_logits[n] = vo + bs;
        o_logits[N + n] = va + bs;
    }
}

__global__ __launch_bounds__(256) void k_fusion(const float* __restrict__ x2o,
                                                const int* __restrict__ idx,
                                                const float* __restrict__ Wf,
                                                const float* __restrict__ bfb,
                                                const float* __restrict__ Wlog,
                                                const float* __restrict__ blog,
                                                const float* __restrict__ Wlog1,
                                                const float* __restrict__ blog1,
                                                float* __restrict__ out_log,
                                                float* __restrict__ out_log1, int NB) {
    int i = (blockIdx.x * 256 + threadIdx.x) >> 5;
    int o = threadIdx.x & 31;
    if (i >= NB) return;
    int i1 = idx[i], i2 = idx[NB + i];
    float e1 = x2o[(size_t)i1 * 32 + o];
    float e2 = x2o[(size_t)i2 * 32 + o];
    float acc = bfb[o];
    for (int c = 0; c < 32; ++c) {
        acc += __shfl(e1, c, 32) * Wf[c * 32 + o];
        acc += __shfl(e2, c, 32) * Wf[(32 + c) * 32 + o];
    }
    float h = acc > 0.f ? acc : 0.f;
    float v0 = h * Wlog[o];
    float v1 = h * Wlog1[o];
    for (int m = 16; m; m >>= 1) {
        v0 += __shfl_xor(v0, m);
        v1 += __shfl_xor(v1, m);
    }
    if (o == 0) {
        out_log[i] = v0 + blog[0];
        out_log1[i] = v1 + blog1[0];
    }
}

// ---------------------------------------------------------------------------
extern "C" void kernel_launch(void* const* d_in, const int* in_sizes, int n_in,
                              void* d_out, int out_size, void* d_ws, size_t ws_size,
                              hipStream_t stream) {
    const float* x_o = (const float*)d_in[0];
    const float* x_a = (const float*)d_in[1];
    const float* W1 = (const float*)d_in[2];
    const float* a_src1 = (const float*)d_in[3];
    const float* a_dst1 = (const float*)d_in[4];
    const float* b1 = (const float*)d_in[5];
    const float* p1 = (const float*)d_in[6];
    const float* W2 = (const float*)d_in[7];
    const float* a_src2 = (const float*)d_in[8];
    const float* a_dst2 = (const float*)d_in[9];
    const float* b2 = (const float*)d_in[10];
    const float* p2 = (const float*)d_in[11];
    const float* adv_w = (const float*)d_in[12];
    const float* adv_b = (const float*)d_in[13];
    const float* Wq = (const float*)d_in[14];
    const float* Wk = (const float*)d_in[15];
    const float* Wf = (const float*)d_in[16];
    const float* bf_ = (const float*)d_in[17];
    const float* Wlog = (const float*)d_in[18];
    const float* blog = (const float*)d_in[19];
    const float* Wlog1 = (const float*)d_in[20];
    const float* blog1 = (const float*)d_in[21];
    const int* ei = (const int*)d_in[22];
    const int* idx = (const int*)d_in[23];

    const int N = in_sizes[0] / 128;
    const int E = in_sizes[22] / 2;
    const int NB = in_sizes[23] / 2;
    const int* esrc = ei;
    const int* edst = ei + E;
    const int GS = (N + 255) / 256;
    const int GE = (E + 255) / 256;
    const int rows_pad = (N + 63) & ~63;

    char* ws = (char*)d_ws;
    size_t off = 0;
    auto alloc = [&](size_t bytes) -> void* {
        void* p = ws + off;
        off += (bytes + 255) & ~(size_t)255;
        return p;
    };
    f16* h1h = (f16*)alloc((size_t)2 * N * 256 * 2);
    f16* x1h = (f16*)alloc((size_t)2 * rows_pad * 256 * 2);
    f16* wpk1 = (f16*)alloc((size_t)16 * 4 * 64 * 8 * 2);
    f16* wpk2 = (f16*)alloc((size_t)2 * 8 * 64 * 8 * 2);
    float* h2 = (float*)alloc((size_t)2 * N * 32 * 4);
    float* x2o = (float*)alloc((size_t)N * 32 * 4);
    float* x2a = (float*)alloc((size_t)N * 32 * 4);
    float* ssrc = (float*)alloc((size_t)2 * N * 4 * 4);
    float* sdst = (float*)alloc((size_t)2 * N * 4 * 4);
    float* s2s = (float*)alloc((size_t)2 * N * 4);
    float* s2d = (float*)alloc((size_t)2 * N * 4);
    int* rowptr = (int*)alloc((size_t)(N + 1) * 4);
    int* cursor = (int*)alloc((size_t)N * 4);
    int* bsums = (int*)alloc(256 * 4);
    int* csrc = (int*)alloc((size_t)E * 4);
    int* cdst = (int*)alloc((size_t)E * 4);
    float4* q4 = (float4*)alloc((size_t)2 * E * 16);
    float* q2 = (float*)alloc((size_t)2 * E * 4);

    // --- CSR build ---
    k_zero_i<<<GS, 256, 0, stream>>>(cursor, N);
    k_count<<<GE, 256, 0, stream>>>(edst, E, cursor);
    k_scan_local<<<GS, 256, 0, stream>>>(cursor, rowptr, bsums, N);
    k_scan_bsums<<<1, 256, 0, stream>>>(bsums, GS);
    k_scan_apply<<<GS, 256, 0, stream>>>(rowptr, bsums, cursor, N, E);
    k_fill<<<GE, 256, 0, stream>>>(esrc, edst, E, cursor, csrc, cdst);

    // --- weight packing (one launch) ---
    k_wpack_all<<<20, 256, 0, stream>>>(W1, wpk1, W2, wpk2);

    // strides (elements) between pass-0 and pass-1 halves
    const size_t h1_str = (size_t)N * 256;
    const size_t x1_str = (size_t)rows_pad * 256;
    const size_t h2_str = (size_t)N * 32;
    const size_t s4_str = (size_t)N * 4;
    const size_t s1_str = (size_t)N;
    const size_t q4f_str = (size_t)E * 4;  // float units
    const size_t q2_str = (size_t)E;

    const int Bg = rows_pad / 64;
    const int Ba1 = (N + 3) / 4;
    const int Ba2 = (N + 7) / 8;

    k_gemm1m<<<2 * Bg, 256, 0, stream>>>(x_o, x_a, wpk1, a_src1, a_dst1, h1h, ssrc, sdst,
                                         N, Bg, h1_str, s4_str);
    k_eq1<<<GE, 256, 0, stream>>>(csrc, cdst, ssrc, sdst, q4, E, s4_str, (size_t)E);
    k_agg1<<<Ba1, 256, 0, stream>>>(rowptr, csrc, (const float*)q4, h1h, b1, p1, x1h,
                                    N, q4f_str, h1_str, x1_str);
    k_gemm2m<<<2 * Bg, 256, 0, stream>>>(x1h, wpk2, a_src2, a_dst2, h2, s2s, s2d, N,
                                         Bg, x1_str, h2_str, s1_str);
    k_eq2<<<GE, 256, 0, stream>>>(csrc, cdst, s2s, s2d, q2, E, s1_str, q2_str);
    k_agg2<<<Ba2, 256, 0, stream>>>(rowptr, csrc, q2, h2, b2, p2, x2o, x2a, N,
                                    q2_str, h2_str);

    // --- output heads ---
    float* out = (float*)d_out;
    float* o_log = out;                        // [NB]
    float* o_q = o_log + NB;                   // [N*32]
    float* o_k = o_q + (size_t)N * 32;         // [N*32]
    float* o_x2 = o_k + (size_t)N * 32;        // [N*32]
    float* o_logits = o_x2 + (size_t)N * 32;   // [2N]
    float* o_log1 = o_logits + (size_t)2 * N;  // [NB]

    k_heads<<<(N + 7) / 8, 256, 0, stream>>>(x2o, x2a, Wq, Wk, adv_w, adv_b,
                                             o_q, o_k, o_x2, o_logits, N);
    k_fusion<<<(NB + 7) / 8, 256, 0, stream>>>(x2o, idx, Wf, bf_, Wlog, blog, Wlog1, blog1,
                                               o_log, o_log1, NB);
}

// Round 8
// 358.802 us; speedup vs baseline: 2.5899x; 1.0466x over previous
//
#include <hip/hip_runtime.h>
#include <hip/hip_bf16.h>
#include <hip/hip_fp16.h>

// ---------------------------------------------------------------------------
// GATEncoder on MI355X.
//   CSR-by-dst built once (hierarchical scan);
//   fp16 MFMA GEMMs (16x16x32_f16), W pre-packed to B-fragment order,
//     gemm1 converts f32 x -> fp16 in-register;
//   agg1: dual-pass wave/node gather; scores computed INLINE (exp on idle
//     trans pipe; ssrc gather is one 16B wave-request on an L2-hot table);
//   agg2h: dual-pass, fp16 h2 payload, heads (q/k/adv/x2) fused in epilogue.
// agg1 sits at the random-gather throughput cap (R7: 2x ILP -> no change);
// fp8 payload ruled out: fp16 absmax 0.0078 is quantization-dominated, x8 step
// would predict ~0.062 > 0.0316 threshold.
// ---------------------------------------------------------------------------

typedef _Float16 f16;
typedef f16 f16x4 __attribute__((ext_vector_type(4)));
typedef f16 f16x8 __attribute__((ext_vector_type(8)));
typedef float f32x4 __attribute__((ext_vector_type(4)));

// ------------------------------ CSR build ----------------------------------
__global__ void k_zero_i(int* __restrict__ p, int n) {
    int i = blockIdx.x * 256 + threadIdx.x;
    if (i < n) p[i] = 0;
}

__global__ void k_count(const int* __restrict__ dst, int E, int* __restrict__ cnt) {
    int e = blockIdx.x * 256 + threadIdx.x;
    if (e < E) atomicAdd(&cnt[dst[e]], 1);
}

__global__ __launch_bounds__(256) void k_scan_local(const int* __restrict__ cnt,
                                                    int* __restrict__ rowptr,
                                                    int* __restrict__ bsums, int N) {
    __shared__ int t[256];
    int tid = threadIdx.x;
    int i = blockIdx.x * 256 + tid;
    int v = (i < N) ? cnt[i] : 0;
    t[tid] = v;
    __syncthreads();
    for (int off = 1; off < 256; off <<= 1) {
        int u = (tid >= off) ? t[tid - off] : 0;
        __syncthreads();
        t[tid] += u;
        __syncthreads();
    }
    if (i < N) rowptr[i] = t[tid] - v;  // exclusive within block
    if (tid == 255) bsums[blockIdx.x] = t[255];
}

__global__ __launch_bounds__(256) void k_scan_bsums(int* __restrict__ bsums, int G) {
    __shared__ int t[256];
    int tid = threadIdx.x;
    int v = (tid < G) ? bsums[tid] : 0;
    t[tid] = v;
    __syncthreads();
    for (int off = 1; off < 256; off <<= 1) {
        int u = (tid >= off) ? t[tid - off] : 0;
        __syncthreads();
        t[tid] += u;
        __syncthreads();
    }
    if (tid < G) bsums[tid] = t[tid] - v;  // exclusive
}

__global__ __launch_bounds__(256) void k_scan_apply(int* __restrict__ rowptr,
                                                    const int* __restrict__ bsums,
                                                    int* __restrict__ cursor, int N, int E) {
    int i = blockIdx.x * 256 + threadIdx.x;
    if (i < N) {
        int r = rowptr[i] + bsums[blockIdx.x];
        rowptr[i] = r;
        cursor[i] = r;
    }
    if (i == 0) rowptr[N] = E;
}

__global__ void k_fill(const int* __restrict__ src, const int* __restrict__ dst, int E,
                       int* __restrict__ cursor, int* __restrict__ csrc) {
    int e = blockIdx.x * 256 + threadIdx.x;
    if (e < E) {
        int d = dst[e];
        int pos = atomicAdd(&cursor[d], 1);
        csrc[pos] = src[e];
    }
}

// --------------------------- weight packing --------------------------------
__device__ __forceinline__ void wpack_one(const float* __restrict__ W,
                                          f16* __restrict__ wpk, int K, int Ncols, int b) {
    int F = K >> 5;
    int total = (Ncols >> 4) * F * 64;
    if (b >= total) return;
    int l = b & 63, tf = b >> 6;
    int t = tf / F, f = tf % F;
    int col = t * 16 + (l & 15);
    int k0 = f * 32 + (l >> 4) * 8;
    f16x8 h;
#pragma unroll
    for (int j = 0; j < 8; ++j) h[j] = (f16)W[(size_t)(k0 + j) * Ncols + col];
    *reinterpret_cast<f16x8*>(wpk + (size_t)b * 8) = h;
}

__global__ __launch_bounds__(256) void k_wpack_all(const float* __restrict__ W1,
                                                   f16* __restrict__ wpk1,
                                                   const float* __restrict__ W2,
                                                   f16* __restrict__ wpk2) {
    int blk = blockIdx.x;
    if (blk < 16) wpack_one(W1, wpk1, 128, 256, blk * 256 + threadIdx.x);
    else wpack_one(W2, wpk2, 256, 32, (blk - 16) * 256 + threadIdx.x);
}

// --------------------------- layer-1 MFMA GEMM + scores --------------------
__global__ __launch_bounds__(256) void k_gemm1m(const float* __restrict__ xa,
                                                const float* __restrict__ xb,
                                                const f16* __restrict__ wpk,
                                                const float* __restrict__ as1,
                                                const float* __restrict__ ad1,
                                                f16* __restrict__ h1h,
                                                float* __restrict__ ssrc,
                                                float* __restrict__ sdst, int N,
                                                int Bper, size_t h1_str, size_t s4_str) {
    int blk = blockIdx.x, pass = 0;
    if (blk >= Bper) { pass = 1; blk -= Bper; }
    const float* x = pass ? xb : xa;
    h1h += (size_t)pass * h1_str;
    ssrc += (size_t)pass * s4_str;
    sdst += (size_t)pass * s4_str;
    int tid = threadIdx.x;
    int w = tid >> 6, l = tid & 63;
    int c16 = l & 15, kg = l >> 4;
    int n0 = blk * 64 + w * 16;
    int arow = n0 + c16;
    f16x8 af[4];
    if (arow < N) {
        const float4* xr4 = reinterpret_cast<const float4*>(x + (size_t)arow * 128 + kg * 8);
#pragma unroll
        for (int f = 0; f < 4; ++f) {
            float4 v0 = xr4[f * 8];
            float4 v1 = xr4[f * 8 + 1];
            af[f][0] = (f16)v0.x; af[f][1] = (f16)v0.y;
            af[f][2] = (f16)v0.z; af[f][3] = (f16)v0.w;
            af[f][4] = (f16)v1.x; af[f][5] = (f16)v1.y;
            af[f][6] = (f16)v1.z; af[f][7] = (f16)v1.w;
        }
    } else {
#pragma unroll
        for (int f = 0; f < 4; ++f)
#pragma unroll
            for (int j = 0; j < 8; ++j) af[f][j] = (f16)0.f;
    }
    float asv[16], adv[16];
#pragma unroll
    for (int t = 0; t < 16; ++t) {
        asv[t] = as1[t * 16 + c16];
        adv[t] = ad1[t * 16 + c16];
    }
    const f16x8* wp = reinterpret_cast<const f16x8*>(wpk);
    f32x4 acc[16];
#pragma unroll
    for (int t = 0; t < 16; ++t) {
        f32x4 a = {0.f, 0.f, 0.f, 0.f};
        a = __builtin_amdgcn_mfma_f32_16x16x32_f16(af[0], wp[(t * 4 + 0) * 64 + l], a, 0, 0, 0);
        a = __builtin_amdgcn_mfma_f32_16x16x32_f16(af[1], wp[(t * 4 + 1) * 64 + l], a, 0, 0, 0);
        a = __builtin_amdgcn_mfma_f32_16x16x32_f16(af[2], wp[(t * 4 + 2) * 64 + l], a, 0, 0, 0);
        a = __builtin_amdgcn_mfma_f32_16x16x32_f16(af[3], wp[(t * 4 + 3) * 64 + l], a, 0, 0, 0);
        acc[t] = a;
    }
    int rbase = n0 + kg * 4;
#pragma unroll
    for (int i = 0; i < 4; ++i) {
        int row = rbase + i;
        if (row < N) {
            f16* hr = h1h + (size_t)row * 256 + c16;
#pragma unroll
            for (int t = 0; t < 16; ++t) hr[t * 16] = (f16)acc[t][i];
        }
    }
#pragma unroll
    for (int i = 0; i < 4; ++i) {
        int row = rbase + i;
#pragma unroll
        for (int hh = 0; hh < 4; ++hh) {
            float ps = 0.f, pd = 0.f;
#pragma unroll
            for (int tt = 0; tt < 4; ++tt) {
                int t = hh * 4 + tt;
                ps += acc[t][i] * asv[t];
                pd += acc[t][i] * adv[t];
            }
#pragma unroll
            for (int m = 1; m < 16; m <<= 1) {
                ps += __shfl_xor(ps, m);
                pd += __shfl_xor(pd, m);
            }
            if (c16 == 0 && row < N) {
                ssrc[row * 4 + hh] = ps;
                sdst[row * 4 + hh] = pd;
            }
        }
    }
}

// --------------------------- layer-2 MFMA GEMM + scores --------------------
// h2 stored as fp16 (halves agg2 gather payload); scores from f32 acc.
__global__ __launch_bounds__(256) void k_gemm2m(const f16* __restrict__ x1h,
                                                const f16* __restrict__ wpk2,
                                                const float* __restrict__ as2,
                                                const float* __restrict__ ad2,
                                                __half* __restrict__ h2h,
                                                float* __restrict__ s2s,
                                                float* __restrict__ s2d, int N,
                                                int Bper, size_t x1_str, size_t h2_str,
                                                size_t s1_str) {
    int blk = blockIdx.x, pass = 0;
    if (blk >= Bper) { pass = 1; blk -= Bper; }
    x1h += (size_t)pass * x1_str;
    h2h += (size_t)pass * h2_str;
    s2s += (size_t)pass * s1_str;
    s2d += (size_t)pass * s1_str;
    int tid = threadIdx.x;
    int w = tid >> 6, l = tid & 63;
    int c16 = l & 15, kg = l >> 4;
    int n0 = blk * 64 + w * 16;
    const f16* xrow = x1h + (size_t)(n0 + c16) * 256 + kg * 8;
    f16x8 af[8];
#pragma unroll
    for (int f = 0; f < 8; ++f) af[f] = *reinterpret_cast<const f16x8*>(xrow + f * 32);
    const f16x8* wp = reinterpret_cast<const f16x8*>(wpk2);
    f32x4 acc[2];
#pragma unroll
    for (int t = 0; t < 2; ++t) {
        f32x4 a = {0.f, 0.f, 0.f, 0.f};
#pragma unroll
        for (int f = 0; f < 8; ++f)
            a = __builtin_amdgcn_mfma_f32_16x16x32_f16(af[f], wp[(t * 8 + f) * 64 + l], a, 0, 0, 0);
        acc[t] = a;
    }
    float asv[2], adv[2];
#pragma unroll
    for (int t = 0; t < 2; ++t) {
        asv[t] = as2[t * 16 + c16];
        adv[t] = ad2[t * 16 + c16];
    }
    int rbase = n0 + kg * 4;
#pragma unroll
    for (int i = 0; i < 4; ++i) {
        int row = rbase + i;
        if (row < N) {
            __half* hr = h2h + (size_t)row * 32 + c16;
            hr[0] = __float2half(acc[0][i]);
            hr[16] = __float2half(acc[1][i]);
        }
        float ps = acc[0][i] * asv[0] + acc[1][i] * asv[1];
        float pd = acc[0][i] * adv[0] + acc[1][i] * adv[1];
#pragma unroll
        for (int m = 1; m < 16; m <<= 1) {
            ps += __shfl_xor(ps, m);
            pd += __shfl_xor(pd, m);
        }
        if (c16 == 0 && row < N) {
            s2s[row] = ps;
            s2d[row] = pd;
        }
    }
}

// ------------------------- layer-1 edge aggregation ------------------------
// Wave per dst node, dual-pass, inline scores. Per edge: 16B ssrc wave-request
// (L2-hot 1.6MB table) + exp on trans pipe + 2x 8B/lane fp16 row gathers.
__global__ __launch_bounds__(256) void k_agg1(const int* __restrict__ rowptr,
                                              const int* __restrict__ csrc,
                                              const float* __restrict__ ssrc,
                                              const float* __restrict__ sdst,
                                              const f16* __restrict__ h1h,
                                              const float* __restrict__ b1,
                                              const float* __restrict__ p1,
                                              f16* __restrict__ x1h, int N,
                                              size_t s4_str, size_t h1_str,
                                              size_t x1_str) {
    int n = __builtin_amdgcn_readfirstlane((blockIdx.x * 256 + threadIdx.x) >> 6);
    int lane = threadIdx.x & 63;
    if (n >= N) return;
    int hs = lane >> 4;
    float sd0 = sdst[n * 4 + hs];
    float sd1 = sdst[s4_str + n * 4 + hs];
    const f16* hp1 = h1h + h1_str;
    int beg = rowptr[n], end = rowptr[n + 1];
    float a0x = 0, a0y = 0, a0z = 0, a0w = 0, z0 = 0;
    float a1x = 0, a1y = 0, a1z = 0, a1w = 0, z1 = 0;
    int j = beg;
    for (; j + 8 <= end; j += 8) {
        int s[8]; float e0[8], e1[8]; uint2 u0[8], u1[8];
#pragma unroll
        for (int k = 0; k < 8; ++k) s[k] = csrc[j + k];
#pragma unroll
        for (int k = 0; k < 8; ++k) e0[k] = ssrc[(size_t)s[k] * 4 + hs];
#pragma unroll
        for (int k = 0; k < 8; ++k) e1[k] = ssrc[s4_str + (size_t)s[k] * 4 + hs];
#pragma unroll
        for (int k = 0; k < 8; ++k)
            u0[k] = reinterpret_cast<const uint2*>(h1h + (size_t)s[k] * 256)[lane];
#pragma unroll
        for (int k = 0; k < 8; ++k)
            u1[k] = reinterpret_cast<const uint2*>(hp1 + (size_t)s[k] * 256)[lane];
#pragma unroll
        for (int k = 0; k < 8; ++k) {
            float t0 = e0[k] + sd0;
            t0 = t0 > 0.f ? t0 : 0.2f * t0;
            float q0 = __expf(t0);
            float t1 = e1[k] + sd1;
            t1 = t1 > 0.f ? t1 : 0.2f * t1;
            float q1 = __expf(t1);
            float2 fa = __half22float2(*reinterpret_cast<__half2*>(&u0[k].x));
            float2 fb = __half22float2(*reinterpret_cast<__half2*>(&u0[k].y));
            z0 += q0;
            a0x += q0 * fa.x; a0y += q0 * fa.y;
            a0z += q0 * fb.x; a0w += q0 * fb.y;
            float2 ga = __half22float2(*reinterpret_cast<__half2*>(&u1[k].x));
            float2 gb = __half22float2(*reinterpret_cast<__half2*>(&u1[k].y));
            z1 += q1;
            a1x += q1 * ga.x; a1y += q1 * ga.y;
            a1z += q1 * gb.x; a1w += q1 * gb.y;
        }
    }
    for (; j < end; ++j) {
        int s = csrc[j];
        float t0 = ssrc[(size_t)s * 4 + hs] + sd0;
        t0 = t0 > 0.f ? t0 : 0.2f * t0;
        float q0 = __expf(t0);
        float t1 = ssrc[s4_str + (size_t)s * 4 + hs] + sd1;
        t1 = t1 > 0.f ? t1 : 0.2f * t1;
        float q1 = __expf(t1);
        uint2 u0 = reinterpret_cast<const uint2*>(h1h + (size_t)s * 256)[lane];
        uint2 u1 = reinterpret_cast<const uint2*>(hp1 + (size_t)s * 256)[lane];
        float2 fa = __half22float2(*reinterpret_cast<__half2*>(&u0.x));
        float2 fb = __half22float2(*reinterpret_cast<__half2*>(&u0.y));
        z0 += q0;
        a0x += q0 * fa.x; a0y += q0 * fa.y; a0z += q0 * fb.x; a0w += q0 * fb.y;
        float2 ga = __half22float2(*reinterpret_cast<__half2*>(&u1.x));
        float2 gb = __half22float2(*reinterpret_cast<__half2*>(&u1.y));
        z1 += q1;
        a1x += q1 * ga.x; a1y += q1 * ga.y; a1z += q1 * gb.x; a1w += q1 * gb.y;
    }
    float4 bb = reinterpret_cast<const float4*>(b1)[lane];
    float4 pp = reinterpret_cast<const float4*>(p1)[lane];
    {
        float rz = 1.f / (z0 + 1e-16f);
        float4 v;
        v.x = a0x * rz + bb.x; v.y = a0y * rz + bb.y;
        v.z = a0z * rz + bb.z; v.w = a0w * rz + bb.w;
        v.x = v.x > 0.f ? v.x : pp.x * v.x;
        v.y = v.y > 0.f ? v.y : pp.y * v.y;
        v.z = v.z > 0.f ? v.z : pp.z * v.z;
        v.w = v.w > 0.f ? v.w : pp.w * v.w;
        f16x4 hv;
        hv[0] = (f16)v.x; hv[1] = (f16)v.y; hv[2] = (f16)v.z; hv[3] = (f16)v.w;
        *reinterpret_cast<f16x4*>(x1h + (size_t)n * 256 + lane * 4) = hv;
    }
    {
        float rz = 1.f / (z1 + 1e-16f);
        float4 v;
        v.x = a1x * rz + bb.x; v.y = a1y * rz + bb.y;
        v.z = a1z * rz + bb.z; v.w = a1w * rz + bb.w;
        v.x = v.x > 0.f ? v.x : pp.x * v.x;
        v.y = v.y > 0.f ? v.y : pp.y * v.y;
        v.z = v.z > 0.f ? v.z : pp.z * v.z;
        v.w = v.w > 0.f ? v.w : pp.w * v.w;
        f16x4 hv;
        hv[0] = (f16)v.x; hv[1] = (f16)v.y; hv[2] = (f16)v.z; hv[3] = (f16)v.w;
        *reinterpret_cast<f16x4*>(x1h + x1_str + (size_t)n * 256 + lane * 4) = hv;
    }
}

// ---------------- layer-2 edge aggregation + fused heads -------------------
// 32-lane group per dst node, dual-pass, inline scores, fp16 h2 payload.
// Epilogue: x2 (both passes in-register) -> q/k projections, x2 copy, adv.
__global__ __launch_bounds__(256) void k_agg2h(const int* __restrict__ rowptr,
                                               const int* __restrict__ csrc,
                                               const float* __restrict__ s2s,
                                               const float* __restrict__ s2d,
                                               const __half* __restrict__ h2h,
                                               const float* __restrict__ b2,
                                               const float* __restrict__ p2,
                                               const float* __restrict__ Wq,
                                               const float* __restrict__ Wk,
                                               const float* __restrict__ advw,
                                               const float* __restrict__ advb,
                                               float* __restrict__ o_q,
                                               float* __restrict__ o_k,
                                               float* __restrict__ o_x2,
                                               float* __restrict__ o_logits, int N,
                                               size_t s1_str, size_t h2_str) {
    int n = (blockIdx.x * 256 + threadIdx.x) >> 5;
    int c = threadIdx.x & 31;
    if (n >= N) return;
    float sd0 = s2d[n], sd1 = s2d[s1_str + n];
    const __half* hb = h2h + h2_str;
    int beg = rowptr[n], end = rowptr[n + 1];
    float acc0 = 0.f, zz0 = 0.f, acc1 = 0.f, zz1 = 0.f;
    int j = beg;
    for (; j + 8 <= end; j += 8) {
        int s[8]; float f0[8], f1[8]; __half g0[8], g1[8];
#pragma unroll
        for (int k = 0; k < 8; ++k) s[k] = csrc[j + k];
#pragma unroll
        for (int k = 0; k < 8; ++k) f0[k] = s2s[s[k]];
#pragma unroll
        for (int k = 0; k < 8; ++k) f1[k] = s2s[s1_str + s[k]];
#pragma unroll
        for (int k = 0; k < 8; ++k) g0[k] = h2h[(size_t)s[k] * 32 + c];
#pragma unroll
        for (int k = 0; k < 8; ++k) g1[k] = hb[(size_t)s[k] * 32 + c];
#pragma unroll
        for (int k = 0; k < 8; ++k) {
            float t0 = f0[k] + sd0;
            t0 = t0 > 0.f ? t0 : 0.2f * t0;
            float q0 = __expf(t0);
            zz0 += q0; acc0 += q0 * __half2float(g0[k]);
            float t1 = f1[k] + sd1;
            t1 = t1 > 0.f ? t1 : 0.2f * t1;
            float q1 = __expf(t1);
            zz1 += q1; acc1 += q1 * __half2float(g1[k]);
        }
    }
    for (; j < end; ++j) {
        int s = csrc[j];
        float t0 = s2s[s] + sd0;
        t0 = t0 > 0.f ? t0 : 0.2f * t0;
        float q0 = __expf(t0);
        zz0 += q0; acc0 += q0 * __half2float(h2h[(size_t)s * 32 + c]);
        float t1 = s2s[s1_str + s] + sd1;
        t1 = t1 > 0.f ? t1 : 0.2f * t1;
        float q1 = __expf(t1);
        zz1 += q1; acc1 += q1 * __half2float(hb[(size_t)s * 32 + c]);
    }
    float bbv = b2[c], ppv = p2[c];
    float v0 = acc0 / (zz0 + 1e-16f) + bbv;
    v0 = v0 > 0.f ? v0 : ppv * v0;
    float v1 = acc1 / (zz1 + 1e-16f) + bbv;
    v1 = v1 > 0.f ? v1 : ppv * v1;
    o_x2[(size_t)n * 32 + c] = v0;
    // --- fused heads: q/k projections (l2norm) + adversarial sums ---
    float accq = 0.f, acck = 0.f;
    for (int cc = 0; cc < 32; ++cc) {
        accq += __shfl(v0, cc, 32) * Wq[cc * 32 + c];
        acck += __shfl(v1, cc, 32) * Wk[cc * 32 + c];
    }
    float sq = accq * accq, sk = acck * acck;
    for (int m = 16; m; m >>= 1) {
        sq += __shfl_xor(sq, m);
        sk += __shfl_xor(sk, m);
    }
    o_q[(size_t)n * 32 + c] = accq / (sqrtf(sq) + 1e-12f);
    o_k[(size_t)n * 32 + c] = acck / (sqrtf(sk) + 1e-12f);
    float ws = 0.f;
    {
        const float4* aw4 = reinterpret_cast<const float4*>(advw + c * 32);
#pragma unroll
        for (int t = 0; t < 8; ++t) {
            float4 v = aw4[t];
            ws += v.x + v.y + v.z + v.w;
        }
    }
    float bs = advb[c];
    for (int m = 16; m; m >>= 1) bs += __shfl_xor(bs, m);
    float vo = v0 * ws, va = v1 * ws;
    for (int m = 16; m; m >>= 1) {
        vo += __shfl_xor(vo, m);
        va += __shfl_xor(va, m);
    }
    if (c == 0) {
        o_logits[n] = vo + bs;
        o_logits[N + n] = va + bs;
    }
}

// ------------------------------- fusion decoder ----------------------------
__global__ __launch_bounds__(256) void k_fusion(const float* __restrict__ x2o,
                                                const int* __restrict__ idx,
                                                const float* __restrict__ Wf,
                                                const float* __restrict__ bfb,
                                                const float* __restrict__ Wlog,
                                                const float* __restrict__ blog,
                                                const float* __restrict__ Wlog1,
                                                const float* __restrict__ blog1,
                                                float* __restrict__ out_log,
                                                float* __restrict__ out_log1, int NB) {
    int i = (blockIdx.x * 256 + threadIdx.x) >> 5;
    int o = threadIdx.x & 31;
    if (i >= NB) return;
    int i1 = idx[i], i2 = idx[NB + i];
    float e1 = x2o[(size_t)i1 * 32 + o];
    float e2 = x2o[(size_t)i2 * 32 + o];
    float acc = bfb[o];
    for (int c = 0; c < 32; ++c) {
        acc += __shfl(e1, c, 32) * Wf[c * 32 + o];
        acc += __shfl(e2, c, 32) * Wf[(32 + c) * 32 + o];
    }
    float h = acc > 0.f ? acc : 0.f;
    float v0 = h * Wlog[o];
    float v1 = h * Wlog1[o];
    for (int m = 16; m; m >>= 1) {
        v0 += __shfl_xor(v0, m);
        v1 += __shfl_xor(v1, m);
    }
    if (o == 0) {
        out_log[i] = v0 + blog[0];
        out_log1[i] = v1 + blog1[0];
    }
}

// ---------------------------------------------------------------------------
extern "C" void kernel_launch(void* const* d_in, const int* in_sizes, int n_in,
                              void* d_out, int out_size, void* d_ws, size_t ws_size,
                              hipStream_t stream) {
    const float* x_o = (const float*)d_in[0];
    const float* x_a = (const float*)d_in[1];
    const float* W1 = (const float*)d_in[2];
    const float* a_src1 = (const float*)d_in[3];
    const float* a_dst1 = (const float*)d_in[4];
    const float* b1 = (const float*)d_in[5];
    const float* p1 = (const float*)d_in[6];
    const float* W2 = (const float*)d_in[7];
    const float* a_src2 = (const float*)d_in[8];
    const float* a_dst2 = (const float*)d_in[9];
    const float* b2 = (const float*)d_in[10];
    const float* p2 = (const float*)d_in[11];
    const float* adv_w = (const float*)d_in[12];
    const float* adv_b = (const float*)d_in[13];
    const float* Wq = (const float*)d_in[14];
    const float* Wk = (const float*)d_in[15];
    const float* Wf = (const float*)d_in[16];
    const float* bf_ = (const float*)d_in[17];
    const float* Wlog = (const float*)d_in[18];
    const float* blog = (const float*)d_in[19];
    const float* Wlog1 = (const float*)d_in[20];
    const float* blog1 = (const float*)d_in[21];
    const int* ei = (const int*)d_in[22];
    const int* idx = (const int*)d_in[23];

    const int N = in_sizes[0] / 128;
    const int E = in_sizes[22] / 2;
    const int NB = in_sizes[23] / 2;
    const int* esrc = ei;
    const int* edst = ei + E;
    const int GS = (N + 255) / 256;
    const int GE = (E + 255) / 256;
    const int rows_pad = (N + 63) & ~63;

    char* ws = (char*)d_ws;
    size_t off = 0;
    auto alloc = [&](size_t bytes) -> void* {
        void* p = ws + off;
        off += (bytes + 255) & ~(size_t)255;
        return p;
    };
    f16* h1h = (f16*)alloc((size_t)2 * N * 256 * 2);
    f16* x1h = (f16*)alloc((size_t)2 * rows_pad * 256 * 2);
    f16* wpk1 = (f16*)alloc((size_t)16 * 4 * 64 * 8 * 2);
    f16* wpk2 = (f16*)alloc((size_t)2 * 8 * 64 * 8 * 2);
    __half* h2h = (__half*)alloc((size_t)2 * N * 32 * 2);
    float* ssrc = (float*)alloc((size_t)2 * N * 4 * 4);
    float* sdst = (float*)alloc((size_t)2 * N * 4 * 4);
    float* s2s = (float*)alloc((size_t)2 * N * 4);
    float* s2d = (float*)alloc((size_t)2 * N * 4);
    int* rowptr = (int*)alloc((size_t)(N + 1) * 4);
    int* cursor = (int*)alloc((size_t)N * 4);
    int* bsums = (int*)alloc(256 * 4);
    int* csrc = (int*)alloc((size_t)E * 4);

    // --- CSR build ---
    k_zero_i<<<GS, 256, 0, stream>>>(cursor, N);
    k_count<<<GE, 256, 0, stream>>>(edst, E, cursor);
    k_scan_local<<<GS, 256, 0, stream>>>(cursor, rowptr, bsums, N);
    k_scan_bsums<<<1, 256, 0, stream>>>(bsums, GS);
    k_scan_apply<<<GS, 256, 0, stream>>>(rowptr, bsums, cursor, N, E);
    k_fill<<<GE, 256, 0, stream>>>(esrc, edst, E, cursor, csrc);

    // --- weight packing (one launch) ---
    k_wpack_all<<<20, 256, 0, stream>>>(W1, wpk1, W2, wpk2);

    // strides (elements) between pass-0 and pass-1 halves
    const size_t h1_str = (size_t)N * 256;
    const size_t x1_str = (size_t)rows_pad * 256;
    const size_t h2_str = (size_t)N * 32;
    const size_t s4_str = (size_t)N * 4;
    const size_t s1_str = (size_t)N;

    const int Bg = rows_pad / 64;
    const int Ba1 = (N + 3) / 4;
    const int Ba2 = (N + 7) / 8;

    // --- output layout ---
    float* out = (float*)d_out;
    float* o_log = out;                        // [NB]
    float* o_q = o_log + NB;                   // [N*32]
    float* o_k = o_q + (size_t)N * 32;         // [N*32]
    float* o_x2 = o_k + (size_t)N * 32;        // [N*32]
    float* o_logits = o_x2 + (size_t)N * 32;   // [2N]
    float* o_log1 = o_logits + (size_t)2 * N;  // [NB]

    k_gemm1m<<<2 * Bg, 256, 0, stream>>>(x_o, x_a, wpk1, a_src1, a_dst1, h1h, ssrc, sdst,
                                         N, Bg, h1_str, s4_str);
    k_agg1<<<Ba1, 256, 0, stream>>>(rowptr, csrc, ssrc, sdst, h1h, b1, p1, x1h,
                                    N, s4_str, h1_str, x1_str);
    k_gemm2m<<<2 * Bg, 256, 0, stream>>>(x1h, wpk2, a_src2, a_dst2, h2h, s2s, s2d, N,
                                         Bg, x1_str, h2_str, s1_str);
    k_agg2h<<<Ba2, 256, 0, stream>>>(rowptr, csrc, s2s, s2d, h2h, b2, p2,
                                     Wq, Wk, adv_w, adv_b,
                                     o_q, o_k, o_x2, o_logits, N, s1_str, h2_str);
    k_fusion<<<(NB + 7) / 8, 256, 0, stream>>>(o_x2, idx, Wf, bf_, Wlog, blog, Wlog1, blog1,
                                               o_log, o_log1, NB);
}

// Round 9
// 357.705 us; speedup vs baseline: 2.5979x; 1.0031x over previous
//
#include <hip/hip_runtime.h>
#include <hip/hip_bf16.h>
#include <hip/hip_fp16.h>

// ---------------------------------------------------------------------------
// GATEncoder on MI355X.
//   CSR-by-dst built once (hierarchical scan, bsums-prefix folded into apply);
//   fp16 MFMA GEMMs (16x16x32_f16), W pre-packed to B-fragment order,
//     gemm1 converts f32 x -> fp16 in-register;
//   Scores for BOTH passes packed per node (float2) -> agg kernels issue ONE
//     score-gather per edge (R8's two-table version cost +13us / +44MB);
//   agg1: dual-pass wave/node gather (8-deep ILP, structural ~7TB/s cap);
//   agg2h: dual-pass, fp16 h2 payload, heads (q/k/adv/x2) fused in epilogue.
// fp8 payload ruled out by error arithmetic (fp16 absmax 0.0078 is
// quantization-dominated; x8 step predicts ~0.06 > 0.0316 threshold).
// ---------------------------------------------------------------------------

typedef _Float16 f16;
typedef f16 f16x4 __attribute__((ext_vector_type(4)));
typedef f16 f16x8 __attribute__((ext_vector_type(8)));
typedef float f32x4 __attribute__((ext_vector_type(4)));

// ------------------------------ CSR build ----------------------------------
__global__ void k_zero_i(int* __restrict__ p, int n) {
    int i = blockIdx.x * 256 + threadIdx.x;
    if (i < n) p[i] = 0;
}

__global__ void k_count(const int* __restrict__ dst, int E, int* __restrict__ cnt) {
    int e = blockIdx.x * 256 + threadIdx.x;
    if (e < E) atomicAdd(&cnt[dst[e]], 1);
}

__global__ __launch_bounds__(256) void k_scan_local(const int* __restrict__ cnt,
                                                    int* __restrict__ rowptr,
                                                    int* __restrict__ bsums, int N) {
    __shared__ int t[256];
    int tid = threadIdx.x;
    int i = blockIdx.x * 256 + tid;
    int v = (i < N) ? cnt[i] : 0;
    t[tid] = v;
    __syncthreads();
    for (int off = 1; off < 256; off <<= 1) {
        int u = (tid >= off) ? t[tid - off] : 0;
        __syncthreads();
        t[tid] += u;
        __syncthreads();
    }
    if (i < N) rowptr[i] = t[tid] - v;  // exclusive within block
    if (tid == 255) bsums[blockIdx.x] = t[255];
}

// apply: each block computes its own prefix over bsums (G<=256), then offsets.
__global__ __launch_bounds__(256) void k_scan_apply(int* __restrict__ rowptr,
                                                    const int* __restrict__ bsums,
                                                    int* __restrict__ cursor, int N, int E) {
    __shared__ int t[256];
    int tid = threadIdx.x;
    int blk = blockIdx.x;
    int v = (tid < blk) ? bsums[tid] : 0;
    t[tid] = v;
    __syncthreads();
    for (int off = 1; off < 256; off <<= 1) {
        int u = (tid >= off) ? t[tid - off] : 0;
        __syncthreads();
        t[tid] += u;
        __syncthreads();
    }
    int offset = t[255];  // sum of bsums[0..blk)
    int i = blk * 256 + tid;
    if (i < N) {
        int r = rowptr[i] + offset;
        rowptr[i] = r;
        cursor[i] = r;
    }
    if (i == 0) rowptr[N] = E;
}

__global__ void k_fill(const int* __restrict__ src, const int* __restrict__ dst, int E,
                       int* __restrict__ cursor, int* __restrict__ csrc) {
    int e = blockIdx.x * 256 + threadIdx.x;
    if (e < E) {
        int d = dst[e];
        int pos = atomicAdd(&cursor[d], 1);
        csrc[pos] = src[e];
    }
}

// --------------------------- weight packing --------------------------------
__device__ __forceinline__ void wpack_one(const float* __restrict__ W,
                                          f16* __restrict__ wpk, int K, int Ncols, int b) {
    int F = K >> 5;
    int total = (Ncols >> 4) * F * 64;
    if (b >= total) return;
    int l = b & 63, tf = b >> 6;
    int t = tf / F, f = tf % F;
    int col = t * 16 + (l & 15);
    int k0 = f * 32 + (l >> 4) * 8;
    f16x8 h;
#pragma unroll
    for (int j = 0; j < 8; ++j) h[j] = (f16)W[(size_t)(k0 + j) * Ncols + col];
    *reinterpret_cast<f16x8*>(wpk + (size_t)b * 8) = h;
}

__global__ __launch_bounds__(256) void k_wpack_all(const float* __restrict__ W1,
                                                   f16* __restrict__ wpk1,
                                                   const float* __restrict__ W2,
                                                   f16* __restrict__ wpk2) {
    int blk = blockIdx.x;
    if (blk < 16) wpack_one(W1, wpk1, 128, 256, blk * 256 + threadIdx.x);
    else wpack_one(W2, wpk2, 256, 32, (blk - 16) * 256 + threadIdx.x);
}

// --------------------------- layer-1 MFMA GEMM + scores --------------------
// Scores written PACKED: spp/sdp[n*8 + hh*2 + pass] (f32).
__global__ __launch_bounds__(256) void k_gemm1m(const float* __restrict__ xa,
                                                const float* __restrict__ xb,
                                                const f16* __restrict__ wpk,
                                                const float* __restrict__ as1,
                                                const float* __restrict__ ad1,
                                                f16* __restrict__ h1h,
                                                float* __restrict__ spp,
                                                float* __restrict__ sdp, int N,
                                                int Bper, size_t h1_str) {
    int blk = blockIdx.x, pass = 0;
    if (blk >= Bper) { pass = 1; blk -= Bper; }
    const float* x = pass ? xb : xa;
    h1h += (size_t)pass * h1_str;
    int tid = threadIdx.x;
    int w = tid >> 6, l = tid & 63;
    int c16 = l & 15, kg = l >> 4;
    int n0 = blk * 64 + w * 16;
    int arow = n0 + c16;
    f16x8 af[4];
    if (arow < N) {
        const float4* xr4 = reinterpret_cast<const float4*>(x + (size_t)arow * 128 + kg * 8);
#pragma unroll
        for (int f = 0; f < 4; ++f) {
            float4 v0 = xr4[f * 8];
            float4 v1 = xr4[f * 8 + 1];
            af[f][0] = (f16)v0.x; af[f][1] = (f16)v0.y;
            af[f][2] = (f16)v0.z; af[f][3] = (f16)v0.w;
            af[f][4] = (f16)v1.x; af[f][5] = (f16)v1.y;
            af[f][6] = (f16)v1.z; af[f][7] = (f16)v1.w;
        }
    } else {
#pragma unroll
        for (int f = 0; f < 4; ++f)
#pragma unroll
            for (int j = 0; j < 8; ++j) af[f][j] = (f16)0.f;
    }
    float asv[16], adv[16];
#pragma unroll
    for (int t = 0; t < 16; ++t) {
        asv[t] = as1[t * 16 + c16];
        adv[t] = ad1[t * 16 + c16];
    }
    const f16x8* wp = reinterpret_cast<const f16x8*>(wpk);
    f32x4 acc[16];
#pragma unroll
    for (int t = 0; t < 16; ++t) {
        f32x4 a = {0.f, 0.f, 0.f, 0.f};
        a = __builtin_amdgcn_mfma_f32_16x16x32_f16(af[0], wp[(t * 4 + 0) * 64 + l], a, 0, 0, 0);
        a = __builtin_amdgcn_mfma_f32_16x16x32_f16(af[1], wp[(t * 4 + 1) * 64 + l], a, 0, 0, 0);
        a = __builtin_amdgcn_mfma_f32_16x16x32_f16(af[2], wp[(t * 4 + 2) * 64 + l], a, 0, 0, 0);
        a = __builtin_amdgcn_mfma_f32_16x16x32_f16(af[3], wp[(t * 4 + 3) * 64 + l], a, 0, 0, 0);
        acc[t] = a;
    }
    int rbase = n0 + kg * 4;
#pragma unroll
    for (int i = 0; i < 4; ++i) {
        int row = rbase + i;
        if (row < N) {
            f16* hr = h1h + (size_t)row * 256 + c16;
#pragma unroll
            for (int t = 0; t < 16; ++t) hr[t * 16] = (f16)acc[t][i];
        }
    }
#pragma unroll
    for (int i = 0; i < 4; ++i) {
        int row = rbase + i;
#pragma unroll
        for (int hh = 0; hh < 4; ++hh) {
            float ps = 0.f, pd = 0.f;
#pragma unroll
            for (int tt = 0; tt < 4; ++tt) {
                int t = hh * 4 + tt;
                ps += acc[t][i] * asv[t];
                pd += acc[t][i] * adv[t];
            }
#pragma unroll
            for (int m = 1; m < 16; m <<= 1) {
                ps += __shfl_xor(ps, m);
                pd += __shfl_xor(pd, m);
            }
            if (c16 == 0 && row < N) {
                spp[(size_t)row * 8 + hh * 2 + pass] = ps;
                sdp[(size_t)row * 8 + hh * 2 + pass] = pd;
            }
        }
    }
}

// --------------------------- layer-2 MFMA GEMM + scores --------------------
// h2 fp16; scores packed s2sp/s2dp[n*2 + pass].
__global__ __launch_bounds__(256) void k_gemm2m(const f16* __restrict__ x1h,
                                                const f16* __restrict__ wpk2,
                                                const float* __restrict__ as2,
                                                const float* __restrict__ ad2,
                                                __half* __restrict__ h2h,
                                                float* __restrict__ s2sp,
                                                float* __restrict__ s2dp, int N,
                                                int Bper, size_t x1_str, size_t h2_str) {
    int blk = blockIdx.x, pass = 0;
    if (blk >= Bper) { pass = 1; blk -= Bper; }
    x1h += (size_t)pass * x1_str;
    h2h += (size_t)pass * h2_str;
    int tid = threadIdx.x;
    int w = tid >> 6, l = tid & 63;
    int c16 = l & 15, kg = l >> 4;
    int n0 = blk * 64 + w * 16;
    const f16* xrow = x1h + (size_t)(n0 + c16) * 256 + kg * 8;
    f16x8 af[8];
#pragma unroll
    for (int f = 0; f < 8; ++f) af[f] = *reinterpret_cast<const f16x8*>(xrow + f * 32);
    const f16x8* wp = reinterpret_cast<const f16x8*>(wpk2);
    f32x4 acc[2];
#pragma unroll
    for (int t = 0; t < 2; ++t) {
        f32x4 a = {0.f, 0.f, 0.f, 0.f};
#pragma unroll
        for (int f = 0; f < 8; ++f)
            a = __builtin_amdgcn_mfma_f32_16x16x32_f16(af[f], wp[(t * 8 + f) * 64 + l], a, 0, 0, 0);
        acc[t] = a;
    }
    float asv[2], adv[2];
#pragma unroll
    for (int t = 0; t < 2; ++t) {
        asv[t] = as2[t * 16 + c16];
        adv[t] = ad2[t * 16 + c16];
    }
    int rbase = n0 + kg * 4;
#pragma unroll
    for (int i = 0; i < 4; ++i) {
        int row = rbase + i;
        if (row < N) {
            __half* hr = h2h + (size_t)row * 32 + c16;
            hr[0] = __float2half(acc[0][i]);
            hr[16] = __float2half(acc[1][i]);
        }
        float ps = acc[0][i] * asv[0] + acc[1][i] * asv[1];
        float pd = acc[0][i] * adv[0] + acc[1][i] * adv[1];
#pragma unroll
        for (int m = 1; m < 16; m <<= 1) {
            ps += __shfl_xor(ps, m);
            pd += __shfl_xor(pd, m);
        }
        if (c16 == 0 && row < N) {
            s2sp[(size_t)row * 2 + pass] = ps;
            s2dp[(size_t)row * 2 + pass] = pd;
        }
    }
}

// ------------------------- layer-1 edge aggregation ------------------------
// Wave per dst node, dual-pass. Per edge: ONE 8B/lane float2 score gather
// (both passes, 32B/wave) + 2x 8B/lane fp16 row gathers + exp on trans pipe.
__global__ __launch_bounds__(256) void k_agg1(const int* __restrict__ rowptr,
                                              const int* __restrict__ csrc,
                                              const float* __restrict__ spp,
                                              const float* __restrict__ sdp,
                                              const f16* __restrict__ h1h,
                                              const float* __restrict__ b1,
                                              const float* __restrict__ p1,
                                              f16* __restrict__ x1h, int N,
                                              size_t h1_str, size_t x1_str) {
    int n = __builtin_amdgcn_readfirstlane((blockIdx.x * 256 + threadIdx.x) >> 6);
    int lane = threadIdx.x & 63;
    if (n >= N) return;
    int hs = lane >> 4;
    const float2* spp2 = reinterpret_cast<const float2*>(spp);  // [n*4 + hh]
    float2 sdv = reinterpret_cast<const float2*>(sdp)[(size_t)n * 4 + hs];
    float sd0 = sdv.x, sd1 = sdv.y;
    const f16* hp1 = h1h + h1_str;
    int beg = rowptr[n], end = rowptr[n + 1];
    float a0x = 0, a0y = 0, a0z = 0, a0w = 0, z0 = 0;
    float a1x = 0, a1y = 0, a1z = 0, a1w = 0, z1 = 0;
    int j = beg;
    for (; j + 8 <= end; j += 8) {
        int s[8]; float2 e[8]; uint2 u0[8], u1[8];
#pragma unroll
        for (int k = 0; k < 8; ++k) s[k] = csrc[j + k];
#pragma unroll
        for (int k = 0; k < 8; ++k) e[k] = spp2[(size_t)s[k] * 4 + hs];
#pragma unroll
        for (int k = 0; k < 8; ++k)
            u0[k] = reinterpret_cast<const uint2*>(h1h + (size_t)s[k] * 256)[lane];
#pragma unroll
        for (int k = 0; k < 8; ++k)
            u1[k] = reinterpret_cast<const uint2*>(hp1 + (size_t)s[k] * 256)[lane];
#pragma unroll
        for (int k = 0; k < 8; ++k) {
            float t0 = e[k].x + sd0;
            t0 = t0 > 0.f ? t0 : 0.2f * t0;
            float q0 = __expf(t0);
            float t1 = e[k].y + sd1;
            t1 = t1 > 0.f ? t1 : 0.2f * t1;
            float q1 = __expf(t1);
            float2 fa = __half22float2(*reinterpret_cast<__half2*>(&u0[k].x));
            float2 fb = __half22float2(*reinterpret_cast<__half2*>(&u0[k].y));
            z0 += q0;
            a0x += q0 * fa.x; a0y += q0 * fa.y;
            a0z += q0 * fb.x; a0w += q0 * fb.y;
            float2 ga = __half22float2(*reinterpret_cast<__half2*>(&u1[k].x));
            float2 gb = __half22float2(*reinterpret_cast<__half2*>(&u1[k].y));
            z1 += q1;
            a1x += q1 * ga.x; a1y += q1 * ga.y;
            a1z += q1 * gb.x; a1w += q1 * gb.y;
        }
    }
    for (; j < end; ++j) {
        int s = csrc[j];
        float2 e = spp2[(size_t)s * 4 + hs];
        float t0 = e.x + sd0;
        t0 = t0 > 0.f ? t0 : 0.2f * t0;
        float q0 = __expf(t0);
        float t1 = e.y + sd1;
        t1 = t1 > 0.f ? t1 : 0.2f * t1;
        float q1 = __expf(t1);
        uint2 u0 = reinterpret_cast<const uint2*>(h1h + (size_t)s * 256)[lane];
        uint2 u1 = reinterpret_cast<const uint2*>(hp1 + (size_t)s * 256)[lane];
        float2 fa = __half22float2(*reinterpret_cast<__half2*>(&u0.x));
        float2 fb = __half22float2(*reinterpret_cast<__half2*>(&u0.y));
        z0 += q0;
        a0x += q0 * fa.x; a0y += q0 * fa.y; a0z += q0 * fb.x; a0w += q0 * fb.y;
        float2 ga = __half22float2(*reinterpret_cast<__half2*>(&u1.x));
        float2 gb = __half22float2(*reinterpret_cast<__half2*>(&u1.y));
        z1 += q1;
        a1x += q1 * ga.x; a1y += q1 * ga.y; a1z += q1 * gb.x; a1w += q1 * gb.y;
    }
    float4 bb = reinterpret_cast<const float4*>(b1)[lane];
    float4 pp = reinterpret_cast<const float4*>(p1)[lane];
    {
        float rz = 1.f / (z0 + 1e-16f);
        float4 v;
        v.x = a0x * rz + bb.x; v.y = a0y * rz + bb.y;
        v.z = a0z * rz + bb.z; v.w = a0w * rz + bb.w;
        v.x = v.x > 0.f ? v.x : pp.x * v.x;
        v.y = v.y > 0.f ? v.y : pp.y * v.y;
        v.z = v.z > 0.f ? v.z : pp.z * v.z;
        v.w = v.w > 0.f ? v.w : pp.w * v.w;
        f16x4 hv;
        hv[0] = (f16)v.x; hv[1] = (f16)v.y; hv[2] = (f16)v.z; hv[3] = (f16)v.w;
        *reinterpret_cast<f16x4*>(x1h + (size_t)n * 256 + lane * 4) = hv;
    }
    {
        float rz = 1.f / (z1 + 1e-16f);
        float4 v;
        v.x = a1x * rz + bb.x; v.y = a1y * rz + bb.y;
        v.z = a1z * rz + bb.z; v.w = a1w * rz + bb.w;
        v.x = v.x > 0.f ? v.x : pp.x * v.x;
        v.y = v.y > 0.f ? v.y : pp.y * v.y;
        v.z = v.z > 0.f ? v.z : pp.z * v.z;
        v.w = v.w > 0.f ? v.w : pp.w * v.w;
        f16x4 hv;
        hv[0] = (f16)v.x; hv[1] = (f16)v.y; hv[2] = (f16)v.z; hv[3] = (f16)v.w;
        *reinterpret_cast<f16x4*>(x1h + x1_str + (size_t)n * 256 + lane * 4) = hv;
    }
}

// ---------------- layer-2 edge aggregation + fused heads -------------------
__global__ __launch_bounds__(256) void k_agg2h(const int* __restrict__ rowptr,
                                               const int* __restrict__ csrc,
                                               const float* __restrict__ s2sp,
                                               const float* __restrict__ s2dp,
                                               const __half* __restrict__ h2h,
                                               const float* __restrict__ b2,
                                               const float* __restrict__ p2,
                                               const float* __restrict__ Wq,
                                               const float* __restrict__ Wk,
                                               const float* __restrict__ advw,
                                               const float* __restrict__ advb,
                                               float* __restrict__ o_q,
                                               float* __restrict__ o_k,
                                               float* __restrict__ o_x2,
                                               float* __restrict__ o_logits, int N,
                                               size_t h2_str) {
    int n = (blockIdx.x * 256 + threadIdx.x) >> 5;
    int c = threadIdx.x & 31;
    if (n >= N) return;
    const float2* s2sp2 = reinterpret_cast<const float2*>(s2sp);
    float2 sdv = reinterpret_cast<const float2*>(s2dp)[n];
    float sd0 = sdv.x, sd1 = sdv.y;
    const __half* hb = h2h + h2_str;
    int beg = rowptr[n], end = rowptr[n + 1];
    float acc0 = 0.f, zz0 = 0.f, acc1 = 0.f, zz1 = 0.f;
    int j = beg;
    for (; j + 8 <= end; j += 8) {
        int s[8]; float2 f[8]; __half g0[8], g1[8];
#pragma unroll
        for (int k = 0; k < 8; ++k) s[k] = csrc[j + k];
#pragma unroll
        for (int k = 0; k < 8; ++k) f[k] = s2sp2[s[k]];
#pragma unroll
        for (int k = 0; k < 8; ++k) g0[k] = h2h[(size_t)s[k] * 32 + c];
#pragma unroll
        for (int k = 0; k < 8; ++k) g1[k] = hb[(size_t)s[k] * 32 + c];
#pragma unroll
        for (int k = 0; k < 8; ++k) {
            float t0 = f[k].x + sd0;
            t0 = t0 > 0.f ? t0 : 0.2f * t0;
            float q0 = __expf(t0);
            zz0 += q0; acc0 += q0 * __half2float(g0[k]);
            float t1 = f[k].y + sd1;
            t1 = t1 > 0.f ? t1 : 0.2f * t1;
            float q1 = __expf(t1);
            zz1 += q1; acc1 += q1 * __half2float(g1[k]);
        }
    }
    for (; j < end; ++j) {
        int s = csrc[j];
        float2 f = s2sp2[s];
        float t0 = f.x + sd0;
        t0 = t0 > 0.f ? t0 : 0.2f * t0;
        float q0 = __expf(t0);
        zz0 += q0; acc0 += q0 * __half2float(h2h[(size_t)s * 32 + c]);
        float t1 = f.y + sd1;
        t1 = t1 > 0.f ? t1 : 0.2f * t1;
        float q1 = __expf(t1);
        zz1 += q1; acc1 += q1 * __half2float(hb[(size_t)s * 32 + c]);
    }
    float bbv = b2[c], ppv = p2[c];
    float v0 = acc0 / (zz0 + 1e-16f) + bbv;
    v0 = v0 > 0.f ? v0 : ppv * v0;
    float v1 = acc1 / (zz1 + 1e-16f) + bbv;
    v1 = v1 > 0.f ? v1 : ppv * v1;
    o_x2[(size_t)n * 32 + c] = v0;
    // --- fused heads: q/k projections (l2norm) + adversarial sums ---
    float accq = 0.f, acck = 0.f;
    for (int cc = 0; cc < 32; ++cc) {
        accq += __shfl(v0, cc, 32) * Wq[cc * 32 + c];
        acck += __shfl(v1, cc, 32) * Wk[cc * 32 + c];
    }
    float sq = accq * accq, sk = acck * acck;
    for (int m = 16; m; m >>= 1) {
        sq += __shfl_xor(sq, m);
        sk += __shfl_xor(sk, m);
    }
    o_q[(size_t)n * 32 + c] = accq / (sqrtf(sq) + 1e-12f);
    o_k[(size_t)n * 32 + c] = acck / (sqrtf(sk) + 1e-12f);
    float ws = 0.f;
    {
        const float4* aw4 = reinterpret_cast<const float4*>(advw + c * 32);
#pragma unroll
        for (int t = 0; t < 8; ++t) {
            float4 v = aw4[t];
            ws += v.x + v.y + v.z + v.w;
        }
    }
    float bs = advb[c];
    for (int m = 16; m; m >>= 1) bs += __shfl_xor(bs, m);
    float vo = v0 * ws, va = v1 * ws;
    for (int m = 16; m; m >>= 1) {
        vo += __shfl_xor(vo, m);
        va += __shfl_xor(va, m);
    }
    if (c == 0) {
        o_logits[n] = vo + bs;
        o_logits[N + n] = va + bs;
    }
}

// ------------------------------- fusion decoder ----------------------------
__global__ __launch_bounds__(256) void k_fusion(const float* __restrict__ x2o,
                                                const int* __restrict__ idx,
                                                const float* __restrict__ Wf,
                                                const float* __restrict__ bfb,
                                                const float* __restrict__ Wlog,
                                                const float* __restrict__ blog,
                                                const float* __restrict__ Wlog1,
                                                const float* __restrict__ blog1,
                                                float* __restrict__ out_log,
                                                float* __restrict__ out_log1, int NB) {
    int i = (blockIdx.x * 256 + threadIdx.x) >> 5;
    int o = threadIdx.x & 31;
    if (i >= NB) return;
    int i1 = idx[i], i2 = idx[NB + i];
    float e1 = x2o[(size_t)i1 * 32 + o];
    float e2 = x2o[(size_t)i2 * 32 + o];
    float acc = bfb[o];
    for (int c = 0; c < 32; ++c) {
        acc += __shfl(e1, c, 32) * Wf[c * 32 + o];
        acc += __shfl(e2, c, 32) * Wf[(32 + c) * 32 + o];
    }
    float h = acc > 0.f ? acc : 0.f;
    float v0 = h * Wlog[o];
    float v1 = h * Wlog1[o];
    for (int m = 16; m; m >>= 1) {
        v0 += __shfl_xor(v0, m);
        v1 += __shfl_xor(v1, m);
    }
    if (o == 0) {
        out_log[i] = v0 + blog[0];
        out_log1[i] = v1 + blog1[0];
    }
}

// ---------------------------------------------------------------------------
extern "C" void kernel_launch(void* const* d_in, const int* in_sizes, int n_in,
                              void* d_out, int out_size, void* d_ws, size_t ws_size,
                              hipStream_t stream) {
    const float* x_o = (const float*)d_in[0];
    const float* x_a = (const float*)d_in[1];
    const float* W1 = (const float*)d_in[2];
    const float* a_src1 = (const float*)d_in[3];
    const float* a_dst1 = (const float*)d_in[4];
    const float* b1 = (const float*)d_in[5];
    const float* p1 = (const float*)d_in[6];
    const float* W2 = (const float*)d_in[7];
    const float* a_src2 = (const float*)d_in[8];
    const float* a_dst2 = (const float*)d_in[9];
    const float* b2 = (const float*)d_in[10];
    const float* p2 = (const float*)d_in[11];
    const float* adv_w = (const float*)d_in[12];
    const float* adv_b = (const float*)d_in[13];
    const float* Wq = (const float*)d_in[14];
    const float* Wk = (const float*)d_in[15];
    const float* Wf = (const float*)d_in[16];
    const float* bf_ = (const float*)d_in[17];
    const float* Wlog = (const float*)d_in[18];
    const float* blog = (const float*)d_in[19];
    const float* Wlog1 = (const float*)d_in[20];
    const float* blog1 = (const float*)d_in[21];
    const int* ei = (const int*)d_in[22];
    const int* idx = (const int*)d_in[23];

    const int N = in_sizes[0] / 128;
    const int E = in_sizes[22] / 2;
    const int NB = in_sizes[23] / 2;
    const int* esrc = ei;
    const int* edst = ei + E;
    const int GS = (N + 255) / 256;
    const int GE = (E + 255) / 256;
    const int rows_pad = (N + 63) & ~63;

    char* ws = (char*)d_ws;
    size_t off = 0;
    auto alloc = [&](size_t bytes) -> void* {
        void* p = ws + off;
        off += (bytes + 255) & ~(size_t)255;
        return p;
    };
    f16* h1h = (f16*)alloc((size_t)2 * N * 256 * 2);
    f16* x1h = (f16*)alloc((size_t)2 * rows_pad * 256 * 2);
    f16* wpk1 = (f16*)alloc((size_t)16 * 4 * 64 * 8 * 2);
    f16* wpk2 = (f16*)alloc((size_t)2 * 8 * 64 * 8 * 2);
    __half* h2h = (__half*)alloc((size_t)2 * N * 32 * 2);
    float* spp = (float*)alloc((size_t)N * 8 * 4);   // packed [n][hh][pass]
    float* sdp = (float*)alloc((size_t)N * 8 * 4);
    float* s2sp = (float*)alloc((size_t)N * 2 * 4);  // packed [n][pass]
    float* s2dp = (float*)alloc((size_t)N * 2 * 4);
    int* rowptr = (int*)alloc((size_t)(N + 1) * 4);
    int* cursor = (int*)alloc((size_t)N * 4);
    int* bsums = (int*)alloc(256 * 4);
    int* csrc = (int*)alloc((size_t)E * 4);

    // --- CSR build ---
    k_zero_i<<<GS, 256, 0, stream>>>(cursor, N);
    k_count<<<GE, 256, 0, stream>>>(edst, E, cursor);
    k_scan_local<<<GS, 256, 0, stream>>>(cursor, rowptr, bsums, N);
    k_scan_apply<<<GS, 256, 0, stream>>>(rowptr, bsums, cursor, N, E);
    k_fill<<<GE, 256, 0, stream>>>(esrc, edst, E, cursor, csrc);

    // --- weight packing (one launch) ---
    k_wpack_all<<<20, 256, 0, stream>>>(W1, wpk1, W2, wpk2);

    const size_t h1_str = (size_t)N * 256;
    const size_t x1_str = (size_t)rows_pad * 256;
    const size_t h2_str = (size_t)N * 32;

    const int Bg = rows_pad / 64;
    const int Ba1 = (N + 3) / 4;
    const int Ba2 = (N + 7) / 8;

    // --- output layout ---
    float* out = (float*)d_out;
    float* o_log = out;                        // [NB]
    float* o_q = o_log + NB;                   // [N*32]
    float* o_k = o_q + (size_t)N * 32;         // [N*32]
    float* o_x2 = o_k + (size_t)N * 32;        // [N*32]
    float* o_logits = o_x2 + (size_t)N * 32;   // [2N]
    float* o_log1 = o_logits + (size_t)2 * N;  // [NB]

    k_gemm1m<<<2 * Bg, 256, 0, stream>>>(x_o, x_a, wpk1, a_src1, a_dst1, h1h, spp, sdp,
                                         N, Bg, h1_str);
    k_agg1<<<Ba1, 256, 0, stream>>>(rowptr, csrc, spp, sdp, h1h, b1, p1, x1h,
                                    N, h1_str, x1_str);
    k_gemm2m<<<2 * Bg, 256, 0, stream>>>(x1h, wpk2, a_src2, a_dst2, h2h, s2sp, s2dp, N,
                                         Bg, x1_str, h2_str);
    k_agg2h<<<Ba2, 256, 0, stream>>>(rowptr, csrc, s2sp, s2dp, h2h, b2, p2,
                                     Wq, Wk, adv_w, adv_b,
                                     o_q, o_k, o_x2, o_logits, N, h2_str);
    k_fusion<<<(NB + 7) / 8, 256, 0, stream>>>(o_x2, idx, Wf, bf_, Wlog, blog, Wlog1, blog1,
                                               o_log, o_log1, NB);
}